// Round 4
// baseline (3666.358 us; speedup 1.0000x reference)
//
#include <hip/hip_runtime.h>
#include <math.h>

#define N_NODES   100000
#define N_EDGES   200000
#define NNZ       2000000
#define K_KEEP    1000000
#define BANDCAP   32768
#define DELTA     1.0e-3f
#define SCAN_BLOCKS 196   // ceil(200000/1024)
#define MAXU 16           // f32 register stash per half-lane: covers deg <= 32

// ---------------- workspace layout (bytes) ----------------
#define OFF_PAB   ((size_t)0)          // f32 p_ab [N_NODES*64]   25,600,000 (row: a[0..31]|b[32..63])
#define OFF_PB32  ((size_t)25600000)   // f32 probs_b [NNZ]        8,000,000 (CSR/p-order probs)
#define OFF_VB    ((size_t)33600000)   // u32 vbucket [NNZ]        8,000,000
#define OFF_POS   ((size_t)41600000)   // u32 pos [NNZ] j->p       8,000,000
#define OFF_HB    ((size_t)49600000)   // u8  hardbit [NNZ]        2,000,000 (p-order)
#define OFF_EOFF  ((size_t)51600000)   // u32 edge_off [N_EDGES]     800,000
#define OFF_CUR   ((size_t)52400000)   // u32 cursor [N_EDGES]       800,000
#define OFF_BS    ((size_t)53200000)   // u32 bsums [256]              1,024
#define OFF_BANDP ((size_t)53201024)   // u32 band_p [BANDCAP]       131,072
#define OFF_BANDJ ((size_t)53332096)   // u32 band_j [BANDCAP]       131,072
#define OFF_BANDK ((size_t)53463168)   // u64 band_key [BANDCAP]     262,144
// --- zero region ---
#define OFF_FLAG  ((size_t)53725312)   // u8  flag [NNZ]           2,000,000 (0 none,1 band,2 selected)
#define OFF_ECNT  ((size_t)55725312)   // u32 edge_cnt [N_EDGES]     800,000
#define OFF_HIST  ((size_t)56525312)   // u32 hist [2*2048]           16,384
#define OFF_ST    ((size_t)56541696)   // SelState                        64
#define ZERO_OFF  OFF_FLAG
#define ZERO_LEN  ((size_t)(56541760 - 53725312))

struct SelState {
    unsigned int B1;        // pass-1 bucket
    unsigned int rem1;      // remaining rank within B1
    float lo_edge, hi_edge; // band boundaries (set by scan pass 2)
    unsigned int n_hi;      // count of probs > hi_edge
    unsigned int band_n;    // band append counter
};

// p_ab[v][k] = sum_d x[v][d]*W1[d][k];  p_ab[v][32+k] = sum_d x[v][d]*W1[64+d][k]
__global__ void proj_kernel(const float* __restrict__ x, const float* __restrict__ W1,
                            float* __restrict__ p_ab) {
    __shared__ float sW[128 * 32];
    __shared__ float sx[8][64];
    for (int t = threadIdx.x; t < 128 * 32; t += 256) sW[t] = W1[t];
    int base = blockIdx.x * 8;
    for (int t = threadIdx.x; t < 512; t += 256) {
        int n = t >> 6, d = t & 63;
        int g = base + n;
        sx[n][d] = (g < N_NODES) ? x[(size_t)g * 64 + d] : 0.f;
    }
    __syncthreads();
    int ln = threadIdx.x >> 5;
    int k  = threadIdx.x & 31;
    int node = base + ln;
    if (node >= N_NODES) return;
    float sa = 0.f, sb = 0.f;
    for (int d = 0; d < 64; ++d) {
        float xv = sx[ln][d];
        sa += xv * sW[d * 32 + k];
        sb += xv * sW[(64 + d) * 32 + k];
    }
    p_ab[(size_t)node * 64 + k]      = sa;
    p_ab[(size_t)node * 64 + 32 + k] = sb;
}

// ---------------- CSR build ----------------
__global__ void count_kernel(const int* __restrict__ E, unsigned int* __restrict__ edge_cnt) {
    int j = blockIdx.x * 256 + threadIdx.x;
    if (j >= NNZ) return;
    atomicAdd(&edge_cnt[E[j]], 1u);
}

__global__ void scanA_kernel(const unsigned int* __restrict__ edge_cnt,
                             unsigned int* __restrict__ edge_off, unsigned int* __restrict__ bsums) {
    __shared__ unsigned int s[256];
    int tid = threadIdx.x;
    int base = blockIdx.x * 1024 + tid * 4;
    unsigned int v0 = (base + 0 < N_EDGES) ? edge_cnt[base + 0] : 0u;
    unsigned int v1 = (base + 1 < N_EDGES) ? edge_cnt[base + 1] : 0u;
    unsigned int v2 = (base + 2 < N_EDGES) ? edge_cnt[base + 2] : 0u;
    unsigned int v3 = (base + 3 < N_EDGES) ? edge_cnt[base + 3] : 0u;
    unsigned int tsum = v0 + v1 + v2 + v3;
    s[tid] = tsum;
    __syncthreads();
    for (int off = 1; off < 256; off <<= 1) {
        unsigned int t = (tid >= off) ? s[tid - off] : 0u;
        __syncthreads();
        s[tid] += t;
        __syncthreads();
    }
    unsigned int excl = s[tid] - tsum;
    if (base + 0 < N_EDGES) edge_off[base + 0] = excl;
    if (base + 1 < N_EDGES) edge_off[base + 1] = excl + v0;
    if (base + 2 < N_EDGES) edge_off[base + 2] = excl + v0 + v1;
    if (base + 3 < N_EDGES) edge_off[base + 3] = excl + v0 + v1 + v2;
    if (tid == 255) bsums[blockIdx.x] = s[255];
}

__global__ void scanB_kernel(unsigned int* __restrict__ bsums) {
    __shared__ unsigned int s[256];
    int tid = threadIdx.x;
    unsigned int v = (tid < SCAN_BLOCKS) ? bsums[tid] : 0u;
    s[tid] = v;
    __syncthreads();
    for (int off = 1; off < 256; off <<= 1) {
        unsigned int t = (tid >= off) ? s[tid - off] : 0u;
        __syncthreads();
        s[tid] += t;
        __syncthreads();
    }
    if (tid < SCAN_BLOCKS) bsums[tid] = s[tid] - v;
}

__global__ void scanC_kernel(unsigned int* __restrict__ edge_off, const unsigned int* __restrict__ bsums,
                             unsigned int* __restrict__ cursor) {
    int i = blockIdx.x * 256 + threadIdx.x;
    if (i >= N_EDGES) return;
    unsigned int o = edge_off[i] + bsums[i >> 10];
    edge_off[i] = o;
    cursor[i] = o;
}

__global__ void bucket_kernel(const int* __restrict__ V, const int* __restrict__ E,
                              unsigned int* __restrict__ cursor,
                              unsigned int* __restrict__ vbucket, unsigned int* __restrict__ pos) {
    int j = blockIdx.x * 256 + threadIdx.x;
    if (j >= NNZ) return;
    int e = E[j];
    unsigned int p = atomicAdd(&cursor[e], 1u);
    vbucket[p] = (unsigned int)V[j];
    pos[j] = p;
}

// ---------------- fused per-edge mean + per-incidence MLP (f32, CSR-order writes) ----------------
__global__ void edge_logit_kernel(const unsigned int* __restrict__ vbucket,
                                  const unsigned int* __restrict__ edge_off,
                                  const unsigned int* __restrict__ edge_cnt,
                                  const float* __restrict__ p_ab,
                                  const float* __restrict__ b1, const float* __restrict__ W2,
                                  const float* __restrict__ b2,
                                  float* __restrict__ probs_b, float* __restrict__ o_ep) {
    int e = blockIdx.x * 4 + (threadIdx.x >> 6);
    if (e >= N_EDGES) return;
    int lane = threadIdx.x & 63;
    int k    = lane & 31;
    unsigned int half = (unsigned int)(lane >> 5);

    unsigned int off = edge_off[e];
    unsigned int deg = edge_cnt[e];

    float aval[MAXU];
    float bacc = 0.f;

    #pragma unroll
    for (int idx = 0; idx < MAXU; ++idx) {
        unsigned int i = half + 2u * (unsigned int)idx;
        if (i < deg) {
            unsigned int v = vbucket[off + i];
            const float* row = p_ab + (size_t)v * 64u;
            aval[idx] = row[k];
            bacc     += row[32 + k];
        }
    }
    if (deg > 2u * MAXU) {
        for (unsigned int i = half + 2u * MAXU; i < deg; i += 2u) {
            unsigned int v = vbucket[off + i];
            bacc += p_ab[(size_t)v * 64u + 32u + k];
        }
    }

    float cc  = (float)(deg > 1u ? deg : 1u);
    float emk = (bacc + __shfl_xor(bacc, 32)) / cc + b1[k];
    float w2k = W2[k];
    float b2v = b2[0];
    float epsum = 0.f;

    #pragma unroll
    for (int idx = 0; idx < MAXU; ++idx) {
        unsigned int i = half + 2u * (unsigned int)idx;
        if (i < deg) {
            float hk = aval[idx] + emk;
            hk = hk > 0.f ? hk : 0.f;
            float t = hk * w2k;
            #pragma unroll
            for (int o = 16; o > 0; o >>= 1) t += __shfl_down(t, o, 32);
            if (k == 0) {
                float pr = 1.f / (1.f + __expf(-(t + b2v)));
                probs_b[off + i] = pr;
                epsum += pr;
            }
        }
    }
    if (deg > 2u * MAXU) {
        for (unsigned int i = half + 2u * MAXU; i < deg; i += 2u) {
            unsigned int v = vbucket[off + i];
            float hk = p_ab[(size_t)v * 64u + k] + emk;
            hk = hk > 0.f ? hk : 0.f;
            float t = hk * w2k;
            #pragma unroll
            for (int o = 16; o > 0; o >>= 1) t += __shfl_down(t, o, 32);
            if (k == 0) {
                float pr = 1.f / (1.f + __expf(-(t + b2v)));
                probs_b[off + i] = pr;
                epsum += pr;
            }
        }
    }
    float etot = epsum + __shfl_xor(epsum, 32);
    if (lane == 0) o_ep[e] = etot / cc;
}

// ---------------- 2-level radix histogram on f32 keys ----------------
__global__ void hist1_kernel(const float* __restrict__ probs_b, unsigned int* __restrict__ hist) {
    __shared__ unsigned int lh[2048];
    for (int t = threadIdx.x; t < 2048; t += 256) lh[t] = 0;
    __syncthreads();
    for (unsigned int i = blockIdx.x * 256 + threadIdx.x; i < NNZ; i += gridDim.x * 256) {
        unsigned int key = __float_as_uint(probs_b[i]);
        atomicAdd(&lh[key >> 21], 1u);
    }
    __syncthreads();
    for (int t = threadIdx.x; t < 2048; t += 256)
        if (lh[t]) atomicAdd(&hist[t], lh[t]);
}

__global__ void hist2_kernel(const float* __restrict__ probs_b, const SelState* __restrict__ st,
                             unsigned int* __restrict__ hist) {
    __shared__ unsigned int lh[2048];
    for (int t = threadIdx.x; t < 2048; t += 256) lh[t] = 0;
    __syncthreads();
    unsigned int B1 = st->B1;
    for (unsigned int i = blockIdx.x * 256 + threadIdx.x; i < NNZ; i += gridDim.x * 256) {
        unsigned int key = __float_as_uint(probs_b[i]);
        if ((key >> 21) == B1) atomicAdd(&lh[(key >> 10) & 2047u], 1u);
    }
    __syncthreads();
    for (int t = threadIdx.x; t < 2048; t += 256)
        if (lh[t]) atomicAdd(&hist[2048 + t], lh[t]);
}

// which=0: select bucket B1 at rank K_KEEP; which=1: select B2 at rank rem1, set band edges
__global__ void scan_sel_kernel(const unsigned int* __restrict__ hist, SelState* __restrict__ st, int which) {
    __shared__ unsigned int csum[256];
    int t = threadIdx.x;
    unsigned int target = (which == 0) ? (unsigned int)K_KEEP : st->rem1;
    const unsigned int* h = hist + (which ? 2048 : 0);
    unsigned int b[8];
    unsigned int s = 0;
    #pragma unroll
    for (int i = 0; i < 8; ++i) { b[i] = h[t * 8 + i]; s += b[i]; }
    csum[t] = s;
    __syncthreads();
    for (int off = 1; off < 256; off <<= 1) {
        unsigned int v = (t + off < 256) ? csum[t + off] : 0u;
        __syncthreads();
        csum[t] += v;
        __syncthreads();
    }
    unsigned int above = csum[t] - s;       // sum over chunks > t
    if (above < target && target <= above + s) {
        unsigned int rem = target - above;
        unsigned int cum = 0;
        #pragma unroll
        for (int i = 7; i >= 0; --i) {
            if (rem <= cum + b[i]) {
                unsigned int bin = (unsigned int)(t * 8 + i);
                if (which == 0) { st->B1 = bin; st->rem1 = rem - cum; }
                else {
                    unsigned int P = (st->B1 << 21) | (bin << 10);
                    st->lo_edge = __uint_as_float(P) - DELTA;
                    st->hi_edge = __uint_as_float(P + 1024u) + DELTA;
                }
                break;
            }
            cum += b[i];
        }
    }
}

// count n_hi = #{p > hi_edge}; flag band members [lo_edge, hi_edge]
__global__ void band_kernel(const float* __restrict__ probs_b, SelState* __restrict__ st,
                            unsigned char* __restrict__ flag) {
    unsigned int p = blockIdx.x * 256 + threadIdx.x;
    float hi = st->hi_edge, lo = st->lo_edge;
    float pk = (p < NNZ) ? probs_b[p] : -1.f;
    bool ishi = pk > hi;
    unsigned long long m = __ballot(ishi);
    if ((threadIdx.x & 63) == 0 && m) atomicAdd(&st->n_hi, (unsigned int)__popcll(m));
    if (p < NNZ && !ishi && pk >= lo) flag[p] = 1;
}

// append (j, p) pairs for band members (j = original incidence index, for tie-break)
__global__ void bandj_kernel(const unsigned int* __restrict__ pos, const unsigned char* __restrict__ flag,
                             SelState* __restrict__ st,
                             unsigned int* __restrict__ band_p, unsigned int* __restrict__ band_j) {
    unsigned int j = blockIdx.x * 256 + threadIdx.x;
    if (j >= NNZ) return;
    unsigned int p = pos[j];
    if (flag[p] == 1u) {
        unsigned int s = atomicAdd(&st->band_n, 1u);
        if (s < BANDCAP) { band_p[s] = p; band_j[s] = j; }
    }
}

// exact f64 recompute of prob for band members (from x, W1 directly)
__global__ void rescue_kernel(const unsigned int* __restrict__ vbucket,
                              const unsigned int* __restrict__ edge_off,
                              const unsigned int* __restrict__ edge_cnt,
                              const float* __restrict__ x, const float* __restrict__ W1,
                              const float* __restrict__ b1, const float* __restrict__ W2,
                              const float* __restrict__ b2,
                              const unsigned int* __restrict__ band_p,
                              const SelState* __restrict__ st,
                              unsigned long long* __restrict__ band_key) {
    unsigned int n = st->band_n; if (n > BANDCAP) n = BANDCAP;
    unsigned int g = blockIdx.x * 8 + (threadIdx.x >> 5);
    if (g >= n) return;
    int k = threadIdx.x & 31;
    unsigned int p = band_p[g];
    unsigned int v = vbucket[p];
    // binary search: largest e with edge_off[e] <= p
    unsigned int lo = 0, hi = N_EDGES - 1;
    while (lo < hi) {
        unsigned int mid = (lo + hi + 1) >> 1;
        if (edge_off[mid] <= p) lo = mid; else hi = mid - 1;
    }
    unsigned int e = lo;
    unsigned int off = edge_off[e];
    unsigned int deg = edge_cnt[e];

    const float* xv = x + (size_t)v * 64u;
    double a = 0.0;
    for (int d = 0; d < 64; ++d) a += (double)xv[d] * (double)W1[d * 32 + k];
    double bsum = 0.0;
    for (unsigned int m = off; m < off + deg; ++m) {
        const float* xm = x + (size_t)vbucket[m] * 64u;
        double acc = 0.0;
        for (int d = 0; d < 64; ++d) acc += (double)xm[d] * (double)W1[(64 + d) * 32 + k];
        bsum += acc;
    }
    double cc = (double)(deg > 1u ? deg : 1u);
    double h = a + bsum / cc + (double)b1[k];
    h = h > 0.0 ? h : 0.0;
    double t = h * (double)W2[k];
    #pragma unroll
    for (int o = 16; o > 0; o >>= 1) t += __shfl_down(t, o, 32);
    if (k == 0) {
        double pr = 1.0 / (1.0 + exp(-(t + (double)b2[0])));
        band_key[g] = (unsigned long long)__double_as_longlong(pr);
    }
}

// exact rank among band by (p64 desc, j asc); mark selected with flag=2
__global__ void rank_kernel(const unsigned long long* __restrict__ band_key,
                            const unsigned int* __restrict__ band_j,
                            const unsigned int* __restrict__ band_p,
                            const SelState* __restrict__ st, unsigned char* __restrict__ flag) {
    unsigned int n = st->band_n; if (n > BANDCAP) n = BANDCAP;
    unsigned int need = (unsigned int)K_KEEP - st->n_hi;
    for (unsigned int i = blockIdx.x * 256 + threadIdx.x; i < n; i += gridDim.x * 256) {
        unsigned long long ki = band_key[i];
        unsigned int ji = band_j[i];
        unsigned int r = 0;
        for (unsigned int q = 0; q < n; ++q) {
            unsigned long long kq = band_key[q];
            unsigned int jq = band_j[q];
            if (kq > ki || (kq == ki && jq < ji)) r++;
        }
        if (r < need) flag[band_p[i]] = 2u;
    }
}

// p-order: hard decision
__global__ void hard_kernel(const float* __restrict__ probs_b, const unsigned char* __restrict__ flag,
                            const SelState* __restrict__ st, unsigned char* __restrict__ hardbit) {
    unsigned int p = blockIdx.x * 256 + threadIdx.x;
    if (p >= NNZ) return;
    hardbit[p] = (probs_b[p] > st->hi_edge || flag[p] == 2u) ? 1u : 0u;
}

// j-order coalesced outputs
__global__ void out_kernel(const float* __restrict__ probs_b, const unsigned char* __restrict__ hardbit,
                           const unsigned int* __restrict__ pos,
                           float* __restrict__ o_probs, float* __restrict__ o_soft, float* __restrict__ o_hard) {
    unsigned int j = blockIdx.x * 256 + threadIdx.x;
    if (j >= NNZ) return;
    unsigned int p = pos[j];
    float pk = probs_b[p];
    float hb = (float)hardbit[p];
    o_probs[j] = pk;
    o_soft[j]  = hb;
    o_hard[j]  = hb;
}

// per-edge: edge_soft / edge_hard from hard bits
__global__ void edge_out_kernel(const unsigned char* __restrict__ hardbit,
                                const unsigned int* __restrict__ edge_off,
                                const unsigned int* __restrict__ edge_cnt,
                                float* __restrict__ o_es, float* __restrict__ o_eh) {
    unsigned int e = blockIdx.x * 256 + threadIdx.x;
    if (e >= N_EDGES) return;
    unsigned int off = edge_off[e], deg = edge_cnt[e];
    unsigned int cnt = 0;
    for (unsigned int i = 0; i < deg; ++i) cnt += hardbit[off + i];
    float cc = (float)(deg > 1u ? deg : 1u);
    o_es[e] = (float)cnt / cc;
    o_eh[e] = cnt ? 1.f : 0.f;
}

extern "C" void kernel_launch(void* const* d_in, const int* in_sizes, int n_in,
                              void* d_out, int out_size, void* d_ws, size_t ws_size,
                              hipStream_t stream) {
    const float* x  = (const float*)d_in[0];
    const int*   V  = (const int*)d_in[1];
    const int*   E  = (const int*)d_in[2];
    const float* W1 = (const float*)d_in[3];
    const float* b1 = (const float*)d_in[4];
    const float* W2 = (const float*)d_in[5];
    const float* b2 = (const float*)d_in[6];

    float* out     = (float*)d_out;
    float* o_probs = out;
    float* o_soft  = out + NNZ;
    float* o_hard  = out + 2 * (size_t)NNZ;
    float* o_ep    = out + 3 * (size_t)NNZ;
    float* o_es    = out + 3 * (size_t)NNZ + N_EDGES;
    float* o_eh    = out + 3 * (size_t)NNZ + 2 * (size_t)N_EDGES;

    char* w = (char*)d_ws;
    float*              p_ab     = (float*)(w + OFF_PAB);
    float*              probs_b  = (float*)(w + OFF_PB32);
    unsigned int*       vbucket  = (unsigned int*)(w + OFF_VB);
    unsigned int*       pos      = (unsigned int*)(w + OFF_POS);
    unsigned char*      hardbit  = (unsigned char*)(w + OFF_HB);
    unsigned int*       edge_off = (unsigned int*)(w + OFF_EOFF);
    unsigned int*       cursor   = (unsigned int*)(w + OFF_CUR);
    unsigned int*       bsums    = (unsigned int*)(w + OFF_BS);
    unsigned int*       band_p   = (unsigned int*)(w + OFF_BANDP);
    unsigned int*       band_j   = (unsigned int*)(w + OFF_BANDJ);
    unsigned long long* band_key = (unsigned long long*)(w + OFF_BANDK);
    unsigned char*      flag     = (unsigned char*)(w + OFF_FLAG);
    unsigned int*       edge_cnt = (unsigned int*)(w + OFF_ECNT);
    unsigned int*       hist     = (unsigned int*)(w + OFF_HIST);
    SelState*           st       = (SelState*)(w + OFF_ST);

    hipMemsetAsync(w + ZERO_OFF, 0, ZERO_LEN, stream);

    proj_kernel<<<(N_NODES + 7) / 8, 256, 0, stream>>>(x, W1, p_ab);

    count_kernel<<<(NNZ + 255) / 256, 256, 0, stream>>>(E, edge_cnt);
    scanA_kernel<<<SCAN_BLOCKS, 256, 0, stream>>>(edge_cnt, edge_off, bsums);
    scanB_kernel<<<1, 256, 0, stream>>>(bsums);
    scanC_kernel<<<(N_EDGES + 255) / 256, 256, 0, stream>>>(edge_off, bsums, cursor);
    bucket_kernel<<<(NNZ + 255) / 256, 256, 0, stream>>>(V, E, cursor, vbucket, pos);

    edge_logit_kernel<<<(N_EDGES + 3) / 4, 256, 0, stream>>>(vbucket, edge_off, edge_cnt,
                                                             p_ab, b1, W2, b2, probs_b, o_ep);

    hist1_kernel<<<1024, 256, 0, stream>>>(probs_b, hist);
    scan_sel_kernel<<<1, 256, 0, stream>>>(hist, st, 0);
    hist2_kernel<<<1024, 256, 0, stream>>>(probs_b, st, hist);
    scan_sel_kernel<<<1, 256, 0, stream>>>(hist, st, 1);

    band_kernel<<<(NNZ + 255) / 256, 256, 0, stream>>>(probs_b, st, flag);
    bandj_kernel<<<(NNZ + 255) / 256, 256, 0, stream>>>(pos, flag, st, band_p, band_j);
    rescue_kernel<<<BANDCAP / 8, 256, 0, stream>>>(vbucket, edge_off, edge_cnt, x, W1, b1, W2, b2,
                                                   band_p, st, band_key);
    rank_kernel<<<128, 256, 0, stream>>>(band_key, band_j, band_p, st, flag);

    hard_kernel<<<(NNZ + 255) / 256, 256, 0, stream>>>(probs_b, flag, st, hardbit);
    out_kernel<<<(NNZ + 255) / 256, 256, 0, stream>>>(probs_b, hardbit, pos, o_probs, o_soft, o_hard);
    edge_out_kernel<<<(N_EDGES + 255) / 256, 256, 0, stream>>>(hardbit, edge_off, edge_cnt, o_es, o_eh);
}

// Round 5
// 2093.926 us; speedup vs baseline: 1.7509x; 1.7509x over previous
//
#include <hip/hip_runtime.h>
#include <math.h>

#define N_NODES   100000
#define N_EDGES   200000
#define NNZ       2000000
#define K_KEEP    1000000
#define BANDCAP   65536
#define DELTA     1.0e-3f
#define SCAN_BLOCKS 196   // ceil(200000/1024)
#define MAXU 16           // f32 register stash per half-lane: covers deg <= 32

// ---------------- workspace layout (bytes) ----------------
#define OFF_PAB   ((size_t)0)          // f32 p_ab [N_NODES*64]   25,600,000 (row: a[0..31]|b[32..63])
#define OFF_PB32  ((size_t)25600000)   // f32 probs_b [NNZ]        8,000,000 (CSR/p-order probs)
#define OFF_VB    ((size_t)33600000)   // u32 vbucket [NNZ]        8,000,000
#define OFF_POS   ((size_t)41600000)   // u32 pos [NNZ] j->p       8,000,000
#define OFF_HB    ((size_t)49600000)   // u8  hardbit [NNZ]        2,000,000 (p-order)
#define OFF_EOFF  ((size_t)51600000)   // u32 edge_off [N_EDGES]     800,000
#define OFF_CUR   ((size_t)52400000)   // u32 cursor [N_EDGES]       800,000
#define OFF_BS    ((size_t)53200000)   // u32 bsums [256]              1,024
#define OFF_BANDP ((size_t)53201024)   // u32 band_p [BANDCAP]       262,144
#define OFF_BANDJ ((size_t)53463168)   // u32 band_j [BANDCAP]       262,144
#define OFF_BANDE ((size_t)53725312)   // u32 band_e [BANDCAP]       262,144
#define OFF_BANDV ((size_t)53987456)   // u32 band_v [BANDCAP]       262,144
#define OFF_BANDK ((size_t)54249600)   // u64 band_key [BANDCAP]     524,288
// --- zero region ---
#define OFF_FLAG  ((size_t)54773888)   // u8  flag [NNZ]           2,000,000 (0 none,1 band,2 selected)
#define OFF_ECNT  ((size_t)56773888)   // u32 edge_cnt [N_EDGES]     800,000
#define OFF_HIST  ((size_t)57573888)   // u32 hist [2*2048]           16,384
#define OFF_ST    ((size_t)57590272)   // SelState                        64
#define ZERO_OFF  OFF_FLAG
#define ZERO_LEN  ((size_t)(57590336 - 54773888))

struct SelState {
    unsigned int B1;        // pass-1 bucket
    unsigned int rem1;      // remaining rank within B1
    float lo_edge, hi_edge; // band boundaries (set by scan pass 2)
    unsigned int n_hi;      // count of probs > hi_edge
    unsigned int band_n;    // band append counter
};

// p_ab[v][k] = sum_d x[v][d]*W1[d][k];  p_ab[v][32+k] = sum_d x[v][d]*W1[64+d][k]
__global__ void proj_kernel(const float* __restrict__ x, const float* __restrict__ W1,
                            float* __restrict__ p_ab) {
    __shared__ float sW[128 * 32];
    __shared__ float sx[8][64];
    for (int t = threadIdx.x; t < 128 * 32; t += 256) sW[t] = W1[t];
    int base = blockIdx.x * 8;
    for (int t = threadIdx.x; t < 512; t += 256) {
        int n = t >> 6, d = t & 63;
        int g = base + n;
        sx[n][d] = (g < N_NODES) ? x[(size_t)g * 64 + d] : 0.f;
    }
    __syncthreads();
    int ln = threadIdx.x >> 5;
    int k  = threadIdx.x & 31;
    int node = base + ln;
    if (node >= N_NODES) return;
    float sa = 0.f, sb = 0.f;
    for (int d = 0; d < 64; ++d) {
        float xv = sx[ln][d];
        sa += xv * sW[d * 32 + k];
        sb += xv * sW[(64 + d) * 32 + k];
    }
    p_ab[(size_t)node * 64 + k]      = sa;
    p_ab[(size_t)node * 64 + 32 + k] = sb;
}

// ---------------- CSR build ----------------
__global__ void count_kernel(const int* __restrict__ E, unsigned int* __restrict__ edge_cnt) {
    int j = blockIdx.x * 256 + threadIdx.x;
    if (j >= NNZ) return;
    atomicAdd(&edge_cnt[E[j]], 1u);
}

__global__ void scanA_kernel(const unsigned int* __restrict__ edge_cnt,
                             unsigned int* __restrict__ edge_off, unsigned int* __restrict__ bsums) {
    __shared__ unsigned int s[256];
    int tid = threadIdx.x;
    int base = blockIdx.x * 1024 + tid * 4;
    unsigned int v0 = (base + 0 < N_EDGES) ? edge_cnt[base + 0] : 0u;
    unsigned int v1 = (base + 1 < N_EDGES) ? edge_cnt[base + 1] : 0u;
    unsigned int v2 = (base + 2 < N_EDGES) ? edge_cnt[base + 2] : 0u;
    unsigned int v3 = (base + 3 < N_EDGES) ? edge_cnt[base + 3] : 0u;
    unsigned int tsum = v0 + v1 + v2 + v3;
    s[tid] = tsum;
    __syncthreads();
    for (int off = 1; off < 256; off <<= 1) {
        unsigned int t = (tid >= off) ? s[tid - off] : 0u;
        __syncthreads();
        s[tid] += t;
        __syncthreads();
    }
    unsigned int excl = s[tid] - tsum;
    if (base + 0 < N_EDGES) edge_off[base + 0] = excl;
    if (base + 1 < N_EDGES) edge_off[base + 1] = excl + v0;
    if (base + 2 < N_EDGES) edge_off[base + 2] = excl + v0 + v1;
    if (base + 3 < N_EDGES) edge_off[base + 3] = excl + v0 + v1 + v2;
    if (tid == 255) bsums[blockIdx.x] = s[255];
}

__global__ void scanB_kernel(unsigned int* __restrict__ bsums) {
    __shared__ unsigned int s[256];
    int tid = threadIdx.x;
    unsigned int v = (tid < SCAN_BLOCKS) ? bsums[tid] : 0u;
    s[tid] = v;
    __syncthreads();
    for (int off = 1; off < 256; off <<= 1) {
        unsigned int t = (tid >= off) ? s[tid - off] : 0u;
        __syncthreads();
        s[tid] += t;
        __syncthreads();
    }
    if (tid < SCAN_BLOCKS) bsums[tid] = s[tid] - v;
}

__global__ void scanC_kernel(unsigned int* __restrict__ edge_off, const unsigned int* __restrict__ bsums,
                             unsigned int* __restrict__ cursor) {
    int i = blockIdx.x * 256 + threadIdx.x;
    if (i >= N_EDGES) return;
    unsigned int o = edge_off[i] + bsums[i >> 10];
    edge_off[i] = o;
    cursor[i] = o;
}

__global__ void bucket_kernel(const int* __restrict__ V, const int* __restrict__ E,
                              unsigned int* __restrict__ cursor,
                              unsigned int* __restrict__ vbucket, unsigned int* __restrict__ pos) {
    int j = blockIdx.x * 256 + threadIdx.x;
    if (j >= NNZ) return;
    int e = E[j];
    unsigned int p = atomicAdd(&cursor[e], 1u);
    vbucket[p] = (unsigned int)V[j];
    pos[j] = p;
}

// ---------------- fused per-edge mean + per-incidence MLP (f32, CSR-order writes) ----------------
__global__ void edge_logit_kernel(const unsigned int* __restrict__ vbucket,
                                  const unsigned int* __restrict__ edge_off,
                                  const unsigned int* __restrict__ edge_cnt,
                                  const float* __restrict__ p_ab,
                                  const float* __restrict__ b1, const float* __restrict__ W2,
                                  const float* __restrict__ b2,
                                  float* __restrict__ probs_b, float* __restrict__ o_ep) {
    int e = blockIdx.x * 4 + (threadIdx.x >> 6);
    if (e >= N_EDGES) return;
    int lane = threadIdx.x & 63;
    int k    = lane & 31;
    unsigned int half = (unsigned int)(lane >> 5);

    unsigned int off = edge_off[e];
    unsigned int deg = edge_cnt[e];

    float aval[MAXU];
    float bacc = 0.f;

    #pragma unroll
    for (int idx = 0; idx < MAXU; ++idx) {
        unsigned int i = half + 2u * (unsigned int)idx;
        if (i < deg) {
            unsigned int v = vbucket[off + i];
            const float* row = p_ab + (size_t)v * 64u;
            aval[idx] = row[k];
            bacc     += row[32 + k];
        }
    }
    if (deg > 2u * MAXU) {
        for (unsigned int i = half + 2u * MAXU; i < deg; i += 2u) {
            unsigned int v = vbucket[off + i];
            bacc += p_ab[(size_t)v * 64u + 32u + k];
        }
    }

    float cc  = (float)(deg > 1u ? deg : 1u);
    float emk = (bacc + __shfl_xor(bacc, 32)) / cc + b1[k];
    float w2k = W2[k];
    float b2v = b2[0];
    float epsum = 0.f;

    #pragma unroll
    for (int idx = 0; idx < MAXU; ++idx) {
        unsigned int i = half + 2u * (unsigned int)idx;
        if (i < deg) {
            float hk = aval[idx] + emk;
            hk = hk > 0.f ? hk : 0.f;
            float t = hk * w2k;
            #pragma unroll
            for (int o = 16; o > 0; o >>= 1) t += __shfl_down(t, o, 32);
            if (k == 0) {
                float pr = 1.f / (1.f + __expf(-(t + b2v)));
                probs_b[off + i] = pr;
                epsum += pr;
            }
        }
    }
    if (deg > 2u * MAXU) {
        for (unsigned int i = half + 2u * MAXU; i < deg; i += 2u) {
            unsigned int v = vbucket[off + i];
            float hk = p_ab[(size_t)v * 64u + k] + emk;
            hk = hk > 0.f ? hk : 0.f;
            float t = hk * w2k;
            #pragma unroll
            for (int o = 16; o > 0; o >>= 1) t += __shfl_down(t, o, 32);
            if (k == 0) {
                float pr = 1.f / (1.f + __expf(-(t + b2v)));
                probs_b[off + i] = pr;
                epsum += pr;
            }
        }
    }
    float etot = epsum + __shfl_xor(epsum, 32);
    if (lane == 0) o_ep[e] = etot / cc;
}

// ---------------- 2-level radix histogram on f32 keys ----------------
__global__ void hist1_kernel(const float* __restrict__ probs_b, unsigned int* __restrict__ hist) {
    __shared__ unsigned int lh[2048];
    for (int t = threadIdx.x; t < 2048; t += 256) lh[t] = 0;
    __syncthreads();
    for (unsigned int i = blockIdx.x * 256 + threadIdx.x; i < NNZ; i += gridDim.x * 256) {
        unsigned int key = __float_as_uint(probs_b[i]);
        atomicAdd(&lh[key >> 21], 1u);
    }
    __syncthreads();
    for (int t = threadIdx.x; t < 2048; t += 256)
        if (lh[t]) atomicAdd(&hist[t], lh[t]);
}

__global__ void hist2_kernel(const float* __restrict__ probs_b, const SelState* __restrict__ st,
                             unsigned int* __restrict__ hist) {
    __shared__ unsigned int lh[2048];
    for (int t = threadIdx.x; t < 2048; t += 256) lh[t] = 0;
    __syncthreads();
    unsigned int B1 = st->B1;
    for (unsigned int i = blockIdx.x * 256 + threadIdx.x; i < NNZ; i += gridDim.x * 256) {
        unsigned int key = __float_as_uint(probs_b[i]);
        if ((key >> 21) == B1) atomicAdd(&lh[(key >> 10) & 2047u], 1u);
    }
    __syncthreads();
    for (int t = threadIdx.x; t < 2048; t += 256)
        if (lh[t]) atomicAdd(&hist[2048 + t], lh[t]);
}

// which=0: select bucket B1 at rank K_KEEP; which=1: select B2 at rank rem1, set band edges
__global__ void scan_sel_kernel(const unsigned int* __restrict__ hist, SelState* __restrict__ st, int which) {
    __shared__ unsigned int csum[256];
    int t = threadIdx.x;
    unsigned int target = (which == 0) ? (unsigned int)K_KEEP : st->rem1;
    const unsigned int* h = hist + (which ? 2048 : 0);
    unsigned int b[8];
    unsigned int s = 0;
    #pragma unroll
    for (int i = 0; i < 8; ++i) { b[i] = h[t * 8 + i]; s += b[i]; }
    csum[t] = s;
    __syncthreads();
    for (int off = 1; off < 256; off <<= 1) {
        unsigned int v = (t + off < 256) ? csum[t + off] : 0u;
        __syncthreads();
        csum[t] += v;
        __syncthreads();
    }
    unsigned int above = csum[t] - s;       // sum over chunks > t
    if (above < target && target <= above + s) {
        unsigned int rem = target - above;
        unsigned int cum = 0;
        #pragma unroll
        for (int i = 7; i >= 0; --i) {
            if (rem <= cum + b[i]) {
                unsigned int bin = (unsigned int)(t * 8 + i);
                if (which == 0) { st->B1 = bin; st->rem1 = rem - cum; }
                else {
                    unsigned int P = (st->B1 << 21) | (bin << 10);
                    st->lo_edge = __uint_as_float(P) - DELTA;
                    st->hi_edge = __uint_as_float(P + 1024u) + DELTA;
                }
                break;
            }
            cum += b[i];
        }
    }
}

// grid-stride: count n_hi (block-reduced, 1 atomic/block); flag band members [lo,hi]
__global__ void band_kernel(const float* __restrict__ probs_b, SelState* __restrict__ st,
                            unsigned char* __restrict__ flag) {
    __shared__ unsigned int cnt_s;
    if (threadIdx.x == 0) cnt_s = 0;
    __syncthreads();
    float hi = st->hi_edge, lo = st->lo_edge;
    unsigned int local = 0;
    for (unsigned int p = blockIdx.x * 256 + threadIdx.x; p < NNZ; p += gridDim.x * 256) {
        float pk = probs_b[p];
        if (pk > hi) local++;
        else if (pk >= lo) flag[p] = 1;
    }
    #pragma unroll
    for (int o = 32; o > 0; o >>= 1) local += __shfl_down(local, o);
    if ((threadIdx.x & 63) == 0 && local) atomicAdd(&cnt_s, local);
    __syncthreads();
    if (threadIdx.x == 0 && cnt_s) atomicAdd(&st->n_hi, cnt_s);
}

// append (p, j, e, v) for band members (j-order pass; e,v read coalesced from E,V)
__global__ void bandj_kernel(const int* __restrict__ V, const int* __restrict__ E,
                             const unsigned int* __restrict__ pos, const unsigned char* __restrict__ flag,
                             SelState* __restrict__ st,
                             unsigned int* __restrict__ band_p, unsigned int* __restrict__ band_j,
                             unsigned int* __restrict__ band_e, unsigned int* __restrict__ band_v) {
    unsigned int j = blockIdx.x * 256 + threadIdx.x;
    if (j >= NNZ) return;
    unsigned int p = pos[j];
    if (flag[p] == 1u) {
        unsigned int s = atomicAdd(&st->band_n, 1u);
        if (s < BANDCAP) {
            band_p[s] = p;
            band_j[s] = j;
            band_e[s] = (unsigned int)E[j];
            band_v[s] = (unsigned int)V[j];
        }
    }
}

// exact f64 recompute for band members; W1 staged in LDS, no binary search
__global__ void rescue_kernel(const unsigned int* __restrict__ vbucket,
                              const unsigned int* __restrict__ edge_off,
                              const unsigned int* __restrict__ edge_cnt,
                              const float* __restrict__ x, const float* __restrict__ W1,
                              const float* __restrict__ b1, const float* __restrict__ W2,
                              const float* __restrict__ b2,
                              const unsigned int* __restrict__ band_e,
                              const unsigned int* __restrict__ band_v,
                              const SelState* __restrict__ st,
                              unsigned long long* __restrict__ band_key) {
    unsigned int n = st->band_n; if (n > BANDCAP) n = BANDCAP;
    if (blockIdx.x * 8 >= n) return;
    __shared__ float sW[128 * 32];
    for (int t = threadIdx.x; t < 128 * 32; t += 256) sW[t] = W1[t];
    __syncthreads();
    unsigned int g = blockIdx.x * 8 + (threadIdx.x >> 5);
    if (g >= n) return;
    int k = threadIdx.x & 31;
    unsigned int v = band_v[g];
    unsigned int e = band_e[g];
    unsigned int off = edge_off[e];
    unsigned int deg = edge_cnt[e];

    const float* xv = x + (size_t)v * 64u;
    double a = 0.0;
    #pragma unroll 8
    for (int d = 0; d < 64; ++d) a += (double)xv[d] * (double)sW[d * 32 + k];
    double bsum = 0.0;
    for (unsigned int m = off; m < off + deg; ++m) {
        const float* xm = x + (size_t)vbucket[m] * 64u;
        double acc = 0.0;
        #pragma unroll 8
        for (int d = 0; d < 64; ++d) acc += (double)xm[d] * (double)sW[(64 + d) * 32 + k];
        bsum += acc;
    }
    double cc = (double)(deg > 1u ? deg : 1u);
    double h = a + bsum / cc + (double)b1[k];
    h = h > 0.0 ? h : 0.0;
    double t = h * (double)W2[k];
    #pragma unroll
    for (int o = 16; o > 0; o >>= 1) t += __shfl_down(t, o, 32);
    if (k == 0) {
        double pr = 1.0 / (1.0 + exp(-(t + (double)b2[0])));
        band_key[g] = (unsigned long long)__double_as_longlong(pr);
    }
}

// LDS-tiled exact rank by (p64 desc, j asc); mark selected with flag=2
#define RTILE 2048
__global__ void rank_kernel(const unsigned long long* __restrict__ band_key,
                            const unsigned int* __restrict__ band_j,
                            const unsigned int* __restrict__ band_p,
                            const SelState* __restrict__ st, unsigned char* __restrict__ flag) {
    __shared__ unsigned long long sk[RTILE];
    __shared__ unsigned int sj[RTILE];
    unsigned int n = st->band_n; if (n > BANDCAP) n = BANDCAP;
    unsigned int need = (unsigned int)K_KEEP - st->n_hi;
    unsigned int i = blockIdx.x * 256 + threadIdx.x;
    bool act = (i < n);
    unsigned long long ki = act ? band_key[i] : 0ull;
    unsigned int ji = act ? band_j[i] : 0u;
    unsigned int r = 0;
    for (unsigned int base = 0; base < n; base += RTILE) {
        unsigned int m = n - base; if (m > RTILE) m = RTILE;
        for (unsigned int t = threadIdx.x; t < m; t += 256) {
            sk[t] = band_key[base + t];
            sj[t] = band_j[base + t];
        }
        __syncthreads();
        if (act) {
            for (unsigned int q = 0; q < m; ++q) {
                unsigned long long kq = sk[q];
                r += (kq > ki || (kq == ki && sj[q] < ji)) ? 1u : 0u;
            }
        }
        __syncthreads();
    }
    if (act && r < need) flag[band_p[i]] = 2u;
}

// p-order: hard decision
__global__ void hard_kernel(const float* __restrict__ probs_b, const unsigned char* __restrict__ flag,
                            const SelState* __restrict__ st, unsigned char* __restrict__ hardbit) {
    unsigned int p = blockIdx.x * 256 + threadIdx.x;
    if (p >= NNZ) return;
    hardbit[p] = (probs_b[p] > st->hi_edge || flag[p] == 2u) ? 1u : 0u;
}

// j-order coalesced outputs
__global__ void out_kernel(const float* __restrict__ probs_b, const unsigned char* __restrict__ hardbit,
                           const unsigned int* __restrict__ pos,
                           float* __restrict__ o_probs, float* __restrict__ o_soft, float* __restrict__ o_hard) {
    unsigned int j = blockIdx.x * 256 + threadIdx.x;
    if (j >= NNZ) return;
    unsigned int p = pos[j];
    float pk = probs_b[p];
    float hb = (float)hardbit[p];
    o_probs[j] = pk;
    o_soft[j]  = hb;
    o_hard[j]  = hb;
}

// per-edge: edge_soft / edge_hard from hard bits
__global__ void edge_out_kernel(const unsigned char* __restrict__ hardbit,
                                const unsigned int* __restrict__ edge_off,
                                const unsigned int* __restrict__ edge_cnt,
                                float* __restrict__ o_es, float* __restrict__ o_eh) {
    unsigned int e = blockIdx.x * 256 + threadIdx.x;
    if (e >= N_EDGES) return;
    unsigned int off = edge_off[e], deg = edge_cnt[e];
    unsigned int cnt = 0;
    for (unsigned int i = 0; i < deg; ++i) cnt += hardbit[off + i];
    float cc = (float)(deg > 1u ? deg : 1u);
    o_es[e] = (float)cnt / cc;
    o_eh[e] = cnt ? 1.f : 0.f;
}

extern "C" void kernel_launch(void* const* d_in, const int* in_sizes, int n_in,
                              void* d_out, int out_size, void* d_ws, size_t ws_size,
                              hipStream_t stream) {
    const float* x  = (const float*)d_in[0];
    const int*   V  = (const int*)d_in[1];
    const int*   E  = (const int*)d_in[2];
    const float* W1 = (const float*)d_in[3];
    const float* b1 = (const float*)d_in[4];
    const float* W2 = (const float*)d_in[5];
    const float* b2 = (const float*)d_in[6];

    float* out     = (float*)d_out;
    float* o_probs = out;
    float* o_soft  = out + NNZ;
    float* o_hard  = out + 2 * (size_t)NNZ;
    float* o_ep    = out + 3 * (size_t)NNZ;
    float* o_es    = out + 3 * (size_t)NNZ + N_EDGES;
    float* o_eh    = out + 3 * (size_t)NNZ + 2 * (size_t)N_EDGES;

    char* w = (char*)d_ws;
    float*              p_ab     = (float*)(w + OFF_PAB);
    float*              probs_b  = (float*)(w + OFF_PB32);
    unsigned int*       vbucket  = (unsigned int*)(w + OFF_VB);
    unsigned int*       pos      = (unsigned int*)(w + OFF_POS);
    unsigned char*      hardbit  = (unsigned char*)(w + OFF_HB);
    unsigned int*       edge_off = (unsigned int*)(w + OFF_EOFF);
    unsigned int*       cursor   = (unsigned int*)(w + OFF_CUR);
    unsigned int*       bsums    = (unsigned int*)(w + OFF_BS);
    unsigned int*       band_p   = (unsigned int*)(w + OFF_BANDP);
    unsigned int*       band_j   = (unsigned int*)(w + OFF_BANDJ);
    unsigned int*       band_e   = (unsigned int*)(w + OFF_BANDE);
    unsigned int*       band_v   = (unsigned int*)(w + OFF_BANDV);
    unsigned long long* band_key = (unsigned long long*)(w + OFF_BANDK);
    unsigned char*      flag     = (unsigned char*)(w + OFF_FLAG);
    unsigned int*       edge_cnt = (unsigned int*)(w + OFF_ECNT);
    unsigned int*       hist     = (unsigned int*)(w + OFF_HIST);
    SelState*           st       = (SelState*)(w + OFF_ST);

    hipMemsetAsync(w + ZERO_OFF, 0, ZERO_LEN, stream);

    proj_kernel<<<(N_NODES + 7) / 8, 256, 0, stream>>>(x, W1, p_ab);

    count_kernel<<<(NNZ + 255) / 256, 256, 0, stream>>>(E, edge_cnt);
    scanA_kernel<<<SCAN_BLOCKS, 256, 0, stream>>>(edge_cnt, edge_off, bsums);
    scanB_kernel<<<1, 256, 0, stream>>>(bsums);
    scanC_kernel<<<(N_EDGES + 255) / 256, 256, 0, stream>>>(edge_off, bsums, cursor);
    bucket_kernel<<<(NNZ + 255) / 256, 256, 0, stream>>>(V, E, cursor, vbucket, pos);

    edge_logit_kernel<<<(N_EDGES + 3) / 4, 256, 0, stream>>>(vbucket, edge_off, edge_cnt,
                                                             p_ab, b1, W2, b2, probs_b, o_ep);

    hist1_kernel<<<1024, 256, 0, stream>>>(probs_b, hist);
    scan_sel_kernel<<<1, 256, 0, stream>>>(hist, st, 0);
    hist2_kernel<<<1024, 256, 0, stream>>>(probs_b, st, hist);
    scan_sel_kernel<<<1, 256, 0, stream>>>(hist, st, 1);

    band_kernel<<<1024, 256, 0, stream>>>(probs_b, st, flag);
    bandj_kernel<<<(NNZ + 255) / 256, 256, 0, stream>>>(V, E, pos, flag, st,
                                                        band_p, band_j, band_e, band_v);
    rescue_kernel<<<BANDCAP / 8, 256, 0, stream>>>(vbucket, edge_off, edge_cnt, x, W1, b1, W2, b2,
                                                   band_e, band_v, st, band_key);
    rank_kernel<<<BANDCAP / 256, 256, 0, stream>>>(band_key, band_j, band_p, st, flag);

    hard_kernel<<<(NNZ + 255) / 256, 256, 0, stream>>>(probs_b, flag, st, hardbit);
    out_kernel<<<(NNZ + 255) / 256, 256, 0, stream>>>(probs_b, hardbit, pos, o_probs, o_soft, o_hard);
    edge_out_kernel<<<(N_EDGES + 255) / 256, 256, 0, stream>>>(hardbit, edge_off, edge_cnt, o_es, o_eh);
}

// Round 6
// 1145.035 us; speedup vs baseline: 3.2020x; 1.8287x over previous
//
#include <hip/hip_runtime.h>
#include <math.h>

#define N_NODES   100000
#define N_EDGES   200000
#define NNZ       2000000
#define K_KEEP    1000000
#define BANDCAP   65536
#define DELTA     1.0e-3f
#define SCAN_BLOCKS 196   // ceil(200000/1024)
#define MAXU 16           // f32 register stash per half-lane: covers deg <= 32

// ---------------- workspace layout (bytes) ----------------
#define OFF_PAB   ((size_t)0)          // f32 p_ab [N_NODES*64]   25,600,000 (row: a[0..31]|b[32..63])
#define OFF_PB32  ((size_t)25600000)   // f32 probs_b [NNZ]        8,000,000 (CSR/p-order probs)
#define OFF_VB    ((size_t)33600000)   // u32 vbucket [NNZ]        8,000,000
#define OFF_POS   ((size_t)41600000)   // u32 pos [NNZ] j->p       8,000,000
#define OFF_HB    ((size_t)49600000)   // u8  hardbit [NNZ]        2,000,000 (p-order)
#define OFF_EOFF  ((size_t)51600000)   // u32 edge_off [N_EDGES]     800,000
#define OFF_CUR   ((size_t)52400000)   // u32 cursor [N_EDGES]       800,000
#define OFF_BS    ((size_t)53200000)   // u32 bsums [256]              1,024
#define OFF_BANDP ((size_t)53201024)   // u32 band_p [BANDCAP]       262,144
#define OFF_BANDJ ((size_t)53463168)   // u32 band_j [BANDCAP]       262,144
#define OFF_BANDE ((size_t)53725312)   // u32 band_e [BANDCAP]       262,144
#define OFF_BANDV ((size_t)53987456)   // u32 band_v [BANDCAP]       262,144
#define OFF_BANDK ((size_t)54249600)   // u64 band_key [BANDCAP]     524,288
// --- zero region ---
#define OFF_FLAG  ((size_t)54773888)   // u8  flag [NNZ]           2,000,000 (0 none,1 band,2 selected)
#define OFF_ECNT  ((size_t)56773888)   // u32 edge_cnt [N_EDGES]     800,000
#define OFF_HIST  ((size_t)57573888)   // u32 hist [2*2048]           16,384
#define OFF_ST    ((size_t)57590272)   // SelState                        64
#define OFF_RGT   ((size_t)57590336)   // u32 rank_gt [BANDCAP]      262,144
#define OFF_REQ   ((size_t)57852480)   // u32 rank_eq [BANDCAP]      262,144
#define ZERO_OFF  OFF_FLAG
#define ZERO_LEN  ((size_t)(58114624 - 54773888))

struct SelState {
    unsigned int B1;        // pass-1 bucket
    unsigned int rem1;      // remaining rank within B1
    float lo_edge, hi_edge; // band boundaries (set by scan pass 2)
    unsigned int n_hi;      // count of probs > hi_edge
    unsigned int band_n;    // band append counter
};

// p_ab[v][k] = sum_d x[v][d]*W1[d][k];  p_ab[v][32+k] = sum_d x[v][d]*W1[64+d][k]
__global__ void proj_kernel(const float* __restrict__ x, const float* __restrict__ W1,
                            float* __restrict__ p_ab) {
    __shared__ float sW[128 * 32];
    __shared__ float sx[8][64];
    for (int t = threadIdx.x; t < 128 * 32; t += 256) sW[t] = W1[t];
    int base = blockIdx.x * 8;
    for (int t = threadIdx.x; t < 512; t += 256) {
        int n = t >> 6, d = t & 63;
        int g = base + n;
        sx[n][d] = (g < N_NODES) ? x[(size_t)g * 64 + d] : 0.f;
    }
    __syncthreads();
    int ln = threadIdx.x >> 5;
    int k  = threadIdx.x & 31;
    int node = base + ln;
    if (node >= N_NODES) return;
    float sa = 0.f, sb = 0.f;
    for (int d = 0; d < 64; ++d) {
        float xv = sx[ln][d];
        sa += xv * sW[d * 32 + k];
        sb += xv * sW[(64 + d) * 32 + k];
    }
    p_ab[(size_t)node * 64 + k]      = sa;
    p_ab[(size_t)node * 64 + 32 + k] = sb;
}

// ---------------- CSR build ----------------
__global__ void count_kernel(const int* __restrict__ E, unsigned int* __restrict__ edge_cnt) {
    int j = blockIdx.x * 256 + threadIdx.x;
    if (j >= NNZ) return;
    atomicAdd(&edge_cnt[E[j]], 1u);
}

__global__ void scanA_kernel(const unsigned int* __restrict__ edge_cnt,
                             unsigned int* __restrict__ edge_off, unsigned int* __restrict__ bsums) {
    __shared__ unsigned int s[256];
    int tid = threadIdx.x;
    int base = blockIdx.x * 1024 + tid * 4;
    unsigned int v0 = (base + 0 < N_EDGES) ? edge_cnt[base + 0] : 0u;
    unsigned int v1 = (base + 1 < N_EDGES) ? edge_cnt[base + 1] : 0u;
    unsigned int v2 = (base + 2 < N_EDGES) ? edge_cnt[base + 2] : 0u;
    unsigned int v3 = (base + 3 < N_EDGES) ? edge_cnt[base + 3] : 0u;
    unsigned int tsum = v0 + v1 + v2 + v3;
    s[tid] = tsum;
    __syncthreads();
    for (int off = 1; off < 256; off <<= 1) {
        unsigned int t = (tid >= off) ? s[tid - off] : 0u;
        __syncthreads();
        s[tid] += t;
        __syncthreads();
    }
    unsigned int excl = s[tid] - tsum;
    if (base + 0 < N_EDGES) edge_off[base + 0] = excl;
    if (base + 1 < N_EDGES) edge_off[base + 1] = excl + v0;
    if (base + 2 < N_EDGES) edge_off[base + 2] = excl + v0 + v1;
    if (base + 3 < N_EDGES) edge_off[base + 3] = excl + v0 + v1 + v2;
    if (tid == 255) bsums[blockIdx.x] = s[255];
}

__global__ void scanB_kernel(unsigned int* __restrict__ bsums) {
    __shared__ unsigned int s[256];
    int tid = threadIdx.x;
    unsigned int v = (tid < SCAN_BLOCKS) ? bsums[tid] : 0u;
    s[tid] = v;
    __syncthreads();
    for (int off = 1; off < 256; off <<= 1) {
        unsigned int t = (tid >= off) ? s[tid - off] : 0u;
        __syncthreads();
        s[tid] += t;
        __syncthreads();
    }
    if (tid < SCAN_BLOCKS) bsums[tid] = s[tid] - v;
}

__global__ void scanC_kernel(unsigned int* __restrict__ edge_off, const unsigned int* __restrict__ bsums,
                             unsigned int* __restrict__ cursor) {
    int i = blockIdx.x * 256 + threadIdx.x;
    if (i >= N_EDGES) return;
    unsigned int o = edge_off[i] + bsums[i >> 10];
    edge_off[i] = o;
    cursor[i] = o;
}

__global__ void bucket_kernel(const int* __restrict__ V, const int* __restrict__ E,
                              unsigned int* __restrict__ cursor,
                              unsigned int* __restrict__ vbucket, unsigned int* __restrict__ pos) {
    int j = blockIdx.x * 256 + threadIdx.x;
    if (j >= NNZ) return;
    int e = E[j];
    unsigned int p = atomicAdd(&cursor[e], 1u);
    vbucket[p] = (unsigned int)V[j];
    pos[j] = p;
}

// ---------------- fused per-edge mean + per-incidence MLP (f32, CSR-order writes) ----------------
__global__ void edge_logit_kernel(const unsigned int* __restrict__ vbucket,
                                  const unsigned int* __restrict__ edge_off,
                                  const unsigned int* __restrict__ edge_cnt,
                                  const float* __restrict__ p_ab,
                                  const float* __restrict__ b1, const float* __restrict__ W2,
                                  const float* __restrict__ b2,
                                  float* __restrict__ probs_b, float* __restrict__ o_ep) {
    int e = blockIdx.x * 4 + (threadIdx.x >> 6);
    if (e >= N_EDGES) return;
    int lane = threadIdx.x & 63;
    int k    = lane & 31;
    unsigned int half = (unsigned int)(lane >> 5);

    unsigned int off = edge_off[e];
    unsigned int deg = edge_cnt[e];

    float aval[MAXU];
    float bacc = 0.f;

    #pragma unroll
    for (int idx = 0; idx < MAXU; ++idx) {
        unsigned int i = half + 2u * (unsigned int)idx;
        if (i < deg) {
            unsigned int v = vbucket[off + i];
            const float* row = p_ab + (size_t)v * 64u;
            aval[idx] = row[k];
            bacc     += row[32 + k];
        }
    }
    if (deg > 2u * MAXU) {
        for (unsigned int i = half + 2u * MAXU; i < deg; i += 2u) {
            unsigned int v = vbucket[off + i];
            bacc += p_ab[(size_t)v * 64u + 32u + k];
        }
    }

    float cc  = (float)(deg > 1u ? deg : 1u);
    float emk = (bacc + __shfl_xor(bacc, 32)) / cc + b1[k];
    float w2k = W2[k];
    float b2v = b2[0];
    float epsum = 0.f;

    #pragma unroll
    for (int idx = 0; idx < MAXU; ++idx) {
        unsigned int i = half + 2u * (unsigned int)idx;
        if (i < deg) {
            float hk = aval[idx] + emk;
            hk = hk > 0.f ? hk : 0.f;
            float t = hk * w2k;
            #pragma unroll
            for (int o = 16; o > 0; o >>= 1) t += __shfl_down(t, o, 32);
            if (k == 0) {
                float pr = 1.f / (1.f + __expf(-(t + b2v)));
                probs_b[off + i] = pr;
                epsum += pr;
            }
        }
    }
    if (deg > 2u * MAXU) {
        for (unsigned int i = half + 2u * MAXU; i < deg; i += 2u) {
            unsigned int v = vbucket[off + i];
            float hk = p_ab[(size_t)v * 64u + k] + emk;
            hk = hk > 0.f ? hk : 0.f;
            float t = hk * w2k;
            #pragma unroll
            for (int o = 16; o > 0; o >>= 1) t += __shfl_down(t, o, 32);
            if (k == 0) {
                float pr = 1.f / (1.f + __expf(-(t + b2v)));
                probs_b[off + i] = pr;
                epsum += pr;
            }
        }
    }
    float etot = epsum + __shfl_xor(epsum, 32);
    if (lane == 0) o_ep[e] = etot / cc;
}

// ---------------- 2-level radix histogram on f32 keys ----------------
__global__ void hist1_kernel(const float* __restrict__ probs_b, unsigned int* __restrict__ hist) {
    __shared__ unsigned int lh[2048];
    for (int t = threadIdx.x; t < 2048; t += 256) lh[t] = 0;
    __syncthreads();
    for (unsigned int i = blockIdx.x * 256 + threadIdx.x; i < NNZ; i += gridDim.x * 256) {
        unsigned int key = __float_as_uint(probs_b[i]);
        atomicAdd(&lh[key >> 21], 1u);
    }
    __syncthreads();
    for (int t = threadIdx.x; t < 2048; t += 256)
        if (lh[t]) atomicAdd(&hist[t], lh[t]);
}

__global__ void hist2_kernel(const float* __restrict__ probs_b, const SelState* __restrict__ st,
                             unsigned int* __restrict__ hist) {
    __shared__ unsigned int lh[2048];
    for (int t = threadIdx.x; t < 2048; t += 256) lh[t] = 0;
    __syncthreads();
    unsigned int B1 = st->B1;
    for (unsigned int i = blockIdx.x * 256 + threadIdx.x; i < NNZ; i += gridDim.x * 256) {
        unsigned int key = __float_as_uint(probs_b[i]);
        if ((key >> 21) == B1) atomicAdd(&lh[(key >> 10) & 2047u], 1u);
    }
    __syncthreads();
    for (int t = threadIdx.x; t < 2048; t += 256)
        if (lh[t]) atomicAdd(&hist[2048 + t], lh[t]);
}

// which=0: select bucket B1 at rank K_KEEP; which=1: select B2 at rank rem1, set band edges
__global__ void scan_sel_kernel(const unsigned int* __restrict__ hist, SelState* __restrict__ st, int which) {
    __shared__ unsigned int csum[256];
    int t = threadIdx.x;
    unsigned int target = (which == 0) ? (unsigned int)K_KEEP : st->rem1;
    const unsigned int* h = hist + (which ? 2048 : 0);
    unsigned int b[8];
    unsigned int s = 0;
    #pragma unroll
    for (int i = 0; i < 8; ++i) { b[i] = h[t * 8 + i]; s += b[i]; }
    csum[t] = s;
    __syncthreads();
    for (int off = 1; off < 256; off <<= 1) {
        unsigned int v = (t + off < 256) ? csum[t + off] : 0u;
        __syncthreads();
        csum[t] += v;
        __syncthreads();
    }
    unsigned int above = csum[t] - s;       // sum over chunks > t
    if (above < target && target <= above + s) {
        unsigned int rem = target - above;
        unsigned int cum = 0;
        #pragma unroll
        for (int i = 7; i >= 0; --i) {
            if (rem <= cum + b[i]) {
                unsigned int bin = (unsigned int)(t * 8 + i);
                if (which == 0) { st->B1 = bin; st->rem1 = rem - cum; }
                else {
                    unsigned int P = (st->B1 << 21) | (bin << 10);
                    st->lo_edge = __uint_as_float(P) - DELTA;
                    st->hi_edge = __uint_as_float(P + 1024u) + DELTA;
                }
                break;
            }
            cum += b[i];
        }
    }
}

// grid-stride: count n_hi (block-reduced, 1 atomic/block); flag band members [lo,hi]
__global__ void band_kernel(const float* __restrict__ probs_b, SelState* __restrict__ st,
                            unsigned char* __restrict__ flag) {
    __shared__ unsigned int cnt_s;
    if (threadIdx.x == 0) cnt_s = 0;
    __syncthreads();
    float hi = st->hi_edge, lo = st->lo_edge;
    unsigned int local = 0;
    for (unsigned int p = blockIdx.x * 256 + threadIdx.x; p < NNZ; p += gridDim.x * 256) {
        float pk = probs_b[p];
        if (pk > hi) local++;
        else if (pk >= lo) flag[p] = 1;
    }
    #pragma unroll
    for (int o = 32; o > 0; o >>= 1) local += __shfl_down(local, o);
    if ((threadIdx.x & 63) == 0 && local) atomicAdd(&cnt_s, local);
    __syncthreads();
    if (threadIdx.x == 0 && cnt_s) atomicAdd(&st->n_hi, cnt_s);
}

// append (p, j, e, v) for band members (j-order pass; e,v read coalesced from E,V)
__global__ void bandj_kernel(const int* __restrict__ V, const int* __restrict__ E,
                             const unsigned int* __restrict__ pos, const unsigned char* __restrict__ flag,
                             SelState* __restrict__ st,
                             unsigned int* __restrict__ band_p, unsigned int* __restrict__ band_j,
                             unsigned int* __restrict__ band_e, unsigned int* __restrict__ band_v) {
    unsigned int j = blockIdx.x * 256 + threadIdx.x;
    if (j >= NNZ) return;
    unsigned int p = pos[j];
    if (flag[p] == 1u) {
        unsigned int s = atomicAdd(&st->band_n, 1u);
        if (s < BANDCAP) {
            band_p[s] = p;
            band_j[s] = j;
            band_e[s] = (unsigned int)E[j];
            band_v[s] = (unsigned int)V[j];
        }
    }
}

// exact f64 recompute for band members; W1 staged in LDS, no binary search
__global__ void rescue_kernel(const unsigned int* __restrict__ vbucket,
                              const unsigned int* __restrict__ edge_off,
                              const unsigned int* __restrict__ edge_cnt,
                              const float* __restrict__ x, const float* __restrict__ W1,
                              const float* __restrict__ b1, const float* __restrict__ W2,
                              const float* __restrict__ b2,
                              const unsigned int* __restrict__ band_e,
                              const unsigned int* __restrict__ band_v,
                              const SelState* __restrict__ st,
                              unsigned long long* __restrict__ band_key) {
    unsigned int n = st->band_n; if (n > BANDCAP) n = BANDCAP;
    if (blockIdx.x * 8 >= n) return;
    __shared__ float sW[128 * 32];
    for (int t = threadIdx.x; t < 128 * 32; t += 256) sW[t] = W1[t];
    __syncthreads();
    unsigned int g = blockIdx.x * 8 + (threadIdx.x >> 5);
    if (g >= n) return;
    int k = threadIdx.x & 31;
    unsigned int v = band_v[g];
    unsigned int e = band_e[g];
    unsigned int off = edge_off[e];
    unsigned int deg = edge_cnt[e];

    const float* xv = x + (size_t)v * 64u;
    double a = 0.0;
    #pragma unroll 8
    for (int d = 0; d < 64; ++d) a += (double)xv[d] * (double)sW[d * 32 + k];
    double bsum = 0.0;
    for (unsigned int m = off; m < off + deg; ++m) {
        const float* xm = x + (size_t)vbucket[m] * 64u;
        double acc = 0.0;
        #pragma unroll 8
        for (int d = 0; d < 64; ++d) acc += (double)xm[d] * (double)sW[(64 + d) * 32 + k];
        bsum += acc;
    }
    double cc = (double)(deg > 1u ? deg : 1u);
    double h = a + bsum / cc + (double)b1[k];
    h = h > 0.0 ? h : 0.0;
    double t = h * (double)W2[k];
    #pragma unroll
    for (int o = 16; o > 0; o >>= 1) t += __shfl_down(t, o, 32);
    if (k == 0) {
        double pr = 1.0 / (1.0 + exp(-(t + (double)b2[0])));
        band_key[g] = (unsigned long long)__double_as_longlong(pr);
    }
}

// ---------------- throughput-bound rank count ----------------
// grid = 64 i-groups x 8 q-slots; each thread owns 4 i-elements in registers;
// q-tiles staged in LDS (keys only), fixed 2048-trip padded inner loop.
#define RT 2048
__global__ void rank_count_kernel(const unsigned long long* __restrict__ band_key,
                                  const SelState* __restrict__ st,
                                  unsigned int* __restrict__ rank_gt, unsigned int* __restrict__ rank_eq) {
    __shared__ unsigned long long sk[RT];   // 16 KB
    unsigned int n = st->band_n; if (n > BANDCAP) n = BANDCAP;
    unsigned int ig = blockIdx.x & 63u;     // i-group
    unsigned int qs = blockIdx.x >> 6;      // q-slot 0..7
    unsigned int i0 = ig * 1024u + threadIdx.x;
    unsigned long long ki[4];
    unsigned int rgt[4] = {0, 0, 0, 0}, req[4] = {0, 0, 0, 0};
    #pragma unroll
    for (int c = 0; c < 4; ++c) {
        unsigned int i = i0 + 256u * c;
        ki[c] = (i < n) ? band_key[i] : ~0ull;
    }
    unsigned int ntiles = (n + RT - 1) / RT;
    for (unsigned int t = qs; t < ntiles; t += 8u) {
        unsigned int base = t * RT;
        unsigned int m = n - base; if (m > RT) m = RT;
        for (unsigned int s = threadIdx.x; s < RT; s += 256)
            sk[s] = (s < m) ? band_key[base + s] : 0ull;   // pad 0: never >, never ==
        __syncthreads();
        #pragma unroll 8
        for (unsigned int q = 0; q < RT; ++q) {
            unsigned long long kq = sk[q];
            #pragma unroll
            for (int c = 0; c < 4; ++c) {
                rgt[c] += (kq > ki[c]) ? 1u : 0u;
                req[c] += (kq == ki[c]) ? 1u : 0u;
            }
        }
        __syncthreads();
    }
    #pragma unroll
    for (int c = 0; c < 4; ++c) {
        unsigned int i = i0 + 256u * c;
        if (i < n) {
            if (rgt[c]) atomicAdd(&rank_gt[i], rgt[c]);
            if (req[c]) atomicAdd(&rank_eq[i], req[c]);
        }
    }
}

// final selection: rank_final = rgt + (#key-equal with smaller j); slow path only for
// an eq-class straddling the boundary (requires exact-duplicate f64 keys there).
__global__ void mark_kernel(const unsigned long long* __restrict__ band_key,
                            const unsigned int* __restrict__ band_j,
                            const unsigned int* __restrict__ band_p,
                            const unsigned int* __restrict__ rank_gt,
                            const unsigned int* __restrict__ rank_eq,
                            const SelState* __restrict__ st, unsigned char* __restrict__ flag) {
    unsigned int n = st->band_n; if (n > BANDCAP) n = BANDCAP;
    unsigned int need = (unsigned int)K_KEEP - st->n_hi;
    unsigned int i = blockIdx.x * 256 + threadIdx.x;
    if (i >= n) return;
    unsigned int rgt = rank_gt[i];
    if (rgt >= need) return;
    unsigned int req = rank_eq[i];          // includes self
    if (rgt + req <= need) { flag[band_p[i]] = 2u; return; }
    // straddling tie class: exact rank via j tie-break
    unsigned long long ki = band_key[i];
    unsigned int ji = band_j[i];
    unsigned int c = 0;
    for (unsigned int q = 0; q < n; ++q)
        if (band_key[q] == ki && band_j[q] < ji) c++;
    if (rgt + c < need) flag[band_p[i]] = 2u;
}

// p-order: hard decision
__global__ void hard_kernel(const float* __restrict__ probs_b, const unsigned char* __restrict__ flag,
                            const SelState* __restrict__ st, unsigned char* __restrict__ hardbit) {
    unsigned int p = blockIdx.x * 256 + threadIdx.x;
    if (p >= NNZ) return;
    hardbit[p] = (probs_b[p] > st->hi_edge || flag[p] == 2u) ? 1u : 0u;
}

// j-order coalesced outputs
__global__ void out_kernel(const float* __restrict__ probs_b, const unsigned char* __restrict__ hardbit,
                           const unsigned int* __restrict__ pos,
                           float* __restrict__ o_probs, float* __restrict__ o_soft, float* __restrict__ o_hard) {
    unsigned int j = blockIdx.x * 256 + threadIdx.x;
    if (j >= NNZ) return;
    unsigned int p = pos[j];
    float pk = probs_b[p];
    float hb = (float)hardbit[p];
    o_probs[j] = pk;
    o_soft[j]  = hb;
    o_hard[j]  = hb;
}

// per-edge: edge_soft / edge_hard from hard bits
__global__ void edge_out_kernel(const unsigned char* __restrict__ hardbit,
                                const unsigned int* __restrict__ edge_off,
                                const unsigned int* __restrict__ edge_cnt,
                                float* __restrict__ o_es, float* __restrict__ o_eh) {
    unsigned int e = blockIdx.x * 256 + threadIdx.x;
    if (e >= N_EDGES) return;
    unsigned int off = edge_off[e], deg = edge_cnt[e];
    unsigned int cnt = 0;
    for (unsigned int i = 0; i < deg; ++i) cnt += hardbit[off + i];
    float cc = (float)(deg > 1u ? deg : 1u);
    o_es[e] = (float)cnt / cc;
    o_eh[e] = cnt ? 1.f : 0.f;
}

extern "C" void kernel_launch(void* const* d_in, const int* in_sizes, int n_in,
                              void* d_out, int out_size, void* d_ws, size_t ws_size,
                              hipStream_t stream) {
    const float* x  = (const float*)d_in[0];
    const int*   V  = (const int*)d_in[1];
    const int*   E  = (const int*)d_in[2];
    const float* W1 = (const float*)d_in[3];
    const float* b1 = (const float*)d_in[4];
    const float* W2 = (const float*)d_in[5];
    const float* b2 = (const float*)d_in[6];

    float* out     = (float*)d_out;
    float* o_probs = out;
    float* o_soft  = out + NNZ;
    float* o_hard  = out + 2 * (size_t)NNZ;
    float* o_ep    = out + 3 * (size_t)NNZ;
    float* o_es    = out + 3 * (size_t)NNZ + N_EDGES;
    float* o_eh    = out + 3 * (size_t)NNZ + 2 * (size_t)N_EDGES;

    char* w = (char*)d_ws;
    float*              p_ab     = (float*)(w + OFF_PAB);
    float*              probs_b  = (float*)(w + OFF_PB32);
    unsigned int*       vbucket  = (unsigned int*)(w + OFF_VB);
    unsigned int*       pos      = (unsigned int*)(w + OFF_POS);
    unsigned char*      hardbit  = (unsigned char*)(w + OFF_HB);
    unsigned int*       edge_off = (unsigned int*)(w + OFF_EOFF);
    unsigned int*       cursor   = (unsigned int*)(w + OFF_CUR);
    unsigned int*       bsums    = (unsigned int*)(w + OFF_BS);
    unsigned int*       band_p   = (unsigned int*)(w + OFF_BANDP);
    unsigned int*       band_j   = (unsigned int*)(w + OFF_BANDJ);
    unsigned int*       band_e   = (unsigned int*)(w + OFF_BANDE);
    unsigned int*       band_v   = (unsigned int*)(w + OFF_BANDV);
    unsigned long long* band_key = (unsigned long long*)(w + OFF_BANDK);
    unsigned char*      flag     = (unsigned char*)(w + OFF_FLAG);
    unsigned int*       edge_cnt = (unsigned int*)(w + OFF_ECNT);
    unsigned int*       hist     = (unsigned int*)(w + OFF_HIST);
    SelState*           st       = (SelState*)(w + OFF_ST);
    unsigned int*       rank_gt  = (unsigned int*)(w + OFF_RGT);
    unsigned int*       rank_eq  = (unsigned int*)(w + OFF_REQ);

    hipMemsetAsync(w + ZERO_OFF, 0, ZERO_LEN, stream);

    proj_kernel<<<(N_NODES + 7) / 8, 256, 0, stream>>>(x, W1, p_ab);

    count_kernel<<<(NNZ + 255) / 256, 256, 0, stream>>>(E, edge_cnt);
    scanA_kernel<<<SCAN_BLOCKS, 256, 0, stream>>>(edge_cnt, edge_off, bsums);
    scanB_kernel<<<1, 256, 0, stream>>>(bsums);
    scanC_kernel<<<(N_EDGES + 255) / 256, 256, 0, stream>>>(edge_off, bsums, cursor);
    bucket_kernel<<<(NNZ + 255) / 256, 256, 0, stream>>>(V, E, cursor, vbucket, pos);

    edge_logit_kernel<<<(N_EDGES + 3) / 4, 256, 0, stream>>>(vbucket, edge_off, edge_cnt,
                                                             p_ab, b1, W2, b2, probs_b, o_ep);

    hist1_kernel<<<1024, 256, 0, stream>>>(probs_b, hist);
    scan_sel_kernel<<<1, 256, 0, stream>>>(hist, st, 0);
    hist2_kernel<<<1024, 256, 0, stream>>>(probs_b, st, hist);
    scan_sel_kernel<<<1, 256, 0, stream>>>(hist, st, 1);

    band_kernel<<<1024, 256, 0, stream>>>(probs_b, st, flag);
    bandj_kernel<<<(NNZ + 255) / 256, 256, 0, stream>>>(V, E, pos, flag, st,
                                                        band_p, band_j, band_e, band_v);
    rescue_kernel<<<BANDCAP / 8, 256, 0, stream>>>(vbucket, edge_off, edge_cnt, x, W1, b1, W2, b2,
                                                   band_e, band_v, st, band_key);
    rank_count_kernel<<<512, 256, 0, stream>>>(band_key, st, rank_gt, rank_eq);
    mark_kernel<<<BANDCAP / 256, 256, 0, stream>>>(band_key, band_j, band_p,
                                                   rank_gt, rank_eq, st, flag);

    hard_kernel<<<(NNZ + 255) / 256, 256, 0, stream>>>(probs_b, flag, st, hardbit);
    out_kernel<<<(NNZ + 255) / 256, 256, 0, stream>>>(probs_b, hardbit, pos, o_probs, o_soft, o_hard);
    edge_out_kernel<<<(N_EDGES + 255) / 256, 256, 0, stream>>>(hardbit, edge_off, edge_cnt, o_es, o_eh);
}

// Round 7
// 952.021 us; speedup vs baseline: 3.8511x; 1.2027x over previous
//
#include <hip/hip_runtime.h>
#include <math.h>

#define N_NODES   100000
#define N_EDGES   200000
#define NNZ       2000000
#define K_KEEP    1000000
#define BANDCAP   131072
#define TIECAP    4096
#define DELTA     1.0e-3f
#define SCAN_BLOCKS 196   // ceil(200000/1024)
#define MAXU 16           // f32 register stash per half-lane: covers deg <= 32
#define USCALE (4294967296.0 / 4.0e-3)   // band key -> u32 map; band width < 4e-3 guaranteed

// ---------------- workspace layout (bytes) ----------------
#define OFF_PAB   ((size_t)0)          // f32 p_ab [N_NODES*64]   25,600,000 (row: a[0..31]|b[32..63])
#define OFF_PB32  ((size_t)25600000)   // f32 probs_b [NNZ]        8,000,000 (CSR/p-order probs)
#define OFF_VB    ((size_t)33600000)   // u32 vbucket [NNZ]        8,000,000
#define OFF_POS   ((size_t)41600000)   // u32 pos [NNZ] j->p       8,000,000
#define OFF_HB    ((size_t)49600000)   // u8  hardbit [NNZ]        2,000,000 (p-order)
#define OFF_EOFF  ((size_t)51600000)   // u32 edge_off [N_EDGES]     800,000
#define OFF_CUR   ((size_t)52400000)   // u32 cursor [N_EDGES]       800,000
#define OFF_BS    ((size_t)53200000)   // u32 bsums [256]              1,024
#define OFF_BANDP ((size_t)53201024)   // u32 band_p [BANDCAP]       524,288
#define OFF_BANDJ ((size_t)53725312)   // u32 band_j [BANDCAP]       524,288
#define OFF_BANDE ((size_t)54249600)   // u32 band_e [BANDCAP]       524,288
#define OFF_BANDV ((size_t)54773888)   // u32 band_v [BANDCAP]       524,288
#define OFF_BANDK ((size_t)55298176)   // u64 band_key [BANDCAP]   1,048,576
#define OFF_TIEK  ((size_t)56346752)   // u64 tie_k [TIECAP]          32,768
#define OFF_TIEJ  ((size_t)56379520)   // u32 tie_j [TIECAP]          16,384
#define OFF_TIEP  ((size_t)56395904)   // u32 tie_p [TIECAP]          16,384
// --- zero region ---
#define OFF_FLAG  ((size_t)56412288)   // u8  flag [NNZ]           2,000,000 (0 none,1 band,2 selected)
#define OFF_ECNT  ((size_t)58412288)   // u32 edge_cnt [N_EDGES]     800,000
#define OFF_HIST  ((size_t)59212288)   // u32 hist [4*2048]           32,768
#define OFF_ST    ((size_t)59245056)   // SelState                        64
#define ZERO_OFF  OFF_FLAG
#define ZERO_LEN  ((size_t)(59245120 - 56412288))

struct SelState {
    unsigned int B1;        // f32 pass-1 bucket
    unsigned int rem1;      // remaining rank within B1
    float lo_edge, hi_edge; // band boundaries
    unsigned int n_hi;      // count of f32 probs > hi_edge
    unsigned int band_n;    // band append counter
    unsigned int bB1;       // band-select pass-1 bucket (u32 map, bits 31:21)
    unsigned int brem1;     // remaining rank within bB1
    unsigned int bU0;       // threshold u-bucket base (width 1024)
    unsigned int brem2;     // remaining rank within the u-bucket
    unsigned int tie_n;     // tie-bucket append counter
};

__device__ __forceinline__ unsigned int band_u32(double key, float lo) {
    double t = (key - (double)lo) * USCALE;
    t = t < 0.0 ? 0.0 : (t > 4294967295.0 ? 4294967295.0 : t);
    return (unsigned int)t;   // monotone non-decreasing in key
}

// p_ab[v][k] = sum_d x[v][d]*W1[d][k];  p_ab[v][32+k] = sum_d x[v][d]*W1[64+d][k]
__global__ void proj_kernel(const float* __restrict__ x, const float* __restrict__ W1,
                            float* __restrict__ p_ab) {
    __shared__ float sW[128 * 32];
    __shared__ float sx[8][64];
    for (int t = threadIdx.x; t < 128 * 32; t += 256) sW[t] = W1[t];
    int base = blockIdx.x * 8;
    for (int t = threadIdx.x; t < 512; t += 256) {
        int n = t >> 6, d = t & 63;
        int g = base + n;
        sx[n][d] = (g < N_NODES) ? x[(size_t)g * 64 + d] : 0.f;
    }
    __syncthreads();
    int ln = threadIdx.x >> 5;
    int k  = threadIdx.x & 31;
    int node = base + ln;
    if (node >= N_NODES) return;
    float sa = 0.f, sb = 0.f;
    for (int d = 0; d < 64; ++d) {
        float xv = sx[ln][d];
        sa += xv * sW[d * 32 + k];
        sb += xv * sW[(64 + d) * 32 + k];
    }
    p_ab[(size_t)node * 64 + k]      = sa;
    p_ab[(size_t)node * 64 + 32 + k] = sb;
}

// ---------------- CSR build ----------------
__global__ void count_kernel(const int* __restrict__ E, unsigned int* __restrict__ edge_cnt) {
    int j = blockIdx.x * 256 + threadIdx.x;
    if (j >= NNZ) return;
    atomicAdd(&edge_cnt[E[j]], 1u);
}

__global__ void scanA_kernel(const unsigned int* __restrict__ edge_cnt,
                             unsigned int* __restrict__ edge_off, unsigned int* __restrict__ bsums) {
    __shared__ unsigned int s[256];
    int tid = threadIdx.x;
    int base = blockIdx.x * 1024 + tid * 4;
    unsigned int v0 = (base + 0 < N_EDGES) ? edge_cnt[base + 0] : 0u;
    unsigned int v1 = (base + 1 < N_EDGES) ? edge_cnt[base + 1] : 0u;
    unsigned int v2 = (base + 2 < N_EDGES) ? edge_cnt[base + 2] : 0u;
    unsigned int v3 = (base + 3 < N_EDGES) ? edge_cnt[base + 3] : 0u;
    unsigned int tsum = v0 + v1 + v2 + v3;
    s[tid] = tsum;
    __syncthreads();
    for (int off = 1; off < 256; off <<= 1) {
        unsigned int t = (tid >= off) ? s[tid - off] : 0u;
        __syncthreads();
        s[tid] += t;
        __syncthreads();
    }
    unsigned int excl = s[tid] - tsum;
    if (base + 0 < N_EDGES) edge_off[base + 0] = excl;
    if (base + 1 < N_EDGES) edge_off[base + 1] = excl + v0;
    if (base + 2 < N_EDGES) edge_off[base + 2] = excl + v0 + v1;
    if (base + 3 < N_EDGES) edge_off[base + 3] = excl + v0 + v1 + v2;
    if (tid == 255) bsums[blockIdx.x] = s[255];
}

__global__ void scanB_kernel(unsigned int* __restrict__ bsums) {
    __shared__ unsigned int s[256];
    int tid = threadIdx.x;
    unsigned int v = (tid < SCAN_BLOCKS) ? bsums[tid] : 0u;
    s[tid] = v;
    __syncthreads();
    for (int off = 1; off < 256; off <<= 1) {
        unsigned int t = (tid >= off) ? s[tid - off] : 0u;
        __syncthreads();
        s[tid] += t;
        __syncthreads();
    }
    if (tid < SCAN_BLOCKS) bsums[tid] = s[tid] - v;
}

__global__ void scanC_kernel(unsigned int* __restrict__ edge_off, const unsigned int* __restrict__ bsums,
                             unsigned int* __restrict__ cursor) {
    int i = blockIdx.x * 256 + threadIdx.x;
    if (i >= N_EDGES) return;
    unsigned int o = edge_off[i] + bsums[i >> 10];
    edge_off[i] = o;
    cursor[i] = o;
}

__global__ void bucket_kernel(const int* __restrict__ V, const int* __restrict__ E,
                              unsigned int* __restrict__ cursor,
                              unsigned int* __restrict__ vbucket, unsigned int* __restrict__ pos) {
    int j = blockIdx.x * 256 + threadIdx.x;
    if (j >= NNZ) return;
    int e = E[j];
    unsigned int p = atomicAdd(&cursor[e], 1u);
    vbucket[p] = (unsigned int)V[j];
    pos[j] = p;
}

// ---------------- fused per-edge mean + per-incidence MLP (f32, CSR-order writes) ----------------
__global__ void edge_logit_kernel(const unsigned int* __restrict__ vbucket,
                                  const unsigned int* __restrict__ edge_off,
                                  const unsigned int* __restrict__ edge_cnt,
                                  const float* __restrict__ p_ab,
                                  const float* __restrict__ b1, const float* __restrict__ W2,
                                  const float* __restrict__ b2,
                                  float* __restrict__ probs_b, float* __restrict__ o_ep) {
    int e = blockIdx.x * 4 + (threadIdx.x >> 6);
    if (e >= N_EDGES) return;
    int lane = threadIdx.x & 63;
    int k    = lane & 31;
    unsigned int half = (unsigned int)(lane >> 5);

    unsigned int off = edge_off[e];
    unsigned int deg = edge_cnt[e];

    float aval[MAXU];
    float bacc = 0.f;

    #pragma unroll
    for (int idx = 0; idx < MAXU; ++idx) {
        unsigned int i = half + 2u * (unsigned int)idx;
        if (i < deg) {
            unsigned int v = vbucket[off + i];
            const float* row = p_ab + (size_t)v * 64u;
            aval[idx] = row[k];
            bacc     += row[32 + k];
        }
    }
    if (deg > 2u * MAXU) {
        for (unsigned int i = half + 2u * MAXU; i < deg; i += 2u) {
            unsigned int v = vbucket[off + i];
            bacc += p_ab[(size_t)v * 64u + 32u + k];
        }
    }

    float cc  = (float)(deg > 1u ? deg : 1u);
    float emk = (bacc + __shfl_xor(bacc, 32)) / cc + b1[k];
    float w2k = W2[k];
    float b2v = b2[0];
    float epsum = 0.f;

    #pragma unroll
    for (int idx = 0; idx < MAXU; ++idx) {
        unsigned int i = half + 2u * (unsigned int)idx;
        if (i < deg) {
            float hk = aval[idx] + emk;
            hk = hk > 0.f ? hk : 0.f;
            float t = hk * w2k;
            #pragma unroll
            for (int o = 16; o > 0; o >>= 1) t += __shfl_down(t, o, 32);
            if (k == 0) {
                float pr = 1.f / (1.f + __expf(-(t + b2v)));
                probs_b[off + i] = pr;
                epsum += pr;
            }
        }
    }
    if (deg > 2u * MAXU) {
        for (unsigned int i = half + 2u * MAXU; i < deg; i += 2u) {
            unsigned int v = vbucket[off + i];
            float hk = p_ab[(size_t)v * 64u + k] + emk;
            hk = hk > 0.f ? hk : 0.f;
            float t = hk * w2k;
            #pragma unroll
            for (int o = 16; o > 0; o >>= 1) t += __shfl_down(t, o, 32);
            if (k == 0) {
                float pr = 1.f / (1.f + __expf(-(t + b2v)));
                probs_b[off + i] = pr;
                epsum += pr;
            }
        }
    }
    float etot = epsum + __shfl_xor(epsum, 32);
    if (lane == 0) o_ep[e] = etot / cc;
}

// ---------------- 2-level radix histogram on f32 keys ----------------
__global__ void hist1_kernel(const float* __restrict__ probs_b, unsigned int* __restrict__ hist) {
    __shared__ unsigned int lh[2048];
    for (int t = threadIdx.x; t < 2048; t += 256) lh[t] = 0;
    __syncthreads();
    for (unsigned int i = blockIdx.x * 256 + threadIdx.x; i < NNZ; i += gridDim.x * 256) {
        unsigned int key = __float_as_uint(probs_b[i]);
        atomicAdd(&lh[key >> 21], 1u);
    }
    __syncthreads();
    for (int t = threadIdx.x; t < 2048; t += 256)
        if (lh[t]) atomicAdd(&hist[t], lh[t]);
}

__global__ void hist2_kernel(const float* __restrict__ probs_b, const SelState* __restrict__ st,
                             unsigned int* __restrict__ hist) {
    __shared__ unsigned int lh[2048];
    for (int t = threadIdx.x; t < 2048; t += 256) lh[t] = 0;
    __syncthreads();
    unsigned int B1 = st->B1;
    for (unsigned int i = blockIdx.x * 256 + threadIdx.x; i < NNZ; i += gridDim.x * 256) {
        unsigned int key = __float_as_uint(probs_b[i]);
        if ((key >> 21) == B1) atomicAdd(&lh[(key >> 10) & 2047u], 1u);
    }
    __syncthreads();
    for (int t = threadIdx.x; t < 2048; t += 256)
        if (lh[t]) atomicAdd(&hist[2048 + t], lh[t]);
}

// which=0: select bucket B1 at rank K_KEEP; which=1: select B2 at rank rem1, set band edges
__global__ void scan_sel_kernel(const unsigned int* __restrict__ hist, SelState* __restrict__ st, int which) {
    __shared__ unsigned int csum[256];
    int t = threadIdx.x;
    unsigned int target = (which == 0) ? (unsigned int)K_KEEP : st->rem1;
    const unsigned int* h = hist + (which ? 2048 : 0);
    unsigned int b[8];
    unsigned int s = 0;
    #pragma unroll
    for (int i = 0; i < 8; ++i) { b[i] = h[t * 8 + i]; s += b[i]; }
    csum[t] = s;
    __syncthreads();
    for (int off = 1; off < 256; off <<= 1) {
        unsigned int v = (t + off < 256) ? csum[t + off] : 0u;
        __syncthreads();
        csum[t] += v;
        __syncthreads();
    }
    unsigned int above = csum[t] - s;       // sum over chunks > t
    if (above < target && target <= above + s) {
        unsigned int rem = target - above;
        unsigned int cum = 0;
        #pragma unroll
        for (int i = 7; i >= 0; --i) {
            if (rem <= cum + b[i]) {
                unsigned int bin = (unsigned int)(t * 8 + i);
                if (which == 0) { st->B1 = bin; st->rem1 = rem - cum; }
                else {
                    unsigned int P = (st->B1 << 21) | (bin << 10);
                    st->lo_edge = __uint_as_float(P) - DELTA;
                    st->hi_edge = __uint_as_float(P + 1024u) + DELTA;
                }
                break;
            }
            cum += b[i];
        }
    }
}

// grid-stride: count n_hi (block-reduced, 1 atomic/block); flag band members [lo,hi]
__global__ void band_kernel(const float* __restrict__ probs_b, SelState* __restrict__ st,
                            unsigned char* __restrict__ flag) {
    __shared__ unsigned int cnt_s;
    if (threadIdx.x == 0) cnt_s = 0;
    __syncthreads();
    float hi = st->hi_edge, lo = st->lo_edge;
    unsigned int local = 0;
    for (unsigned int p = blockIdx.x * 256 + threadIdx.x; p < NNZ; p += gridDim.x * 256) {
        float pk = probs_b[p];
        if (pk > hi) local++;
        else if (pk >= lo) flag[p] = 1;
    }
    #pragma unroll
    for (int o = 32; o > 0; o >>= 1) local += __shfl_down(local, o);
    if ((threadIdx.x & 63) == 0 && local) atomicAdd(&cnt_s, local);
    __syncthreads();
    if (threadIdx.x == 0 && cnt_s) atomicAdd(&st->n_hi, cnt_s);
}

// append (p, j, e, v) for band members (j-order pass; e,v read coalesced from E,V)
__global__ void bandj_kernel(const int* __restrict__ V, const int* __restrict__ E,
                             const unsigned int* __restrict__ pos, const unsigned char* __restrict__ flag,
                             SelState* __restrict__ st,
                             unsigned int* __restrict__ band_p, unsigned int* __restrict__ band_j,
                             unsigned int* __restrict__ band_e, unsigned int* __restrict__ band_v) {
    unsigned int j = blockIdx.x * 256 + threadIdx.x;
    if (j >= NNZ) return;
    unsigned int p = pos[j];
    if (flag[p] == 1u) {
        unsigned int s = atomicAdd(&st->band_n, 1u);
        if (s < BANDCAP) {
            band_p[s] = p;
            band_j[s] = j;
            band_e[s] = (unsigned int)E[j];
            band_v[s] = (unsigned int)V[j];
        }
    }
}

// exact f64 recompute for band members; W1 staged in LDS
__global__ void rescue_kernel(const unsigned int* __restrict__ vbucket,
                              const unsigned int* __restrict__ edge_off,
                              const unsigned int* __restrict__ edge_cnt,
                              const float* __restrict__ x, const float* __restrict__ W1,
                              const float* __restrict__ b1, const float* __restrict__ W2,
                              const float* __restrict__ b2,
                              const unsigned int* __restrict__ band_e,
                              const unsigned int* __restrict__ band_v,
                              const SelState* __restrict__ st,
                              unsigned long long* __restrict__ band_key) {
    unsigned int n = st->band_n; if (n > BANDCAP) n = BANDCAP;
    if (blockIdx.x * 8 >= n) return;
    __shared__ float sW[128 * 32];
    for (int t = threadIdx.x; t < 128 * 32; t += 256) sW[t] = W1[t];
    __syncthreads();
    unsigned int g = blockIdx.x * 8 + (threadIdx.x >> 5);
    if (g >= n) return;
    int k = threadIdx.x & 31;
    unsigned int v = band_v[g];
    unsigned int e = band_e[g];
    unsigned int off = edge_off[e];
    unsigned int deg = edge_cnt[e];

    const float* xv = x + (size_t)v * 64u;
    double a = 0.0;
    #pragma unroll 8
    for (int d = 0; d < 64; ++d) a += (double)xv[d] * (double)sW[d * 32 + k];
    double bsum = 0.0;
    for (unsigned int m = off; m < off + deg; ++m) {
        const float* xm = x + (size_t)vbucket[m] * 64u;
        double acc = 0.0;
        #pragma unroll 8
        for (int d = 0; d < 64; ++d) acc += (double)xm[d] * (double)sW[(64 + d) * 32 + k];
        bsum += acc;
    }
    double cc = (double)(deg > 1u ? deg : 1u);
    double h = a + bsum / cc + (double)b1[k];
    h = h > 0.0 ? h : 0.0;
    double t = h * (double)W2[k];
    #pragma unroll
    for (int o = 16; o > 0; o >>= 1) t += __shfl_down(t, o, 32);
    if (k == 0) {
        double pr = 1.0 / (1.0 + exp(-(t + (double)b2[0])));
        band_key[g] = (unsigned long long)__double_as_longlong(pr);
    }
}

// ---------------- O(n) band selection: 2-level hist on monotone u32 map ----------------
__global__ void bhist1_kernel(const unsigned long long* __restrict__ band_key,
                              const SelState* __restrict__ st, unsigned int* __restrict__ hist) {
    __shared__ unsigned int lh[2048];
    for (int t = threadIdx.x; t < 2048; t += 256) lh[t] = 0;
    __syncthreads();
    unsigned int n = st->band_n; if (n > BANDCAP) n = BANDCAP;
    float lo = st->lo_edge;
    for (unsigned int i = blockIdx.x * 256 + threadIdx.x; i < n; i += gridDim.x * 256) {
        unsigned int u = band_u32(__longlong_as_double((long long)band_key[i]), lo);
        atomicAdd(&lh[u >> 21], 1u);
    }
    __syncthreads();
    for (int t = threadIdx.x; t < 2048; t += 256)
        if (lh[t]) atomicAdd(&hist[4096 + t], lh[t]);
}

__global__ void bhist2_kernel(const unsigned long long* __restrict__ band_key,
                              const SelState* __restrict__ st, unsigned int* __restrict__ hist) {
    __shared__ unsigned int lh[2048];
    for (int t = threadIdx.x; t < 2048; t += 256) lh[t] = 0;
    __syncthreads();
    unsigned int n = st->band_n; if (n > BANDCAP) n = BANDCAP;
    float lo = st->lo_edge;
    unsigned int bB1 = st->bB1;
    for (unsigned int i = blockIdx.x * 256 + threadIdx.x; i < n; i += gridDim.x * 256) {
        unsigned int u = band_u32(__longlong_as_double((long long)band_key[i]), lo);
        if ((u >> 21) == bB1) atomicAdd(&lh[(u >> 10) & 2047u], 1u);
    }
    __syncthreads();
    for (int t = threadIdx.x; t < 2048; t += 256)
        if (lh[t]) atomicAdd(&hist[6144 + t], lh[t]);
}

// which=0: bucket bB1 at rank (K_KEEP - n_hi); which=1: bucket bB2 at rank brem1 -> bU0, brem2
__global__ void bscan_kernel(const unsigned int* __restrict__ hist, SelState* __restrict__ st, int which) {
    __shared__ unsigned int csum[256];
    int t = threadIdx.x;
    unsigned int target = (which == 0) ? ((unsigned int)K_KEEP - st->n_hi) : st->brem1;
    const unsigned int* h = hist + (which ? 6144 : 4096);
    unsigned int b[8];
    unsigned int s = 0;
    #pragma unroll
    for (int i = 0; i < 8; ++i) { b[i] = h[t * 8 + i]; s += b[i]; }
    csum[t] = s;
    __syncthreads();
    for (int off = 1; off < 256; off <<= 1) {
        unsigned int v = (t + off < 256) ? csum[t + off] : 0u;
        __syncthreads();
        csum[t] += v;
        __syncthreads();
    }
    unsigned int above = csum[t] - s;
    if (above < target && target <= above + s) {
        unsigned int rem = target - above;
        unsigned int cum = 0;
        #pragma unroll
        for (int i = 7; i >= 0; --i) {
            if (rem <= cum + b[i]) {
                unsigned int bin = (unsigned int)(t * 8 + i);
                if (which == 0) { st->bB1 = bin; st->brem1 = rem - cum; }
                else            { st->bU0 = (st->bB1 << 21) | (bin << 10); st->brem2 = rem - cum; }
                break;
            }
            cum += b[i];
        }
    }
}

// mark u >= bU0+1024 selected; collect tie bucket [bU0, bU0+1024)
__global__ void btie_kernel(const unsigned long long* __restrict__ band_key,
                            const unsigned int* __restrict__ band_j,
                            const unsigned int* __restrict__ band_p,
                            SelState* __restrict__ st, unsigned char* __restrict__ flag,
                            unsigned long long* __restrict__ tie_k,
                            unsigned int* __restrict__ tie_j, unsigned int* __restrict__ tie_p) {
    unsigned int n = st->band_n; if (n > BANDCAP) n = BANDCAP;
    unsigned int i = blockIdx.x * 256 + threadIdx.x;
    if (i >= n) return;
    float lo = st->lo_edge;
    unsigned int U0 = st->bU0;
    unsigned long long key = band_key[i];
    unsigned int u = band_u32(__longlong_as_double((long long)key), lo);
    if (u >= U0 + 1024u) {
        flag[band_p[i]] = 2u;
    } else if (u >= U0) {
        unsigned int s = atomicAdd(&st->tie_n, 1u);
        if (s < TIECAP) { tie_k[s] = key; tie_j[s] = band_j[i]; tie_p[s] = band_p[i]; }
    }
}

// exact rank inside the (tiny) tie bucket by (key desc, j asc); take first brem2
__global__ void btierank_kernel(const unsigned long long* __restrict__ tie_k,
                                const unsigned int* __restrict__ tie_j,
                                const unsigned int* __restrict__ tie_p,
                                const SelState* __restrict__ st, unsigned char* __restrict__ flag) {
    unsigned int n = st->tie_n; if (n > TIECAP) n = TIECAP;
    unsigned int need = st->brem2;
    for (unsigned int i = threadIdx.x; i < n; i += 256) {
        unsigned long long ki = tie_k[i];
        unsigned int ji = tie_j[i];
        unsigned int r = 0;
        for (unsigned int q = 0; q < n; ++q) {
            unsigned long long kq = tie_k[q];
            if (kq > ki || (kq == ki && tie_j[q] < ji)) r++;
        }
        if (r < need) flag[tie_p[i]] = 2u;
    }
}

// p-order: hard decision
__global__ void hard_kernel(const float* __restrict__ probs_b, const unsigned char* __restrict__ flag,
                            const SelState* __restrict__ st, unsigned char* __restrict__ hardbit) {
    unsigned int p = blockIdx.x * 256 + threadIdx.x;
    if (p >= NNZ) return;
    hardbit[p] = (probs_b[p] > st->hi_edge || flag[p] == 2u) ? 1u : 0u;
}

// j-order coalesced outputs
__global__ void out_kernel(const float* __restrict__ probs_b, const unsigned char* __restrict__ hardbit,
                           const unsigned int* __restrict__ pos,
                           float* __restrict__ o_probs, float* __restrict__ o_soft, float* __restrict__ o_hard) {
    unsigned int j = blockIdx.x * 256 + threadIdx.x;
    if (j >= NNZ) return;
    unsigned int p = pos[j];
    float pk = probs_b[p];
    float hb = (float)hardbit[p];
    o_probs[j] = pk;
    o_soft[j]  = hb;
    o_hard[j]  = hb;
}

// per-edge: edge_soft / edge_hard from hard bits
__global__ void edge_out_kernel(const unsigned char* __restrict__ hardbit,
                                const unsigned int* __restrict__ edge_off,
                                const unsigned int* __restrict__ edge_cnt,
                                float* __restrict__ o_es, float* __restrict__ o_eh) {
    unsigned int e = blockIdx.x * 256 + threadIdx.x;
    if (e >= N_EDGES) return;
    unsigned int off = edge_off[e], deg = edge_cnt[e];
    unsigned int cnt = 0;
    for (unsigned int i = 0; i < deg; ++i) cnt += hardbit[off + i];
    float cc = (float)(deg > 1u ? deg : 1u);
    o_es[e] = (float)cnt / cc;
    o_eh[e] = cnt ? 1.f : 0.f;
}

extern "C" void kernel_launch(void* const* d_in, const int* in_sizes, int n_in,
                              void* d_out, int out_size, void* d_ws, size_t ws_size,
                              hipStream_t stream) {
    const float* x  = (const float*)d_in[0];
    const int*   V  = (const int*)d_in[1];
    const int*   E  = (const int*)d_in[2];
    const float* W1 = (const float*)d_in[3];
    const float* b1 = (const float*)d_in[4];
    const float* W2 = (const float*)d_in[5];
    const float* b2 = (const float*)d_in[6];

    float* out     = (float*)d_out;
    float* o_probs = out;
    float* o_soft  = out + NNZ;
    float* o_hard  = out + 2 * (size_t)NNZ;
    float* o_ep    = out + 3 * (size_t)NNZ;
    float* o_es    = out + 3 * (size_t)NNZ + N_EDGES;
    float* o_eh    = out + 3 * (size_t)NNZ + 2 * (size_t)N_EDGES;

    char* w = (char*)d_ws;
    float*              p_ab     = (float*)(w + OFF_PAB);
    float*              probs_b  = (float*)(w + OFF_PB32);
    unsigned int*       vbucket  = (unsigned int*)(w + OFF_VB);
    unsigned int*       pos      = (unsigned int*)(w + OFF_POS);
    unsigned char*      hardbit  = (unsigned char*)(w + OFF_HB);
    unsigned int*       edge_off = (unsigned int*)(w + OFF_EOFF);
    unsigned int*       cursor   = (unsigned int*)(w + OFF_CUR);
    unsigned int*       bsums    = (unsigned int*)(w + OFF_BS);
    unsigned int*       band_p   = (unsigned int*)(w + OFF_BANDP);
    unsigned int*       band_j   = (unsigned int*)(w + OFF_BANDJ);
    unsigned int*       band_e   = (unsigned int*)(w + OFF_BANDE);
    unsigned int*       band_v   = (unsigned int*)(w + OFF_BANDV);
    unsigned long long* band_key = (unsigned long long*)(w + OFF_BANDK);
    unsigned long long* tie_k    = (unsigned long long*)(w + OFF_TIEK);
    unsigned int*       tie_j    = (unsigned int*)(w + OFF_TIEJ);
    unsigned int*       tie_p    = (unsigned int*)(w + OFF_TIEP);
    unsigned char*      flag     = (unsigned char*)(w + OFF_FLAG);
    unsigned int*       edge_cnt = (unsigned int*)(w + OFF_ECNT);
    unsigned int*       hist     = (unsigned int*)(w + OFF_HIST);
    SelState*           st       = (SelState*)(w + OFF_ST);

    hipMemsetAsync(w + ZERO_OFF, 0, ZERO_LEN, stream);

    proj_kernel<<<(N_NODES + 7) / 8, 256, 0, stream>>>(x, W1, p_ab);

    count_kernel<<<(NNZ + 255) / 256, 256, 0, stream>>>(E, edge_cnt);
    scanA_kernel<<<SCAN_BLOCKS, 256, 0, stream>>>(edge_cnt, edge_off, bsums);
    scanB_kernel<<<1, 256, 0, stream>>>(bsums);
    scanC_kernel<<<(N_EDGES + 255) / 256, 256, 0, stream>>>(edge_off, bsums, cursor);
    bucket_kernel<<<(NNZ + 255) / 256, 256, 0, stream>>>(V, E, cursor, vbucket, pos);

    edge_logit_kernel<<<(N_EDGES + 3) / 4, 256, 0, stream>>>(vbucket, edge_off, edge_cnt,
                                                             p_ab, b1, W2, b2, probs_b, o_ep);

    hist1_kernel<<<1024, 256, 0, stream>>>(probs_b, hist);
    scan_sel_kernel<<<1, 256, 0, stream>>>(hist, st, 0);
    hist2_kernel<<<1024, 256, 0, stream>>>(probs_b, st, hist);
    scan_sel_kernel<<<1, 256, 0, stream>>>(hist, st, 1);

    band_kernel<<<1024, 256, 0, stream>>>(probs_b, st, flag);
    bandj_kernel<<<(NNZ + 255) / 256, 256, 0, stream>>>(V, E, pos, flag, st,
                                                        band_p, band_j, band_e, band_v);
    rescue_kernel<<<BANDCAP / 8, 256, 0, stream>>>(vbucket, edge_off, edge_cnt, x, W1, b1, W2, b2,
                                                   band_e, band_v, st, band_key);

    bhist1_kernel<<<64, 256, 0, stream>>>(band_key, st, hist);
    bscan_kernel<<<1, 256, 0, stream>>>(hist, st, 0);
    bhist2_kernel<<<64, 256, 0, stream>>>(band_key, st, hist);
    bscan_kernel<<<1, 256, 0, stream>>>(hist, st, 1);
    btie_kernel<<<BANDCAP / 256, 256, 0, stream>>>(band_key, band_j, band_p, st, flag,
                                                   tie_k, tie_j, tie_p);
    btierank_kernel<<<1, 256, 0, stream>>>(tie_k, tie_j, tie_p, st, flag);

    hard_kernel<<<(NNZ + 255) / 256, 256, 0, stream>>>(probs_b, flag, st, hardbit);
    out_kernel<<<(NNZ + 255) / 256, 256, 0, stream>>>(probs_b, hardbit, pos, o_probs, o_soft, o_hard);
    edge_out_kernel<<<(N_EDGES + 255) / 256, 256, 0, stream>>>(hardbit, edge_off, edge_cnt, o_es, o_eh);
}

// Round 8
// 873.135 us; speedup vs baseline: 4.1991x; 1.0903x over previous
//
#include <hip/hip_runtime.h>
#include <math.h>

#define N_NODES   100000
#define N_EDGES   200000
#define NNZ       2000000
#define K_KEEP    1000000
#define BANDCAP   131072
#define TIECAP    4096
#define DELTA     1.0e-3f
#define SCAN_BLOCKS 196   // ceil(200000/1024)
#define USCALE (4294967296.0 / 4.0e-3)   // band key -> u32 map; band width < 4e-3 guaranteed

// ---------------- workspace layout (bytes) ----------------
#define OFF_PAB   ((size_t)0)          // f32 p_ab [N_NODES*64]   25,600,000 (row: a[0..31]|b[32..63])
#define OFF_PB32  ((size_t)25600000)   // f32 probs_b [NNZ]        8,000,000 (CSR/p-order probs)
#define OFF_VB    ((size_t)33600000)   // u32 vbucket [NNZ]        8,000,000
#define OFF_POS   ((size_t)41600000)   // u32 pos [NNZ] j->p       8,000,000
#define OFF_EOFF  ((size_t)51600000)   // u32 edge_off [N_EDGES]     800,000
#define OFF_CUR   ((size_t)52400000)   // u32 cursor [N_EDGES]       800,000
#define OFF_BS    ((size_t)53200000)   // u32 bsums [256]              1,024
#define OFF_BANDP ((size_t)53201024)   // u32 band_p [BANDCAP]       524,288
#define OFF_BANDJ ((size_t)53725312)   // u32 band_j [BANDCAP]       524,288
#define OFF_BANDE ((size_t)54249600)   // u32 band_e [BANDCAP]       524,288
#define OFF_BANDV ((size_t)54773888)   // u32 band_v [BANDCAP]       524,288
#define OFF_BANDK ((size_t)55298176)   // u64 band_key [BANDCAP]   1,048,576
#define OFF_TIEK  ((size_t)56346752)   // u64 tie_k [TIECAP]          32,768
#define OFF_TIEJ  ((size_t)56379520)   // u32 tie_j [TIECAP]          16,384
#define OFF_TIEP  ((size_t)56395904)   // u32 tie_p [TIECAP]          16,384
// --- zero region ---
#define OFF_FLAG  ((size_t)56412288)   // u8  flag [NNZ]           2,000,000 (0 none,1 band,2 selected)
#define OFF_ECNT  ((size_t)58412288)   // u32 edge_cnt [N_EDGES]     800,000
#define OFF_HIST  ((size_t)59212288)   // u32 hist [4*2048]           32,768
#define OFF_ST    ((size_t)59245056)   // SelState                        64
#define ZERO_OFF  OFF_FLAG
#define ZERO_LEN  ((size_t)(59245120 - 56412288))

struct SelState {
    unsigned int B1;        // f32 pass-1 bucket
    unsigned int rem1;      // remaining rank within B1
    float lo_edge, hi_edge; // band boundaries
    unsigned int n_hi;      // count of f32 probs > hi_edge
    unsigned int band_n;    // band append counter
    unsigned int bB1;       // band-select pass-1 bucket (u32 map, bits 31:21)
    unsigned int brem1;     // remaining rank within bB1
    unsigned int bU0;       // threshold u-bucket base (width 1024)
    unsigned int brem2;     // remaining rank within the u-bucket
    unsigned int tie_n;     // tie-bucket append counter
};

__device__ __forceinline__ unsigned int band_u32(double key, float lo) {
    double t = (key - (double)lo) * USCALE;
    t = t < 0.0 ? 0.0 : (t > 4294967295.0 ? 4294967295.0 : t);
    return (unsigned int)t;   // monotone non-decreasing in key
}

// p_ab[v][k] = sum_d x[v][d]*W1[d][k];  p_ab[v][32+k] = sum_d x[v][d]*W1[64+d][k]
__global__ void proj_kernel(const float* __restrict__ x, const float* __restrict__ W1,
                            float* __restrict__ p_ab) {
    __shared__ float sW[128 * 32];
    __shared__ float sx[8][64];
    for (int t = threadIdx.x; t < 128 * 32; t += 256) sW[t] = W1[t];
    int base = blockIdx.x * 8;
    for (int t = threadIdx.x; t < 512; t += 256) {
        int n = t >> 6, d = t & 63;
        int g = base + n;
        sx[n][d] = (g < N_NODES) ? x[(size_t)g * 64 + d] : 0.f;
    }
    __syncthreads();
    int ln = threadIdx.x >> 5;
    int k  = threadIdx.x & 31;
    int node = base + ln;
    if (node >= N_NODES) return;
    float sa = 0.f, sb = 0.f;
    for (int d = 0; d < 64; ++d) {
        float xv = sx[ln][d];
        sa += xv * sW[d * 32 + k];
        sb += xv * sW[(64 + d) * 32 + k];
    }
    p_ab[(size_t)node * 64 + k]      = sa;
    p_ab[(size_t)node * 64 + 32 + k] = sb;
}

// ---------------- CSR build ----------------
__global__ void count_kernel(const int* __restrict__ E, unsigned int* __restrict__ edge_cnt) {
    int j = blockIdx.x * 256 + threadIdx.x;
    if (j >= NNZ) return;
    atomicAdd(&edge_cnt[E[j]], 1u);
}

__global__ void scanA_kernel(const unsigned int* __restrict__ edge_cnt,
                             unsigned int* __restrict__ edge_off, unsigned int* __restrict__ bsums) {
    __shared__ unsigned int s[256];
    int tid = threadIdx.x;
    int base = blockIdx.x * 1024 + tid * 4;
    unsigned int v0 = (base + 0 < N_EDGES) ? edge_cnt[base + 0] : 0u;
    unsigned int v1 = (base + 1 < N_EDGES) ? edge_cnt[base + 1] : 0u;
    unsigned int v2 = (base + 2 < N_EDGES) ? edge_cnt[base + 2] : 0u;
    unsigned int v3 = (base + 3 < N_EDGES) ? edge_cnt[base + 3] : 0u;
    unsigned int tsum = v0 + v1 + v2 + v3;
    s[tid] = tsum;
    __syncthreads();
    for (int off = 1; off < 256; off <<= 1) {
        unsigned int t = (tid >= off) ? s[tid - off] : 0u;
        __syncthreads();
        s[tid] += t;
        __syncthreads();
    }
    unsigned int excl = s[tid] - tsum;
    if (base + 0 < N_EDGES) edge_off[base + 0] = excl;
    if (base + 1 < N_EDGES) edge_off[base + 1] = excl + v0;
    if (base + 2 < N_EDGES) edge_off[base + 2] = excl + v0 + v1;
    if (base + 3 < N_EDGES) edge_off[base + 3] = excl + v0 + v1 + v2;
    if (tid == 255) bsums[blockIdx.x] = s[255];
}

__global__ void scanB_kernel(unsigned int* __restrict__ bsums) {
    __shared__ unsigned int s[256];
    int tid = threadIdx.x;
    unsigned int v = (tid < SCAN_BLOCKS) ? bsums[tid] : 0u;
    s[tid] = v;
    __syncthreads();
    for (int off = 1; off < 256; off <<= 1) {
        unsigned int t = (tid >= off) ? s[tid - off] : 0u;
        __syncthreads();
        s[tid] += t;
        __syncthreads();
    }
    if (tid < SCAN_BLOCKS) bsums[tid] = s[tid] - v;
}

__global__ void scanC_kernel(unsigned int* __restrict__ edge_off, const unsigned int* __restrict__ bsums,
                             unsigned int* __restrict__ cursor) {
    int i = blockIdx.x * 256 + threadIdx.x;
    if (i >= N_EDGES) return;
    unsigned int o = edge_off[i] + bsums[i >> 10];
    edge_off[i] = o;
    cursor[i] = o;
}

__global__ void bucket_kernel(const int* __restrict__ V, const int* __restrict__ E,
                              unsigned int* __restrict__ cursor,
                              unsigned int* __restrict__ vbucket, unsigned int* __restrict__ pos) {
    int j = blockIdx.x * 256 + threadIdx.x;
    if (j >= NNZ) return;
    int e = E[j];
    unsigned int p = atomicAdd(&cursor[e], 1u);
    vbucket[p] = (unsigned int)V[j];
    pos[j] = p;
}

// ---------------- fused per-edge mean + per-incidence MLP (f32, CSR-order writes) ----------------
// one 64-lane wave per edge; half h handles incidences i = h, h+2, ...
// pass 1 (rolled): a-vals -> LDS stash, b-vals accumulated; pass 2 (rolled): MLP + reduce.
__global__ void edge_logit_kernel(const unsigned int* __restrict__ vbucket,
                                  const unsigned int* __restrict__ edge_off,
                                  const unsigned int* __restrict__ edge_cnt,
                                  const float* __restrict__ p_ab,
                                  const float* __restrict__ b1, const float* __restrict__ W2,
                                  const float* __restrict__ b2,
                                  float* __restrict__ probs_b, float* __restrict__ o_ep) {
    __shared__ float sa[4][32 * 32];   // 16 KB: [wave][slot i][k]
    int e = blockIdx.x * 4 + (threadIdx.x >> 6);
    if (e >= N_EDGES) return;
    int w    = threadIdx.x >> 6;
    int lane = threadIdx.x & 63;
    int k    = lane & 31;
    unsigned int half = (unsigned int)(lane >> 5);

    unsigned int off = edge_off[e];
    unsigned int deg = edge_cnt[e];
    unsigned int mind = deg < 32u ? deg : 32u;

    float bacc = 0.f;
    for (unsigned int i = half; i < mind; i += 2u) {
        unsigned int v = vbucket[off + i];
        const float* row = p_ab + (size_t)v * 64u;
        sa[w][i * 32 + k] = row[k];
        bacc += row[32 + k];
    }
    for (unsigned int i = 32u + half; i < deg; i += 2u) {   // deg>32 tail: b only
        unsigned int v = vbucket[off + i];
        bacc += p_ab[(size_t)v * 64u + 32u + k];
    }

    float cc  = (float)(deg > 1u ? deg : 1u);
    float emk = (bacc + __shfl_xor(bacc, 32)) / cc + b1[k];
    float w2k = W2[k];
    float b2v = b2[0];
    float epsum = 0.f;

    for (unsigned int i = half; i < mind; i += 2u) {
        float hk = sa[w][i * 32 + k] + emk;
        hk = hk > 0.f ? hk : 0.f;
        float t = hk * w2k;
        #pragma unroll
        for (int o = 16; o > 0; o >>= 1) t += __shfl_down(t, o, 32);
        if (k == 0) {
            float pr = 1.f / (1.f + __expf(-(t + b2v)));
            probs_b[off + i] = pr;
            epsum += pr;
        }
    }
    for (unsigned int i = 32u + half; i < deg; i += 2u) {   // deg>32 tail: a from global
        unsigned int v = vbucket[off + i];
        float hk = p_ab[(size_t)v * 64u + k] + emk;
        hk = hk > 0.f ? hk : 0.f;
        float t = hk * w2k;
        #pragma unroll
        for (int o = 16; o > 0; o >>= 1) t += __shfl_down(t, o, 32);
        if (k == 0) {
            float pr = 1.f / (1.f + __expf(-(t + b2v)));
            probs_b[off + i] = pr;
            epsum += pr;
        }
    }
    float etot = epsum + __shfl_xor(epsum, 32);
    if (lane == 0) o_ep[e] = etot / cc;
}

// ---------------- 2-level radix histogram on f32 keys ----------------
__global__ void hist1_kernel(const float* __restrict__ probs_b, unsigned int* __restrict__ hist) {
    __shared__ unsigned int lh[2048];
    for (int t = threadIdx.x; t < 2048; t += 256) lh[t] = 0;
    __syncthreads();
    for (unsigned int i = blockIdx.x * 256 + threadIdx.x; i < NNZ; i += gridDim.x * 256) {
        unsigned int key = __float_as_uint(probs_b[i]);
        atomicAdd(&lh[key >> 21], 1u);
    }
    __syncthreads();
    for (int t = threadIdx.x; t < 2048; t += 256)
        if (lh[t]) atomicAdd(&hist[t], lh[t]);
}

__global__ void hist2_kernel(const float* __restrict__ probs_b, const SelState* __restrict__ st,
                             unsigned int* __restrict__ hist) {
    __shared__ unsigned int lh[2048];
    for (int t = threadIdx.x; t < 2048; t += 256) lh[t] = 0;
    __syncthreads();
    unsigned int B1 = st->B1;
    for (unsigned int i = blockIdx.x * 256 + threadIdx.x; i < NNZ; i += gridDim.x * 256) {
        unsigned int key = __float_as_uint(probs_b[i]);
        if ((key >> 21) == B1) atomicAdd(&lh[(key >> 10) & 2047u], 1u);
    }
    __syncthreads();
    for (int t = threadIdx.x; t < 2048; t += 256)
        if (lh[t]) atomicAdd(&hist[2048 + t], lh[t]);
}

// which=0: select bucket B1 at rank K_KEEP; which=1: select B2 at rank rem1, set band edges
__global__ void scan_sel_kernel(const unsigned int* __restrict__ hist, SelState* __restrict__ st, int which) {
    __shared__ unsigned int csum[256];
    int t = threadIdx.x;
    unsigned int target = (which == 0) ? (unsigned int)K_KEEP : st->rem1;
    const unsigned int* h = hist + (which ? 2048 : 0);
    unsigned int b[8];
    unsigned int s = 0;
    #pragma unroll
    for (int i = 0; i < 8; ++i) { b[i] = h[t * 8 + i]; s += b[i]; }
    csum[t] = s;
    __syncthreads();
    for (int off = 1; off < 256; off <<= 1) {
        unsigned int v = (t + off < 256) ? csum[t + off] : 0u;
        __syncthreads();
        csum[t] += v;
        __syncthreads();
    }
    unsigned int above = csum[t] - s;       // sum over chunks > t
    if (above < target && target <= above + s) {
        unsigned int rem = target - above;
        unsigned int cum = 0;
        #pragma unroll
        for (int i = 7; i >= 0; --i) {
            if (rem <= cum + b[i]) {
                unsigned int bin = (unsigned int)(t * 8 + i);
                if (which == 0) { st->B1 = bin; st->rem1 = rem - cum; }
                else {
                    unsigned int P = (st->B1 << 21) | (bin << 10);
                    st->lo_edge = __uint_as_float(P) - DELTA;
                    st->hi_edge = __uint_as_float(P + 1024u) + DELTA;
                }
                break;
            }
            cum += b[i];
        }
    }
}

// grid-stride: count n_hi (block-reduced, 1 atomic/block); flag band members [lo,hi]
__global__ void band_kernel(const float* __restrict__ probs_b, SelState* __restrict__ st,
                            unsigned char* __restrict__ flag) {
    __shared__ unsigned int cnt_s;
    if (threadIdx.x == 0) cnt_s = 0;
    __syncthreads();
    float hi = st->hi_edge, lo = st->lo_edge;
    unsigned int local = 0;
    for (unsigned int p = blockIdx.x * 256 + threadIdx.x; p < NNZ; p += gridDim.x * 256) {
        float pk = probs_b[p];
        if (pk > hi) local++;
        else if (pk >= lo) flag[p] = 1;
    }
    #pragma unroll
    for (int o = 32; o > 0; o >>= 1) local += __shfl_down(local, o);
    if ((threadIdx.x & 63) == 0 && local) atomicAdd(&cnt_s, local);
    __syncthreads();
    if (threadIdx.x == 0 && cnt_s) atomicAdd(&st->n_hi, cnt_s);
}

// append (p, j, e, v) for band members (j-order pass; e,v read coalesced from E,V)
__global__ void bandj_kernel(const int* __restrict__ V, const int* __restrict__ E,
                             const unsigned int* __restrict__ pos, const unsigned char* __restrict__ flag,
                             SelState* __restrict__ st,
                             unsigned int* __restrict__ band_p, unsigned int* __restrict__ band_j,
                             unsigned int* __restrict__ band_e, unsigned int* __restrict__ band_v) {
    unsigned int j = blockIdx.x * 256 + threadIdx.x;
    if (j >= NNZ) return;
    unsigned int p = pos[j];
    if (flag[p] == 1u) {
        unsigned int s = atomicAdd(&st->band_n, 1u);
        if (s < BANDCAP) {
            band_p[s] = p;
            band_j[s] = j;
            band_e[s] = (unsigned int)E[j];
            band_v[s] = (unsigned int)V[j];
        }
    }
}

// exact f64 recompute for band members; W1 staged in LDS
__global__ void rescue_kernel(const unsigned int* __restrict__ vbucket,
                              const unsigned int* __restrict__ edge_off,
                              const unsigned int* __restrict__ edge_cnt,
                              const float* __restrict__ x, const float* __restrict__ W1,
                              const float* __restrict__ b1, const float* __restrict__ W2,
                              const float* __restrict__ b2,
                              const unsigned int* __restrict__ band_e,
                              const unsigned int* __restrict__ band_v,
                              const SelState* __restrict__ st,
                              unsigned long long* __restrict__ band_key) {
    unsigned int n = st->band_n; if (n > BANDCAP) n = BANDCAP;
    if (blockIdx.x * 8 >= n) return;
    __shared__ float sW[128 * 32];
    for (int t = threadIdx.x; t < 128 * 32; t += 256) sW[t] = W1[t];
    __syncthreads();
    unsigned int g = blockIdx.x * 8 + (threadIdx.x >> 5);
    if (g >= n) return;
    int k = threadIdx.x & 31;
    unsigned int v = band_v[g];
    unsigned int e = band_e[g];
    unsigned int off = edge_off[e];
    unsigned int deg = edge_cnt[e];

    const float* xv = x + (size_t)v * 64u;
    double a = 0.0;
    #pragma unroll 8
    for (int d = 0; d < 64; ++d) a += (double)xv[d] * (double)sW[d * 32 + k];
    double bsum = 0.0;
    for (unsigned int m = off; m < off + deg; ++m) {
        const float* xm = x + (size_t)vbucket[m] * 64u;
        double acc = 0.0;
        #pragma unroll 8
        for (int d = 0; d < 64; ++d) acc += (double)xm[d] * (double)sW[(64 + d) * 32 + k];
        bsum += acc;
    }
    double cc = (double)(deg > 1u ? deg : 1u);
    double h = a + bsum / cc + (double)b1[k];
    h = h > 0.0 ? h : 0.0;
    double t = h * (double)W2[k];
    #pragma unroll
    for (int o = 16; o > 0; o >>= 1) t += __shfl_down(t, o, 32);
    if (k == 0) {
        double pr = 1.0 / (1.0 + exp(-(t + (double)b2[0])));
        band_key[g] = (unsigned long long)__double_as_longlong(pr);
    }
}

// ---------------- O(n) band selection: 2-level hist on monotone u32 map ----------------
__global__ void bhist1_kernel(const unsigned long long* __restrict__ band_key,
                              const SelState* __restrict__ st, unsigned int* __restrict__ hist) {
    __shared__ unsigned int lh[2048];
    for (int t = threadIdx.x; t < 2048; t += 256) lh[t] = 0;
    __syncthreads();
    unsigned int n = st->band_n; if (n > BANDCAP) n = BANDCAP;
    float lo = st->lo_edge;
    for (unsigned int i = blockIdx.x * 256 + threadIdx.x; i < n; i += gridDim.x * 256) {
        unsigned int u = band_u32(__longlong_as_double((long long)band_key[i]), lo);
        atomicAdd(&lh[u >> 21], 1u);
    }
    __syncthreads();
    for (int t = threadIdx.x; t < 2048; t += 256)
        if (lh[t]) atomicAdd(&hist[4096 + t], lh[t]);
}

__global__ void bhist2_kernel(const unsigned long long* __restrict__ band_key,
                              const SelState* __restrict__ st, unsigned int* __restrict__ hist) {
    __shared__ unsigned int lh[2048];
    for (int t = threadIdx.x; t < 2048; t += 256) lh[t] = 0;
    __syncthreads();
    unsigned int n = st->band_n; if (n > BANDCAP) n = BANDCAP;
    float lo = st->lo_edge;
    unsigned int bB1 = st->bB1;
    for (unsigned int i = blockIdx.x * 256 + threadIdx.x; i < n; i += gridDim.x * 256) {
        unsigned int u = band_u32(__longlong_as_double((long long)band_key[i]), lo);
        if ((u >> 21) == bB1) atomicAdd(&lh[(u >> 10) & 2047u], 1u);
    }
    __syncthreads();
    for (int t = threadIdx.x; t < 2048; t += 256)
        if (lh[t]) atomicAdd(&hist[6144 + t], lh[t]);
}

// which=0: bucket bB1 at rank (K_KEEP - n_hi); which=1: bucket bB2 at rank brem1 -> bU0, brem2
__global__ void bscan_kernel(const unsigned int* __restrict__ hist, SelState* __restrict__ st, int which) {
    __shared__ unsigned int csum[256];
    int t = threadIdx.x;
    unsigned int target = (which == 0) ? ((unsigned int)K_KEEP - st->n_hi) : st->brem1;
    const unsigned int* h = hist + (which ? 6144 : 4096);
    unsigned int b[8];
    unsigned int s = 0;
    #pragma unroll
    for (int i = 0; i < 8; ++i) { b[i] = h[t * 8 + i]; s += b[i]; }
    csum[t] = s;
    __syncthreads();
    for (int off = 1; off < 256; off <<= 1) {
        unsigned int v = (t + off < 256) ? csum[t + off] : 0u;
        __syncthreads();
        csum[t] += v;
        __syncthreads();
    }
    unsigned int above = csum[t] - s;
    if (above < target && target <= above + s) {
        unsigned int rem = target - above;
        unsigned int cum = 0;
        #pragma unroll
        for (int i = 7; i >= 0; --i) {
            if (rem <= cum + b[i]) {
                unsigned int bin = (unsigned int)(t * 8 + i);
                if (which == 0) { st->bB1 = bin; st->brem1 = rem - cum; }
                else            { st->bU0 = (st->bB1 << 21) | (bin << 10); st->brem2 = rem - cum; }
                break;
            }
            cum += b[i];
        }
    }
}

// mark u >= bU0+1024 selected; collect tie bucket [bU0, bU0+1024)
__global__ void btie_kernel(const unsigned long long* __restrict__ band_key,
                            const unsigned int* __restrict__ band_j,
                            const unsigned int* __restrict__ band_p,
                            SelState* __restrict__ st, unsigned char* __restrict__ flag,
                            unsigned long long* __restrict__ tie_k,
                            unsigned int* __restrict__ tie_j, unsigned int* __restrict__ tie_p) {
    unsigned int n = st->band_n; if (n > BANDCAP) n = BANDCAP;
    unsigned int i = blockIdx.x * 256 + threadIdx.x;
    if (i >= n) return;
    float lo = st->lo_edge;
    unsigned int U0 = st->bU0;
    unsigned long long key = band_key[i];
    unsigned int u = band_u32(__longlong_as_double((long long)key), lo);
    if (u >= U0 + 1024u) {
        flag[band_p[i]] = 2u;
    } else if (u >= U0) {
        unsigned int s = atomicAdd(&st->tie_n, 1u);
        if (s < TIECAP) { tie_k[s] = key; tie_j[s] = band_j[i]; tie_p[s] = band_p[i]; }
    }
}

// exact rank inside the (tiny) tie bucket by (key desc, j asc); take first brem2
__global__ void btierank_kernel(const unsigned long long* __restrict__ tie_k,
                                const unsigned int* __restrict__ tie_j,
                                const unsigned int* __restrict__ tie_p,
                                const SelState* __restrict__ st, unsigned char* __restrict__ flag) {
    unsigned int n = st->tie_n; if (n > TIECAP) n = TIECAP;
    unsigned int need = st->brem2;
    for (unsigned int i = threadIdx.x; i < n; i += 256) {
        unsigned long long ki = tie_k[i];
        unsigned int ji = tie_j[i];
        unsigned int r = 0;
        for (unsigned int q = 0; q < n; ++q) {
            unsigned long long kq = tie_k[q];
            if (kq > ki || (kq == ki && tie_j[q] < ji)) r++;
        }
        if (r < need) flag[tie_p[i]] = 2u;
    }
}

// j-order coalesced outputs; hard bit computed inline from gathered probs/flag
__global__ void out_kernel(const float* __restrict__ probs_b, const unsigned char* __restrict__ flag,
                           const unsigned int* __restrict__ pos, const SelState* __restrict__ st,
                           float* __restrict__ o_probs, float* __restrict__ o_soft, float* __restrict__ o_hard) {
    unsigned int j = blockIdx.x * 256 + threadIdx.x;
    if (j >= NNZ) return;
    float hi = st->hi_edge;
    unsigned int p = pos[j];
    float pk = probs_b[p];
    float hb = (pk > hi || flag[p] == 2u) ? 1.f : 0.f;
    o_probs[j] = pk;
    o_soft[j]  = hb;
    o_hard[j]  = hb;
}

// per-edge: edge_soft / edge_hard recomputed from CSR-coalesced probs/flag
__global__ void edge_out_kernel(const float* __restrict__ probs_b, const unsigned char* __restrict__ flag,
                                const unsigned int* __restrict__ edge_off,
                                const unsigned int* __restrict__ edge_cnt,
                                const SelState* __restrict__ st,
                                float* __restrict__ o_es, float* __restrict__ o_eh) {
    unsigned int e = blockIdx.x * 256 + threadIdx.x;
    if (e >= N_EDGES) return;
    float hi = st->hi_edge;
    unsigned int off = edge_off[e], deg = edge_cnt[e];
    unsigned int cnt = 0;
    for (unsigned int i = 0; i < deg; ++i)
        cnt += (probs_b[off + i] > hi || flag[off + i] == 2u) ? 1u : 0u;
    float cc = (float)(deg > 1u ? deg : 1u);
    o_es[e] = (float)cnt / cc;
    o_eh[e] = cnt ? 1.f : 0.f;
}

extern "C" void kernel_launch(void* const* d_in, const int* in_sizes, int n_in,
                              void* d_out, int out_size, void* d_ws, size_t ws_size,
                              hipStream_t stream) {
    const float* x  = (const float*)d_in[0];
    const int*   V  = (const int*)d_in[1];
    const int*   E  = (const int*)d_in[2];
    const float* W1 = (const float*)d_in[3];
    const float* b1 = (const float*)d_in[4];
    const float* W2 = (const float*)d_in[5];
    const float* b2 = (const float*)d_in[6];

    float* out     = (float*)d_out;
    float* o_probs = out;
    float* o_soft  = out + NNZ;
    float* o_hard  = out + 2 * (size_t)NNZ;
    float* o_ep    = out + 3 * (size_t)NNZ;
    float* o_es    = out + 3 * (size_t)NNZ + N_EDGES;
    float* o_eh    = out + 3 * (size_t)NNZ + 2 * (size_t)N_EDGES;

    char* w = (char*)d_ws;
    float*              p_ab     = (float*)(w + OFF_PAB);
    float*              probs_b  = (float*)(w + OFF_PB32);
    unsigned int*       vbucket  = (unsigned int*)(w + OFF_VB);
    unsigned int*       pos      = (unsigned int*)(w + OFF_POS);
    unsigned int*       edge_off = (unsigned int*)(w + OFF_EOFF);
    unsigned int*       cursor   = (unsigned int*)(w + OFF_CUR);
    unsigned int*       bsums    = (unsigned int*)(w + OFF_BS);
    unsigned int*       band_p   = (unsigned int*)(w + OFF_BANDP);
    unsigned int*       band_j   = (unsigned int*)(w + OFF_BANDJ);
    unsigned int*       band_e   = (unsigned int*)(w + OFF_BANDE);
    unsigned int*       band_v   = (unsigned int*)(w + OFF_BANDV);
    unsigned long long* band_key = (unsigned long long*)(w + OFF_BANDK);
    unsigned long long* tie_k    = (unsigned long long*)(w + OFF_TIEK);
    unsigned int*       tie_j    = (unsigned int*)(w + OFF_TIEJ);
    unsigned int*       tie_p    = (unsigned int*)(w + OFF_TIEP);
    unsigned char*      flag     = (unsigned char*)(w + OFF_FLAG);
    unsigned int*       edge_cnt = (unsigned int*)(w + OFF_ECNT);
    unsigned int*       hist     = (unsigned int*)(w + OFF_HIST);
    SelState*           st       = (SelState*)(w + OFF_ST);

    hipMemsetAsync(w + ZERO_OFF, 0, ZERO_LEN, stream);

    proj_kernel<<<(N_NODES + 7) / 8, 256, 0, stream>>>(x, W1, p_ab);

    count_kernel<<<(NNZ + 255) / 256, 256, 0, stream>>>(E, edge_cnt);
    scanA_kernel<<<SCAN_BLOCKS, 256, 0, stream>>>(edge_cnt, edge_off, bsums);
    scanB_kernel<<<1, 256, 0, stream>>>(bsums);
    scanC_kernel<<<(N_EDGES + 255) / 256, 256, 0, stream>>>(edge_off, bsums, cursor);
    bucket_kernel<<<(NNZ + 255) / 256, 256, 0, stream>>>(V, E, cursor, vbucket, pos);

    edge_logit_kernel<<<(N_EDGES + 3) / 4, 256, 0, stream>>>(vbucket, edge_off, edge_cnt,
                                                             p_ab, b1, W2, b2, probs_b, o_ep);

    hist1_kernel<<<1024, 256, 0, stream>>>(probs_b, hist);
    scan_sel_kernel<<<1, 256, 0, stream>>>(hist, st, 0);
    hist2_kernel<<<1024, 256, 0, stream>>>(probs_b, st, hist);
    scan_sel_kernel<<<1, 256, 0, stream>>>(hist, st, 1);

    band_kernel<<<1024, 256, 0, stream>>>(probs_b, st, flag);
    bandj_kernel<<<(NNZ + 255) / 256, 256, 0, stream>>>(V, E, pos, flag, st,
                                                        band_p, band_j, band_e, band_v);
    rescue_kernel<<<BANDCAP / 8, 256, 0, stream>>>(vbucket, edge_off, edge_cnt, x, W1, b1, W2, b2,
                                                   band_e, band_v, st, band_key);

    bhist1_kernel<<<64, 256, 0, stream>>>(band_key, st, hist);
    bscan_kernel<<<1, 256, 0, stream>>>(hist, st, 0);
    bhist2_kernel<<<64, 256, 0, stream>>>(band_key, st, hist);
    bscan_kernel<<<1, 256, 0, stream>>>(hist, st, 1);
    btie_kernel<<<BANDCAP / 256, 256, 0, stream>>>(band_key, band_j, band_p, st, flag,
                                                   tie_k, tie_j, tie_p);
    btierank_kernel<<<1, 256, 0, stream>>>(tie_k, tie_j, tie_p, st, flag);

    out_kernel<<<(NNZ + 255) / 256, 256, 0, stream>>>(probs_b, flag, pos, st, o_probs, o_soft, o_hard);
    edge_out_kernel<<<(N_EDGES + 255) / 256, 256, 0, stream>>>(probs_b, flag, edge_off, edge_cnt, st,
                                                               o_es, o_eh);
}

// Round 9
// 863.035 us; speedup vs baseline: 4.2482x; 1.0117x over previous
//
#include <hip/hip_runtime.h>
#include <math.h>

#define N_NODES   100000
#define N_EDGES   200000
#define NNZ       2000000
#define K_KEEP    1000000
#define BANDCAP   131072
#define TIECAP    4096
#define DELTA     1.0e-3f
#define SCAN_BLOCKS 196   // ceil(200000/1024)
#define USCALE (4294967296.0 / 4.0e-3)   // band key -> u32 map; band width < 4e-3 guaranteed

// ---------------- workspace layout (bytes) ----------------
#define OFF_PAB   ((size_t)0)          // f32 p_ab [N_NODES*64]   25,600,000 (row: a[0..31]|b[32..63])
#define OFF_PB32  ((size_t)25600000)   // f32 probs_b [NNZ]        8,000,000 (CSR/p-order probs)
#define OFF_VJ    ((size_t)33600000)   // uint2 vj [NNZ]          16,000,000 (.x=vertex, .y=orig j)
#define OFF_POS   ((size_t)49600000)   // u32 pos [NNZ] j->p       8,000,000
#define OFF_EOFF  ((size_t)57600000)   // u32 edge_off [N_EDGES]     800,000
#define OFF_CUR   ((size_t)58400000)   // u32 cursor [N_EDGES]       800,000
#define OFF_BS    ((size_t)59200000)   // u32 bsums [256]              1,024
#define OFF_BANDP ((size_t)59201024)   // u32 band_p [BANDCAP]       524,288
#define OFF_BANDJ ((size_t)59725312)   // u32 band_j [BANDCAP]       524,288
#define OFF_BANDE ((size_t)60249600)   // u32 band_e [BANDCAP]       524,288
#define OFF_BANDV ((size_t)60773888)   // u32 band_v [BANDCAP]       524,288
#define OFF_BANDK ((size_t)61298176)   // u64 band_key [BANDCAP]   1,048,576
#define OFF_TIEK  ((size_t)62346752)   // u64 tie_k [TIECAP]          32,768
#define OFF_TIEJ  ((size_t)62379520)   // u32 tie_j [TIECAP]          16,384
#define OFF_TIEP  ((size_t)62395904)   // u32 tie_p [TIECAP]          16,384
// --- zero region ---
#define OFF_FLAG  ((size_t)62412288)   // u8  flag [NNZ]           2,000,000 (0 none,1 band,2 selected)
#define OFF_ECNT  ((size_t)64412288)   // u32 edge_cnt [N_EDGES]     800,000
#define OFF_HIST  ((size_t)65212288)   // u32 hist [4*2048]           32,768
#define OFF_ST    ((size_t)65245056)   // SelState                        64
#define ZERO_OFF  OFF_FLAG
#define ZERO_LEN  ((size_t)(65245120 - 62412288))

struct SelState {
    unsigned int B1;        // f32 pass-1 bucket
    unsigned int rem1;      // remaining rank within B1
    float lo_edge, hi_edge; // band boundaries
    unsigned int n_hi;      // count of f32 probs > hi_edge
    unsigned int band_n;    // band append counter
    unsigned int bB1;       // band-select pass-1 bucket (u32 map, bits 31:21)
    unsigned int brem1;     // remaining rank within bB1
    unsigned int bU0;       // threshold u-bucket base (width 1024)
    unsigned int brem2;     // remaining rank within the u-bucket
    unsigned int tie_n;     // tie-bucket append counter
};

__device__ __forceinline__ unsigned int band_u32(double key, float lo) {
    double t = (key - (double)lo) * USCALE;
    t = t < 0.0 ? 0.0 : (t > 4294967295.0 ? 4294967295.0 : t);
    return (unsigned int)t;   // monotone non-decreasing in key
}

// p_ab[v][k] = sum_d x[v][d]*W1[d][k];  p_ab[v][32+k] = sum_d x[v][d]*W1[64+d][k]
__global__ void proj_kernel(const float* __restrict__ x, const float* __restrict__ W1,
                            float* __restrict__ p_ab) {
    __shared__ float sW[128 * 32];
    __shared__ float sx[8][64];
    for (int t = threadIdx.x; t < 128 * 32; t += 256) sW[t] = W1[t];
    int base = blockIdx.x * 8;
    for (int t = threadIdx.x; t < 512; t += 256) {
        int n = t >> 6, d = t & 63;
        int g = base + n;
        sx[n][d] = (g < N_NODES) ? x[(size_t)g * 64 + d] : 0.f;
    }
    __syncthreads();
    int ln = threadIdx.x >> 5;
    int k  = threadIdx.x & 31;
    int node = base + ln;
    if (node >= N_NODES) return;
    float sa = 0.f, sb = 0.f;
    for (int d = 0; d < 64; ++d) {
        float xv = sx[ln][d];
        sa += xv * sW[d * 32 + k];
        sb += xv * sW[(64 + d) * 32 + k];
    }
    p_ab[(size_t)node * 64 + k]      = sa;
    p_ab[(size_t)node * 64 + 32 + k] = sb;
}

// ---------------- CSR build ----------------
__global__ void count_kernel(const int* __restrict__ E, unsigned int* __restrict__ edge_cnt) {
    int j = blockIdx.x * 256 + threadIdx.x;
    if (j >= NNZ) return;
    atomicAdd(&edge_cnt[E[j]], 1u);
}

__global__ void scanA_kernel(const unsigned int* __restrict__ edge_cnt,
                             unsigned int* __restrict__ edge_off, unsigned int* __restrict__ bsums) {
    __shared__ unsigned int s[256];
    int tid = threadIdx.x;
    int base = blockIdx.x * 1024 + tid * 4;
    unsigned int v0 = (base + 0 < N_EDGES) ? edge_cnt[base + 0] : 0u;
    unsigned int v1 = (base + 1 < N_EDGES) ? edge_cnt[base + 1] : 0u;
    unsigned int v2 = (base + 2 < N_EDGES) ? edge_cnt[base + 2] : 0u;
    unsigned int v3 = (base + 3 < N_EDGES) ? edge_cnt[base + 3] : 0u;
    unsigned int tsum = v0 + v1 + v2 + v3;
    s[tid] = tsum;
    __syncthreads();
    for (int off = 1; off < 256; off <<= 1) {
        unsigned int t = (tid >= off) ? s[tid - off] : 0u;
        __syncthreads();
        s[tid] += t;
        __syncthreads();
    }
    unsigned int excl = s[tid] - tsum;
    if (base + 0 < N_EDGES) edge_off[base + 0] = excl;
    if (base + 1 < N_EDGES) edge_off[base + 1] = excl + v0;
    if (base + 2 < N_EDGES) edge_off[base + 2] = excl + v0 + v1;
    if (base + 3 < N_EDGES) edge_off[base + 3] = excl + v0 + v1 + v2;
    if (tid == 255) bsums[blockIdx.x] = s[255];
}

__global__ void scanB_kernel(unsigned int* __restrict__ bsums) {
    __shared__ unsigned int s[256];
    int tid = threadIdx.x;
    unsigned int v = (tid < SCAN_BLOCKS) ? bsums[tid] : 0u;
    s[tid] = v;
    __syncthreads();
    for (int off = 1; off < 256; off <<= 1) {
        unsigned int t = (tid >= off) ? s[tid - off] : 0u;
        __syncthreads();
        s[tid] += t;
        __syncthreads();
    }
    if (tid < SCAN_BLOCKS) bsums[tid] = s[tid] - v;
}

__global__ void scanC_kernel(unsigned int* __restrict__ edge_off, const unsigned int* __restrict__ bsums,
                             unsigned int* __restrict__ cursor) {
    int i = blockIdx.x * 256 + threadIdx.x;
    if (i >= N_EDGES) return;
    unsigned int o = edge_off[i] + bsums[i >> 10];
    edge_off[i] = o;
    cursor[i] = o;
}

// 8 incidences/thread: 8 independent atomic returns in flight (hide far-atomic latency)
__global__ void bucket_kernel(const int* __restrict__ V, const int* __restrict__ E,
                              unsigned int* __restrict__ cursor,
                              uint2* __restrict__ vj, unsigned int* __restrict__ pos) {
    unsigned int base = blockIdx.x * 2048 + threadIdx.x;
    int ev[8], vv[8];
    unsigned int pp[8];
    #pragma unroll
    for (int c = 0; c < 8; ++c) {
        unsigned int j = base + 256u * c;
        if (j < NNZ) { ev[c] = E[j]; vv[c] = V[j]; }
    }
    #pragma unroll
    for (int c = 0; c < 8; ++c) {
        unsigned int j = base + 256u * c;
        if (j < NNZ) pp[c] = atomicAdd(&cursor[ev[c]], 1u);
    }
    #pragma unroll
    for (int c = 0; c < 8; ++c) {
        unsigned int j = base + 256u * c;
        if (j < NNZ) {
            vj[pp[c]] = make_uint2((unsigned int)vv[c], j);
            pos[j] = pp[c];
        }
    }
}

// ---------------- fused per-edge mean + per-incidence MLP (f32, CSR-order writes) ----------------
__global__ void edge_logit_kernel(const uint2* __restrict__ vj,
                                  const unsigned int* __restrict__ edge_off,
                                  const unsigned int* __restrict__ edge_cnt,
                                  const float* __restrict__ p_ab,
                                  const float* __restrict__ b1, const float* __restrict__ W2,
                                  const float* __restrict__ b2,
                                  float* __restrict__ probs_b, float* __restrict__ o_ep) {
    __shared__ float sa[4][32 * 32];   // 16 KB: [wave][slot i][k]
    int e = blockIdx.x * 4 + (threadIdx.x >> 6);
    if (e >= N_EDGES) return;
    int w    = threadIdx.x >> 6;
    int lane = threadIdx.x & 63;
    int k    = lane & 31;
    unsigned int half = (unsigned int)(lane >> 5);

    unsigned int off = edge_off[e];
    unsigned int deg = edge_cnt[e];
    unsigned int mind = deg < 32u ? deg : 32u;

    float bacc = 0.f;
    for (unsigned int i = half; i < mind; i += 2u) {
        unsigned int v = vj[off + i].x;
        const float* row = p_ab + (size_t)v * 64u;
        sa[w][i * 32 + k] = row[k];
        bacc += row[32 + k];
    }
    for (unsigned int i = 32u + half; i < deg; i += 2u) {   // deg>32 tail: b only
        unsigned int v = vj[off + i].x;
        bacc += p_ab[(size_t)v * 64u + 32u + k];
    }

    float cc  = (float)(deg > 1u ? deg : 1u);
    float emk = (bacc + __shfl_xor(bacc, 32)) / cc + b1[k];
    float w2k = W2[k];
    float b2v = b2[0];
    float epsum = 0.f;

    for (unsigned int i = half; i < mind; i += 2u) {
        float hk = sa[w][i * 32 + k] + emk;
        hk = hk > 0.f ? hk : 0.f;
        float t = hk * w2k;
        #pragma unroll
        for (int o = 16; o > 0; o >>= 1) t += __shfl_down(t, o, 32);
        if (k == 0) {
            float pr = 1.f / (1.f + __expf(-(t + b2v)));
            probs_b[off + i] = pr;
            epsum += pr;
        }
    }
    for (unsigned int i = 32u + half; i < deg; i += 2u) {   // deg>32 tail: a from global
        unsigned int v = vj[off + i].x;
        float hk = p_ab[(size_t)v * 64u + k] + emk;
        hk = hk > 0.f ? hk : 0.f;
        float t = hk * w2k;
        #pragma unroll
        for (int o = 16; o > 0; o >>= 1) t += __shfl_down(t, o, 32);
        if (k == 0) {
            float pr = 1.f / (1.f + __expf(-(t + b2v)));
            probs_b[off + i] = pr;
            epsum += pr;
        }
    }
    float etot = epsum + __shfl_xor(epsum, 32);
    if (lane == 0) o_ep[e] = etot / cc;
}

// ---------------- 2-level radix histogram on f32 keys ----------------
__global__ void hist1_kernel(const float* __restrict__ probs_b, unsigned int* __restrict__ hist) {
    __shared__ unsigned int lh[2048];
    for (int t = threadIdx.x; t < 2048; t += 256) lh[t] = 0;
    __syncthreads();
    for (unsigned int i = blockIdx.x * 256 + threadIdx.x; i < NNZ; i += gridDim.x * 256) {
        unsigned int key = __float_as_uint(probs_b[i]);
        atomicAdd(&lh[key >> 21], 1u);
    }
    __syncthreads();
    for (int t = threadIdx.x; t < 2048; t += 256)
        if (lh[t]) atomicAdd(&hist[t], lh[t]);
}

__global__ void hist2_kernel(const float* __restrict__ probs_b, const SelState* __restrict__ st,
                             unsigned int* __restrict__ hist) {
    __shared__ unsigned int lh[2048];
    for (int t = threadIdx.x; t < 2048; t += 256) lh[t] = 0;
    __syncthreads();
    unsigned int B1 = st->B1;
    for (unsigned int i = blockIdx.x * 256 + threadIdx.x; i < NNZ; i += gridDim.x * 256) {
        unsigned int key = __float_as_uint(probs_b[i]);
        if ((key >> 21) == B1) atomicAdd(&lh[(key >> 10) & 2047u], 1u);
    }
    __syncthreads();
    for (int t = threadIdx.x; t < 2048; t += 256)
        if (lh[t]) atomicAdd(&hist[2048 + t], lh[t]);
}

// which=0: select bucket B1 at rank K_KEEP; which=1: select B2 at rank rem1, set band edges
__global__ void scan_sel_kernel(const unsigned int* __restrict__ hist, SelState* __restrict__ st, int which) {
    __shared__ unsigned int csum[256];
    int t = threadIdx.x;
    unsigned int target = (which == 0) ? (unsigned int)K_KEEP : st->rem1;
    const unsigned int* h = hist + (which ? 2048 : 0);
    unsigned int b[8];
    unsigned int s = 0;
    #pragma unroll
    for (int i = 0; i < 8; ++i) { b[i] = h[t * 8 + i]; s += b[i]; }
    csum[t] = s;
    __syncthreads();
    for (int off = 1; off < 256; off <<= 1) {
        unsigned int v = (t + off < 256) ? csum[t + off] : 0u;
        __syncthreads();
        csum[t] += v;
        __syncthreads();
    }
    unsigned int above = csum[t] - s;       // sum over chunks > t
    if (above < target && target <= above + s) {
        unsigned int rem = target - above;
        unsigned int cum = 0;
        #pragma unroll
        for (int i = 7; i >= 0; --i) {
            if (rem <= cum + b[i]) {
                unsigned int bin = (unsigned int)(t * 8 + i);
                if (which == 0) { st->B1 = bin; st->rem1 = rem - cum; }
                else {
                    unsigned int P = (st->B1 << 21) | (bin << 10);
                    st->lo_edge = __uint_as_float(P) - DELTA;
                    st->hi_edge = __uint_as_float(P + 1024u) + DELTA;
                }
                break;
            }
            cum += b[i];
        }
    }
}

// grid-stride: count n_hi (block-reduced, 1 atomic/block); flag band members [lo,hi]
__global__ void band_kernel(const float* __restrict__ probs_b, SelState* __restrict__ st,
                            unsigned char* __restrict__ flag) {
    __shared__ unsigned int cnt_s;
    if (threadIdx.x == 0) cnt_s = 0;
    __syncthreads();
    float hi = st->hi_edge, lo = st->lo_edge;
    unsigned int local = 0;
    for (unsigned int p = blockIdx.x * 256 + threadIdx.x; p < NNZ; p += gridDim.x * 256) {
        float pk = probs_b[p];
        if (pk > hi) local++;
        else if (pk >= lo) flag[p] = 1;
    }
    #pragma unroll
    for (int o = 32; o > 0; o >>= 1) local += __shfl_down(local, o);
    if ((threadIdx.x & 63) == 0 && local) atomicAdd(&cnt_s, local);
    __syncthreads();
    if (threadIdx.x == 0 && cnt_s) atomicAdd(&st->n_hi, cnt_s);
}

// p-order append: flag read coalesced, j from vj, e/v scattered only for band members
__global__ void bandj_kernel(const int* __restrict__ E, const uint2* __restrict__ vj,
                             const unsigned char* __restrict__ flag,
                             SelState* __restrict__ st,
                             unsigned int* __restrict__ band_p, unsigned int* __restrict__ band_j,
                             unsigned int* __restrict__ band_e, unsigned int* __restrict__ band_v) {
    unsigned int p = blockIdx.x * 256 + threadIdx.x;
    if (p >= NNZ) return;
    if (flag[p] == 1u) {
        uint2 t = vj[p];
        unsigned int s = atomicAdd(&st->band_n, 1u);
        if (s < BANDCAP) {
            band_p[s] = p;
            band_j[s] = t.y;
            band_e[s] = (unsigned int)E[t.y];
            band_v[s] = t.x;
        }
    }
}

// exact f64 recompute for band members; W1 staged in LDS
__global__ void rescue_kernel(const uint2* __restrict__ vj,
                              const unsigned int* __restrict__ edge_off,
                              const unsigned int* __restrict__ edge_cnt,
                              const float* __restrict__ x, const float* __restrict__ W1,
                              const float* __restrict__ b1, const float* __restrict__ W2,
                              const float* __restrict__ b2,
                              const unsigned int* __restrict__ band_e,
                              const unsigned int* __restrict__ band_v,
                              const SelState* __restrict__ st,
                              unsigned long long* __restrict__ band_key) {
    unsigned int n = st->band_n; if (n > BANDCAP) n = BANDCAP;
    if (blockIdx.x * 8 >= n) return;
    __shared__ float sW[128 * 32];
    for (int t = threadIdx.x; t < 128 * 32; t += 256) sW[t] = W1[t];
    __syncthreads();
    unsigned int g = blockIdx.x * 8 + (threadIdx.x >> 5);
    if (g >= n) return;
    int k = threadIdx.x & 31;
    unsigned int v = band_v[g];
    unsigned int e = band_e[g];
    unsigned int off = edge_off[e];
    unsigned int deg = edge_cnt[e];

    const float* xv = x + (size_t)v * 64u;
    double a = 0.0;
    #pragma unroll 8
    for (int d = 0; d < 64; ++d) a += (double)xv[d] * (double)sW[d * 32 + k];
    double bsum = 0.0;
    for (unsigned int m = off; m < off + deg; ++m) {
        const float* xm = x + (size_t)vj[m].x * 64u;
        double acc = 0.0;
        #pragma unroll 8
        for (int d = 0; d < 64; ++d) acc += (double)xm[d] * (double)sW[(64 + d) * 32 + k];
        bsum += acc;
    }
    double cc = (double)(deg > 1u ? deg : 1u);
    double h = a + bsum / cc + (double)b1[k];
    h = h > 0.0 ? h : 0.0;
    double t = h * (double)W2[k];
    #pragma unroll
    for (int o = 16; o > 0; o >>= 1) t += __shfl_down(t, o, 32);
    if (k == 0) {
        double pr = 1.0 / (1.0 + exp(-(t + (double)b2[0])));
        band_key[g] = (unsigned long long)__double_as_longlong(pr);
    }
}

// ---------------- O(n) band selection: 2-level hist on monotone u32 map ----------------
__global__ void bhist1_kernel(const unsigned long long* __restrict__ band_key,
                              const SelState* __restrict__ st, unsigned int* __restrict__ hist) {
    __shared__ unsigned int lh[2048];
    for (int t = threadIdx.x; t < 2048; t += 256) lh[t] = 0;
    __syncthreads();
    unsigned int n = st->band_n; if (n > BANDCAP) n = BANDCAP;
    float lo = st->lo_edge;
    for (unsigned int i = blockIdx.x * 256 + threadIdx.x; i < n; i += gridDim.x * 256) {
        unsigned int u = band_u32(__longlong_as_double((long long)band_key[i]), lo);
        atomicAdd(&lh[u >> 21], 1u);
    }
    __syncthreads();
    for (int t = threadIdx.x; t < 2048; t += 256)
        if (lh[t]) atomicAdd(&hist[4096 + t], lh[t]);
}

__global__ void bhist2_kernel(const unsigned long long* __restrict__ band_key,
                              const SelState* __restrict__ st, unsigned int* __restrict__ hist) {
    __shared__ unsigned int lh[2048];
    for (int t = threadIdx.x; t < 2048; t += 256) lh[t] = 0;
    __syncthreads();
    unsigned int n = st->band_n; if (n > BANDCAP) n = BANDCAP;
    float lo = st->lo_edge;
    unsigned int bB1 = st->bB1;
    for (unsigned int i = blockIdx.x * 256 + threadIdx.x; i < n; i += gridDim.x * 256) {
        unsigned int u = band_u32(__longlong_as_double((long long)band_key[i]), lo);
        if ((u >> 21) == bB1) atomicAdd(&lh[(u >> 10) & 2047u], 1u);
    }
    __syncthreads();
    for (int t = threadIdx.x; t < 2048; t += 256)
        if (lh[t]) atomicAdd(&hist[6144 + t], lh[t]);
}

// which=0: bucket bB1 at rank (K_KEEP - n_hi); which=1: bucket bB2 at rank brem1 -> bU0, brem2
__global__ void bscan_kernel(const unsigned int* __restrict__ hist, SelState* __restrict__ st, int which) {
    __shared__ unsigned int csum[256];
    int t = threadIdx.x;
    unsigned int target = (which == 0) ? ((unsigned int)K_KEEP - st->n_hi) : st->brem1;
    const unsigned int* h = hist + (which ? 6144 : 4096);
    unsigned int b[8];
    unsigned int s = 0;
    #pragma unroll
    for (int i = 0; i < 8; ++i) { b[i] = h[t * 8 + i]; s += b[i]; }
    csum[t] = s;
    __syncthreads();
    for (int off = 1; off < 256; off <<= 1) {
        unsigned int v = (t + off < 256) ? csum[t + off] : 0u;
        __syncthreads();
        csum[t] += v;
        __syncthreads();
    }
    unsigned int above = csum[t] - s;
    if (above < target && target <= above + s) {
        unsigned int rem = target - above;
        unsigned int cum = 0;
        #pragma unroll
        for (int i = 7; i >= 0; --i) {
            if (rem <= cum + b[i]) {
                unsigned int bin = (unsigned int)(t * 8 + i);
                if (which == 0) { st->bB1 = bin; st->brem1 = rem - cum; }
                else            { st->bU0 = (st->bB1 << 21) | (bin << 10); st->brem2 = rem - cum; }
                break;
            }
            cum += b[i];
        }
    }
}

// mark u >= bU0+1024 selected; collect tie bucket [bU0, bU0+1024)
__global__ void btie_kernel(const unsigned long long* __restrict__ band_key,
                            const unsigned int* __restrict__ band_j,
                            const unsigned int* __restrict__ band_p,
                            SelState* __restrict__ st, unsigned char* __restrict__ flag,
                            unsigned long long* __restrict__ tie_k,
                            unsigned int* __restrict__ tie_j, unsigned int* __restrict__ tie_p) {
    unsigned int n = st->band_n; if (n > BANDCAP) n = BANDCAP;
    unsigned int i = blockIdx.x * 256 + threadIdx.x;
    if (i >= n) return;
    float lo = st->lo_edge;
    unsigned int U0 = st->bU0;
    unsigned long long key = band_key[i];
    unsigned int u = band_u32(__longlong_as_double((long long)key), lo);
    if (u >= U0 + 1024u) {
        flag[band_p[i]] = 2u;
    } else if (u >= U0) {
        unsigned int s = atomicAdd(&st->tie_n, 1u);
        if (s < TIECAP) { tie_k[s] = key; tie_j[s] = band_j[i]; tie_p[s] = band_p[i]; }
    }
}

// exact rank inside the (tiny) tie bucket by (key desc, j asc); take first brem2
__global__ void btierank_kernel(const unsigned long long* __restrict__ tie_k,
                                const unsigned int* __restrict__ tie_j,
                                const unsigned int* __restrict__ tie_p,
                                const SelState* __restrict__ st, unsigned char* __restrict__ flag) {
    unsigned int n = st->tie_n; if (n > TIECAP) n = TIECAP;
    unsigned int need = st->brem2;
    for (unsigned int i = threadIdx.x; i < n; i += 256) {
        unsigned long long ki = tie_k[i];
        unsigned int ji = tie_j[i];
        unsigned int r = 0;
        for (unsigned int q = 0; q < n; ++q) {
            unsigned long long kq = tie_k[q];
            if (kq > ki || (kq == ki && tie_j[q] < ji)) r++;
        }
        if (r < need) flag[tie_p[i]] = 2u;
    }
}

// j-order coalesced outputs; hard bit computed inline from gathered probs/flag
__global__ void out_kernel(const float* __restrict__ probs_b, const unsigned char* __restrict__ flag,
                           const unsigned int* __restrict__ pos, const SelState* __restrict__ st,
                           float* __restrict__ o_probs, float* __restrict__ o_soft, float* __restrict__ o_hard) {
    unsigned int j = blockIdx.x * 256 + threadIdx.x;
    if (j >= NNZ) return;
    float hi = st->hi_edge;
    unsigned int p = pos[j];
    float pk = probs_b[p];
    float hb = (pk > hi || flag[p] == 2u) ? 1.f : 0.f;
    o_probs[j] = pk;
    o_soft[j]  = hb;
    o_hard[j]  = hb;
}

// per-edge: edge_soft / edge_hard recomputed from CSR-coalesced probs/flag
__global__ void edge_out_kernel(const float* __restrict__ probs_b, const unsigned char* __restrict__ flag,
                                const unsigned int* __restrict__ edge_off,
                                const unsigned int* __restrict__ edge_cnt,
                                const SelState* __restrict__ st,
                                float* __restrict__ o_es, float* __restrict__ o_eh) {
    unsigned int e = blockIdx.x * 256 + threadIdx.x;
    if (e >= N_EDGES) return;
    float hi = st->hi_edge;
    unsigned int off = edge_off[e], deg = edge_cnt[e];
    unsigned int cnt = 0;
    for (unsigned int i = 0; i < deg; ++i)
        cnt += (probs_b[off + i] > hi || flag[off + i] == 2u) ? 1u : 0u;
    float cc = (float)(deg > 1u ? deg : 1u);
    o_es[e] = (float)cnt / cc;
    o_eh[e] = cnt ? 1.f : 0.f;
}

extern "C" void kernel_launch(void* const* d_in, const int* in_sizes, int n_in,
                              void* d_out, int out_size, void* d_ws, size_t ws_size,
                              hipStream_t stream) {
    const float* x  = (const float*)d_in[0];
    const int*   V  = (const int*)d_in[1];
    const int*   E  = (const int*)d_in[2];
    const float* W1 = (const float*)d_in[3];
    const float* b1 = (const float*)d_in[4];
    const float* W2 = (const float*)d_in[5];
    const float* b2 = (const float*)d_in[6];

    float* out     = (float*)d_out;
    float* o_probs = out;
    float* o_soft  = out + NNZ;
    float* o_hard  = out + 2 * (size_t)NNZ;
    float* o_ep    = out + 3 * (size_t)NNZ;
    float* o_es    = out + 3 * (size_t)NNZ + N_EDGES;
    float* o_eh    = out + 3 * (size_t)NNZ + 2 * (size_t)N_EDGES;

    char* w = (char*)d_ws;
    float*              p_ab     = (float*)(w + OFF_PAB);
    float*              probs_b  = (float*)(w + OFF_PB32);
    uint2*              vj       = (uint2*)(w + OFF_VJ);
    unsigned int*       pos      = (unsigned int*)(w + OFF_POS);
    unsigned int*       edge_off = (unsigned int*)(w + OFF_EOFF);
    unsigned int*       cursor   = (unsigned int*)(w + OFF_CUR);
    unsigned int*       bsums    = (unsigned int*)(w + OFF_BS);
    unsigned int*       band_p   = (unsigned int*)(w + OFF_BANDP);
    unsigned int*       band_j   = (unsigned int*)(w + OFF_BANDJ);
    unsigned int*       band_e   = (unsigned int*)(w + OFF_BANDE);
    unsigned int*       band_v   = (unsigned int*)(w + OFF_BANDV);
    unsigned long long* band_key = (unsigned long long*)(w + OFF_BANDK);
    unsigned long long* tie_k    = (unsigned long long*)(w + OFF_TIEK);
    unsigned int*       tie_j    = (unsigned int*)(w + OFF_TIEJ);
    unsigned int*       tie_p    = (unsigned int*)(w + OFF_TIEP);
    unsigned char*      flag     = (unsigned char*)(w + OFF_FLAG);
    unsigned int*       edge_cnt = (unsigned int*)(w + OFF_ECNT);
    unsigned int*       hist     = (unsigned int*)(w + OFF_HIST);
    SelState*           st       = (SelState*)(w + OFF_ST);

    hipMemsetAsync(w + ZERO_OFF, 0, ZERO_LEN, stream);

    proj_kernel<<<(N_NODES + 7) / 8, 256, 0, stream>>>(x, W1, p_ab);

    count_kernel<<<(NNZ + 255) / 256, 256, 0, stream>>>(E, edge_cnt);
    scanA_kernel<<<SCAN_BLOCKS, 256, 0, stream>>>(edge_cnt, edge_off, bsums);
    scanB_kernel<<<1, 256, 0, stream>>>(bsums);
    scanC_kernel<<<(N_EDGES + 255) / 256, 256, 0, stream>>>(edge_off, bsums, cursor);
    bucket_kernel<<<(NNZ + 2047) / 2048, 256, 0, stream>>>(V, E, cursor, vj, pos);

    edge_logit_kernel<<<(N_EDGES + 3) / 4, 256, 0, stream>>>(vj, edge_off, edge_cnt,
                                                             p_ab, b1, W2, b2, probs_b, o_ep);

    hist1_kernel<<<1024, 256, 0, stream>>>(probs_b, hist);
    scan_sel_kernel<<<1, 256, 0, stream>>>(hist, st, 0);
    hist2_kernel<<<1024, 256, 0, stream>>>(probs_b, st, hist);
    scan_sel_kernel<<<1, 256, 0, stream>>>(hist, st, 1);

    band_kernel<<<1024, 256, 0, stream>>>(probs_b, st, flag);
    bandj_kernel<<<(NNZ + 255) / 256, 256, 0, stream>>>(E, vj, flag, st,
                                                        band_p, band_j, band_e, band_v);
    rescue_kernel<<<BANDCAP / 8, 256, 0, stream>>>(vj, edge_off, edge_cnt, x, W1, b1, W2, b2,
                                                   band_e, band_v, st, band_key);

    bhist1_kernel<<<64, 256, 0, stream>>>(band_key, st, hist);
    bscan_kernel<<<1, 256, 0, stream>>>(hist, st, 0);
    bhist2_kernel<<<64, 256, 0, stream>>>(band_key, st, hist);
    bscan_kernel<<<1, 256, 0, stream>>>(hist, st, 1);
    btie_kernel<<<BANDCAP / 256, 256, 0, stream>>>(band_key, band_j, band_p, st, flag,
                                                   tie_k, tie_j, tie_p);
    btierank_kernel<<<1, 256, 0, stream>>>(tie_k, tie_j, tie_p, st, flag);

    out_kernel<<<(NNZ + 255) / 256, 256, 0, stream>>>(probs_b, flag, pos, st, o_probs, o_soft, o_hard);
    edge_out_kernel<<<(N_EDGES + 255) / 256, 256, 0, stream>>>(probs_b, flag, edge_off, edge_cnt, st,
                                                               o_es, o_eh);
}

// Round 10
// 852.463 us; speedup vs baseline: 4.3009x; 1.0124x over previous
//
#include <hip/hip_runtime.h>
#include <math.h>

#define N_NODES   100000
#define N_EDGES   200000
#define NNZ       2000000
#define K_KEEP    1000000
#define BANDCAP   131072
#define TIECAP    4096
#define DELTA     1.0e-3f
#define SCAN_BLOCKS 196   // ceil(200000/1024)
#define USCALE (4294967296.0 / 4.0e-3)   // band key -> u32 map; band width < 4e-3 guaranteed

// ---------------- workspace layout (bytes) ----------------
#define OFF_PAB   ((size_t)0)          // float2 p_ab2 [N_NODES*32] 25,600,000 (.x=a_vk, .y=b_vk)
#define OFF_PB32  ((size_t)25600000)   // f32 probs_b [NNZ]        8,000,000 (CSR/p-order probs)
#define OFF_VJ    ((size_t)33600000)   // uint2 vj [NNZ]          16,000,000 (.x=vertex, .y=orig j)
#define OFF_POS   ((size_t)49600000)   // u32 pos [NNZ] j->p       8,000,000
#define OFF_EOFF  ((size_t)57600000)   // u32 edge_off [N_EDGES]     800,000
#define OFF_CUR   ((size_t)58400000)   // u32 cursor [N_EDGES]       800,000
#define OFF_BS    ((size_t)59200000)   // u32 bsums [256]              1,024
#define OFF_BANDP ((size_t)59201024)   // u32 band_p [BANDCAP]       524,288
#define OFF_BANDJ ((size_t)59725312)   // u32 band_j [BANDCAP]       524,288
#define OFF_BANDE ((size_t)60249600)   // u32 band_e [BANDCAP]       524,288
#define OFF_BANDV ((size_t)60773888)   // u32 band_v [BANDCAP]       524,288
#define OFF_BANDK ((size_t)61298176)   // u64 band_key [BANDCAP]   1,048,576
#define OFF_TIEK  ((size_t)62346752)   // u64 tie_k [TIECAP]          32,768
#define OFF_TIEJ  ((size_t)62379520)   // u32 tie_j [TIECAP]          16,384
#define OFF_TIEP  ((size_t)62395904)   // u32 tie_p [TIECAP]          16,384
// --- zero region ---
#define OFF_FLAG  ((size_t)62412288)   // u8  flag [NNZ]           2,000,000 (0 none,1 band,2 selected)
#define OFF_ECNT  ((size_t)64412288)   // u32 edge_cnt [N_EDGES]     800,000
#define OFF_HIST  ((size_t)65212288)   // u32 hist [4*2048]           32,768
#define OFF_ST    ((size_t)65245056)   // SelState                        64
#define ZERO_OFF  OFF_FLAG
#define ZERO_LEN  ((size_t)(65245120 - 62412288))

struct SelState {
    unsigned int B1;        // f32 pass-1 bucket
    unsigned int rem1;      // remaining rank within B1
    float lo_edge, hi_edge; // band boundaries
    unsigned int n_hi;      // count of f32 probs > hi_edge
    unsigned int band_n;    // band append counter
    unsigned int bB1;       // band-select pass-1 bucket (u32 map, bits 31:21)
    unsigned int brem1;     // remaining rank within bB1
    unsigned int bU0;       // threshold u-bucket base (width 1024)
    unsigned int brem2;     // remaining rank within the u-bucket
    unsigned int tie_n;     // tie-bucket append counter
};

__device__ __forceinline__ unsigned int band_u32(double key, float lo) {
    double t = (key - (double)lo) * USCALE;
    t = t < 0.0 ? 0.0 : (t > 4294967295.0 ? 4294967295.0 : t);
    return (unsigned int)t;   // monotone non-decreasing in key
}

// p_ab2[v][k] = (sum_d x[v][d]*W1[d][k], sum_d x[v][d]*W1[64+d][k])
__global__ void proj_kernel(const float* __restrict__ x, const float* __restrict__ W1,
                            float2* __restrict__ p_ab2) {
    __shared__ float sW[128 * 32];
    __shared__ float sx[8][64];
    for (int t = threadIdx.x; t < 128 * 32; t += 256) sW[t] = W1[t];
    int base = blockIdx.x * 8;
    for (int t = threadIdx.x; t < 512; t += 256) {
        int n = t >> 6, d = t & 63;
        int g = base + n;
        sx[n][d] = (g < N_NODES) ? x[(size_t)g * 64 + d] : 0.f;
    }
    __syncthreads();
    int ln = threadIdx.x >> 5;
    int k  = threadIdx.x & 31;
    int node = base + ln;
    if (node >= N_NODES) return;
    float sa = 0.f, sb = 0.f;
    for (int d = 0; d < 64; ++d) {
        float xv = sx[ln][d];
        sa += xv * sW[d * 32 + k];
        sb += xv * sW[(64 + d) * 32 + k];
    }
    p_ab2[(size_t)node * 32 + k] = make_float2(sa, sb);
}

// ---------------- CSR build ----------------
__global__ void count_kernel(const int* __restrict__ E, unsigned int* __restrict__ edge_cnt) {
    int j = blockIdx.x * 256 + threadIdx.x;
    if (j >= NNZ) return;
    atomicAdd(&edge_cnt[E[j]], 1u);
}

__global__ void scanA_kernel(const unsigned int* __restrict__ edge_cnt,
                             unsigned int* __restrict__ edge_off, unsigned int* __restrict__ bsums) {
    __shared__ unsigned int s[256];
    int tid = threadIdx.x;
    int base = blockIdx.x * 1024 + tid * 4;
    unsigned int v0 = (base + 0 < N_EDGES) ? edge_cnt[base + 0] : 0u;
    unsigned int v1 = (base + 1 < N_EDGES) ? edge_cnt[base + 1] : 0u;
    unsigned int v2 = (base + 2 < N_EDGES) ? edge_cnt[base + 2] : 0u;
    unsigned int v3 = (base + 3 < N_EDGES) ? edge_cnt[base + 3] : 0u;
    unsigned int tsum = v0 + v1 + v2 + v3;
    s[tid] = tsum;
    __syncthreads();
    for (int off = 1; off < 256; off <<= 1) {
        unsigned int t = (tid >= off) ? s[tid - off] : 0u;
        __syncthreads();
        s[tid] += t;
        __syncthreads();
    }
    unsigned int excl = s[tid] - tsum;
    if (base + 0 < N_EDGES) edge_off[base + 0] = excl;
    if (base + 1 < N_EDGES) edge_off[base + 1] = excl + v0;
    if (base + 2 < N_EDGES) edge_off[base + 2] = excl + v0 + v1;
    if (base + 3 < N_EDGES) edge_off[base + 3] = excl + v0 + v1 + v2;
    if (tid == 255) bsums[blockIdx.x] = s[255];
}

__global__ void scanB_kernel(unsigned int* __restrict__ bsums) {
    __shared__ unsigned int s[256];
    int tid = threadIdx.x;
    unsigned int v = (tid < SCAN_BLOCKS) ? bsums[tid] : 0u;
    s[tid] = v;
    __syncthreads();
    for (int off = 1; off < 256; off <<= 1) {
        unsigned int t = (tid >= off) ? s[tid - off] : 0u;
        __syncthreads();
        s[tid] += t;
        __syncthreads();
    }
    if (tid < SCAN_BLOCKS) bsums[tid] = s[tid] - v;
}

__global__ void scanC_kernel(unsigned int* __restrict__ edge_off, const unsigned int* __restrict__ bsums,
                             unsigned int* __restrict__ cursor) {
    int i = blockIdx.x * 256 + threadIdx.x;
    if (i >= N_EDGES) return;
    unsigned int o = edge_off[i] + bsums[i >> 10];
    edge_off[i] = o;
    cursor[i] = o;
}

// 8 incidences/thread: 8 independent atomic returns in flight (hide far-atomic latency)
__global__ void bucket_kernel(const int* __restrict__ V, const int* __restrict__ E,
                              unsigned int* __restrict__ cursor,
                              uint2* __restrict__ vj, unsigned int* __restrict__ pos) {
    unsigned int base = blockIdx.x * 2048 + threadIdx.x;
    int ev[8], vv[8];
    unsigned int pp[8];
    #pragma unroll
    for (int c = 0; c < 8; ++c) {
        unsigned int j = base + 256u * c;
        if (j < NNZ) { ev[c] = E[j]; vv[c] = V[j]; }
    }
    #pragma unroll
    for (int c = 0; c < 8; ++c) {
        unsigned int j = base + 256u * c;
        if (j < NNZ) pp[c] = atomicAdd(&cursor[ev[c]], 1u);
    }
    #pragma unroll
    for (int c = 0; c < 8; ++c) {
        unsigned int j = base + 256u * c;
        if (j < NNZ) {
            vj[pp[c]] = make_uint2((unsigned int)vv[c], j);
            pos[j] = pp[c];
        }
    }
}

// ---------------- fused per-edge mean + per-incidence MLP (f32, CSR-order writes) ----------------
// one 64-lane wave per edge; half h handles incidences i = h, h+2, ...
// member ids preloaded coalesced + shfl-broadcast; float2 row load serves both a and b;
// per-incidence logits parked in LDS, one vectorized sigmoid epilogue with coalesced stores.
__global__ void edge_logit_kernel(const uint2* __restrict__ vj,
                                  const unsigned int* __restrict__ edge_off,
                                  const unsigned int* __restrict__ edge_cnt,
                                  const float2* __restrict__ p_ab2,
                                  const float* __restrict__ b1, const float* __restrict__ W2,
                                  const float* __restrict__ b2,
                                  float* __restrict__ probs_b, float* __restrict__ o_ep) {
    __shared__ float sa[4][32 * 32];   // 16 KB: [wave][slot i][k]
    __shared__ float slog[4][32];      // per-incidence logits
    int e = blockIdx.x * 4 + (threadIdx.x >> 6);
    if (e >= N_EDGES) return;
    int w    = threadIdx.x >> 6;
    int lane = threadIdx.x & 63;
    int k    = lane & 31;
    unsigned int half = (unsigned int)(lane >> 5);

    unsigned int off = edge_off[e];
    unsigned int deg = edge_cnt[e];
    unsigned int mind = deg < 32u ? deg : 32u;

    // coalesced member-id preload (lanes 0..mind-1)
    unsigned int myv = ((unsigned int)lane < mind) ? vj[off + lane].x : 0u;

    float bacc = 0.f;
    for (unsigned int i = half; i < mind; i += 2u) {
        unsigned int v = (unsigned int)__shfl((int)myv, (int)i, 64);
        float2 r = p_ab2[(size_t)v * 32u + k];
        sa[w][i * 32 + k] = r.x;
        bacc += r.y;
    }
    for (unsigned int i = 32u + half; i < deg; i += 2u) {   // deg>32 tail: b only
        unsigned int v = vj[off + i].x;
        bacc += p_ab2[(size_t)v * 32u + k].y;
    }

    float cc  = (float)(deg > 1u ? deg : 1u);
    float emk = (bacc + __shfl_xor(bacc, 32)) / cc + b1[k];
    float w2k = W2[k];
    float b2v = b2[0];
    float prsum = 0.f;

    for (unsigned int i = half; i < mind; i += 2u) {
        float hk = sa[w][i * 32 + k] + emk;
        hk = hk > 0.f ? hk : 0.f;
        float t = hk * w2k;
        #pragma unroll
        for (int o = 16; o > 0; o >>= 1) t += __shfl_down(t, o, 32);
        if (k == 0) slog[w][i] = t;
    }
    // vectorized epilogue: lane i <-> incidence i (same wave; LDS ops in order)
    if ((unsigned int)lane < mind) {
        float pr = 1.f / (1.f + __expf(-(slog[w][lane] + b2v)));
        probs_b[off + lane] = pr;      // coalesced
        prsum = pr;
    }
    for (unsigned int i = 32u + half; i < deg; i += 2u) {   // deg>32 tail: a from global
        unsigned int v = vj[off + i].x;
        float hk = p_ab2[(size_t)v * 32u + k].x + emk;
        hk = hk > 0.f ? hk : 0.f;
        float t = hk * w2k;
        #pragma unroll
        for (int o = 16; o > 0; o >>= 1) t += __shfl_down(t, o, 32);
        if (k == 0) {
            float pr = 1.f / (1.f + __expf(-(t + b2v)));
            probs_b[off + i] = pr;
            prsum += pr;
        }
    }
    #pragma unroll
    for (int o = 32; o > 0; o >>= 1) prsum += __shfl_down(prsum, o, 64);
    if (lane == 0) o_ep[e] = prsum / cc;
}

// ---------------- 2-level radix histogram on f32 keys ----------------
__global__ void hist1_kernel(const float* __restrict__ probs_b, unsigned int* __restrict__ hist) {
    __shared__ unsigned int lh[2048];
    for (int t = threadIdx.x; t < 2048; t += 256) lh[t] = 0;
    __syncthreads();
    for (unsigned int i = blockIdx.x * 256 + threadIdx.x; i < NNZ; i += gridDim.x * 256) {
        unsigned int key = __float_as_uint(probs_b[i]);
        atomicAdd(&lh[key >> 21], 1u);
    }
    __syncthreads();
    for (int t = threadIdx.x; t < 2048; t += 256)
        if (lh[t]) atomicAdd(&hist[t], lh[t]);
}

__global__ void hist2_kernel(const float* __restrict__ probs_b, const SelState* __restrict__ st,
                             unsigned int* __restrict__ hist) {
    __shared__ unsigned int lh[2048];
    for (int t = threadIdx.x; t < 2048; t += 256) lh[t] = 0;
    __syncthreads();
    unsigned int B1 = st->B1;
    for (unsigned int i = blockIdx.x * 256 + threadIdx.x; i < NNZ; i += gridDim.x * 256) {
        unsigned int key = __float_as_uint(probs_b[i]);
        if ((key >> 21) == B1) atomicAdd(&lh[(key >> 10) & 2047u], 1u);
    }
    __syncthreads();
    for (int t = threadIdx.x; t < 2048; t += 256)
        if (lh[t]) atomicAdd(&hist[2048 + t], lh[t]);
}

// which=0: select bucket B1 at rank K_KEEP; which=1: select B2 at rank rem1, set band edges
__global__ void scan_sel_kernel(const unsigned int* __restrict__ hist, SelState* __restrict__ st, int which) {
    __shared__ unsigned int csum[256];
    int t = threadIdx.x;
    unsigned int target = (which == 0) ? (unsigned int)K_KEEP : st->rem1;
    const unsigned int* h = hist + (which ? 2048 : 0);
    unsigned int b[8];
    unsigned int s = 0;
    #pragma unroll
    for (int i = 0; i < 8; ++i) { b[i] = h[t * 8 + i]; s += b[i]; }
    csum[t] = s;
    __syncthreads();
    for (int off = 1; off < 256; off <<= 1) {
        unsigned int v = (t + off < 256) ? csum[t + off] : 0u;
        __syncthreads();
        csum[t] += v;
        __syncthreads();
    }
    unsigned int above = csum[t] - s;       // sum over chunks > t
    if (above < target && target <= above + s) {
        unsigned int rem = target - above;
        unsigned int cum = 0;
        #pragma unroll
        for (int i = 7; i >= 0; --i) {
            if (rem <= cum + b[i]) {
                unsigned int bin = (unsigned int)(t * 8 + i);
                if (which == 0) { st->B1 = bin; st->rem1 = rem - cum; }
                else {
                    unsigned int P = (st->B1 << 21) | (bin << 10);
                    st->lo_edge = __uint_as_float(P) - DELTA;
                    st->hi_edge = __uint_as_float(P + 1024u) + DELTA;
                }
                break;
            }
            cum += b[i];
        }
    }
}

// grid-stride: count n_hi (block-reduced, 1 atomic/block); flag band members [lo,hi]
__global__ void band_kernel(const float* __restrict__ probs_b, SelState* __restrict__ st,
                            unsigned char* __restrict__ flag) {
    __shared__ unsigned int cnt_s;
    if (threadIdx.x == 0) cnt_s = 0;
    __syncthreads();
    float hi = st->hi_edge, lo = st->lo_edge;
    unsigned int local = 0;
    for (unsigned int p = blockIdx.x * 256 + threadIdx.x; p < NNZ; p += gridDim.x * 256) {
        float pk = probs_b[p];
        if (pk > hi) local++;
        else if (pk >= lo) flag[p] = 1;
    }
    #pragma unroll
    for (int o = 32; o > 0; o >>= 1) local += __shfl_down(local, o);
    if ((threadIdx.x & 63) == 0 && local) atomicAdd(&cnt_s, local);
    __syncthreads();
    if (threadIdx.x == 0 && cnt_s) atomicAdd(&st->n_hi, cnt_s);
}

// p-order append: flag read coalesced, j from vj, e/v scattered only for band members
__global__ void bandj_kernel(const int* __restrict__ E, const uint2* __restrict__ vj,
                             const unsigned char* __restrict__ flag,
                             SelState* __restrict__ st,
                             unsigned int* __restrict__ band_p, unsigned int* __restrict__ band_j,
                             unsigned int* __restrict__ band_e, unsigned int* __restrict__ band_v) {
    unsigned int p = blockIdx.x * 256 + threadIdx.x;
    if (p >= NNZ) return;
    if (flag[p] == 1u) {
        uint2 t = vj[p];
        unsigned int s = atomicAdd(&st->band_n, 1u);
        if (s < BANDCAP) {
            band_p[s] = p;
            band_j[s] = t.y;
            band_e[s] = (unsigned int)E[t.y];
            band_v[s] = t.x;
        }
    }
}

// exact f64 recompute for band members; W1 staged in LDS
__global__ void rescue_kernel(const uint2* __restrict__ vj,
                              const unsigned int* __restrict__ edge_off,
                              const unsigned int* __restrict__ edge_cnt,
                              const float* __restrict__ x, const float* __restrict__ W1,
                              const float* __restrict__ b1, const float* __restrict__ W2,
                              const float* __restrict__ b2,
                              const unsigned int* __restrict__ band_e,
                              const unsigned int* __restrict__ band_v,
                              const SelState* __restrict__ st,
                              unsigned long long* __restrict__ band_key) {
    unsigned int n = st->band_n; if (n > BANDCAP) n = BANDCAP;
    if (blockIdx.x * 8 >= n) return;
    __shared__ float sW[128 * 32];
    for (int t = threadIdx.x; t < 128 * 32; t += 256) sW[t] = W1[t];
    __syncthreads();
    unsigned int g = blockIdx.x * 8 + (threadIdx.x >> 5);
    if (g >= n) return;
    int k = threadIdx.x & 31;
    unsigned int v = band_v[g];
    unsigned int e = band_e[g];
    unsigned int off = edge_off[e];
    unsigned int deg = edge_cnt[e];

    const float* xv = x + (size_t)v * 64u;
    double a = 0.0;
    #pragma unroll 8
    for (int d = 0; d < 64; ++d) a += (double)xv[d] * (double)sW[d * 32 + k];
    double bsum = 0.0;
    for (unsigned int m = off; m < off + deg; ++m) {
        const float* xm = x + (size_t)vj[m].x * 64u;
        double acc = 0.0;
        #pragma unroll 8
        for (int d = 0; d < 64; ++d) acc += (double)xm[d] * (double)sW[(64 + d) * 32 + k];
        bsum += acc;
    }
    double cc = (double)(deg > 1u ? deg : 1u);
    double h = a + bsum / cc + (double)b1[k];
    h = h > 0.0 ? h : 0.0;
    double t = h * (double)W2[k];
    #pragma unroll
    for (int o = 16; o > 0; o >>= 1) t += __shfl_down(t, o, 32);
    if (k == 0) {
        double pr = 1.0 / (1.0 + exp(-(t + (double)b2[0])));
        band_key[g] = (unsigned long long)__double_as_longlong(pr);
    }
}

// ---------------- O(n) band selection: 2-level hist on monotone u32 map ----------------
__global__ void bhist1_kernel(const unsigned long long* __restrict__ band_key,
                              const SelState* __restrict__ st, unsigned int* __restrict__ hist) {
    __shared__ unsigned int lh[2048];
    for (int t = threadIdx.x; t < 2048; t += 256) lh[t] = 0;
    __syncthreads();
    unsigned int n = st->band_n; if (n > BANDCAP) n = BANDCAP;
    float lo = st->lo_edge;
    for (unsigned int i = blockIdx.x * 256 + threadIdx.x; i < n; i += gridDim.x * 256) {
        unsigned int u = band_u32(__longlong_as_double((long long)band_key[i]), lo);
        atomicAdd(&lh[u >> 21], 1u);
    }
    __syncthreads();
    for (int t = threadIdx.x; t < 2048; t += 256)
        if (lh[t]) atomicAdd(&hist[4096 + t], lh[t]);
}

__global__ void bhist2_kernel(const unsigned long long* __restrict__ band_key,
                              const SelState* __restrict__ st, unsigned int* __restrict__ hist) {
    __shared__ unsigned int lh[2048];
    for (int t = threadIdx.x; t < 2048; t += 256) lh[t] = 0;
    __syncthreads();
    unsigned int n = st->band_n; if (n > BANDCAP) n = BANDCAP;
    float lo = st->lo_edge;
    unsigned int bB1 = st->bB1;
    for (unsigned int i = blockIdx.x * 256 + threadIdx.x; i < n; i += gridDim.x * 256) {
        unsigned int u = band_u32(__longlong_as_double((long long)band_key[i]), lo);
        if ((u >> 21) == bB1) atomicAdd(&lh[(u >> 10) & 2047u], 1u);
    }
    __syncthreads();
    for (int t = threadIdx.x; t < 2048; t += 256)
        if (lh[t]) atomicAdd(&hist[6144 + t], lh[t]);
}

// which=0: bucket bB1 at rank (K_KEEP - n_hi); which=1: bucket bB2 at rank brem1 -> bU0, brem2
__global__ void bscan_kernel(const unsigned int* __restrict__ hist, SelState* __restrict__ st, int which) {
    __shared__ unsigned int csum[256];
    int t = threadIdx.x;
    unsigned int target = (which == 0) ? ((unsigned int)K_KEEP - st->n_hi) : st->brem1;
    const unsigned int* h = hist + (which ? 6144 : 4096);
    unsigned int b[8];
    unsigned int s = 0;
    #pragma unroll
    for (int i = 0; i < 8; ++i) { b[i] = h[t * 8 + i]; s += b[i]; }
    csum[t] = s;
    __syncthreads();
    for (int off = 1; off < 256; off <<= 1) {
        unsigned int v = (t + off < 256) ? csum[t + off] : 0u;
        __syncthreads();
        csum[t] += v;
        __syncthreads();
    }
    unsigned int above = csum[t] - s;
    if (above < target && target <= above + s) {
        unsigned int rem = target - above;
        unsigned int cum = 0;
        #pragma unroll
        for (int i = 7; i >= 0; --i) {
            if (rem <= cum + b[i]) {
                unsigned int bin = (unsigned int)(t * 8 + i);
                if (which == 0) { st->bB1 = bin; st->brem1 = rem - cum; }
                else            { st->bU0 = (st->bB1 << 21) | (bin << 10); st->brem2 = rem - cum; }
                break;
            }
            cum += b[i];
        }
    }
}

// mark u >= bU0+1024 selected; collect tie bucket [bU0, bU0+1024)
__global__ void btie_kernel(const unsigned long long* __restrict__ band_key,
                            const unsigned int* __restrict__ band_j,
                            const unsigned int* __restrict__ band_p,
                            SelState* __restrict__ st, unsigned char* __restrict__ flag,
                            unsigned long long* __restrict__ tie_k,
                            unsigned int* __restrict__ tie_j, unsigned int* __restrict__ tie_p) {
    unsigned int n = st->band_n; if (n > BANDCAP) n = BANDCAP;
    unsigned int i = blockIdx.x * 256 + threadIdx.x;
    if (i >= n) return;
    float lo = st->lo_edge;
    unsigned int U0 = st->bU0;
    unsigned long long key = band_key[i];
    unsigned int u = band_u32(__longlong_as_double((long long)key), lo);
    if (u >= U0 + 1024u) {
        flag[band_p[i]] = 2u;
    } else if (u >= U0) {
        unsigned int s = atomicAdd(&st->tie_n, 1u);
        if (s < TIECAP) { tie_k[s] = key; tie_j[s] = band_j[i]; tie_p[s] = band_p[i]; }
    }
}

// exact rank inside the (tiny) tie bucket by (key desc, j asc); take first brem2
__global__ void btierank_kernel(const unsigned long long* __restrict__ tie_k,
                                const unsigned int* __restrict__ tie_j,
                                const unsigned int* __restrict__ tie_p,
                                const SelState* __restrict__ st, unsigned char* __restrict__ flag) {
    unsigned int n = st->tie_n; if (n > TIECAP) n = TIECAP;
    unsigned int need = st->brem2;
    for (unsigned int i = threadIdx.x; i < n; i += 256) {
        unsigned long long ki = tie_k[i];
        unsigned int ji = tie_j[i];
        unsigned int r = 0;
        for (unsigned int q = 0; q < n; ++q) {
            unsigned long long kq = tie_k[q];
            if (kq > ki || (kq == ki && tie_j[q] < ji)) r++;
        }
        if (r < need) flag[tie_p[i]] = 2u;
    }
}

// j-order coalesced outputs; hard bit computed inline from gathered probs/flag
__global__ void out_kernel(const float* __restrict__ probs_b, const unsigned char* __restrict__ flag,
                           const unsigned int* __restrict__ pos, const SelState* __restrict__ st,
                           float* __restrict__ o_probs, float* __restrict__ o_soft, float* __restrict__ o_hard) {
    unsigned int j = blockIdx.x * 256 + threadIdx.x;
    if (j >= NNZ) return;
    float hi = st->hi_edge;
    unsigned int p = pos[j];
    float pk = probs_b[p];
    float hb = (pk > hi || flag[p] == 2u) ? 1.f : 0.f;
    o_probs[j] = pk;
    o_soft[j]  = hb;
    o_hard[j]  = hb;
}

// per-edge: edge_soft / edge_hard recomputed from CSR-coalesced probs/flag
__global__ void edge_out_kernel(const float* __restrict__ probs_b, const unsigned char* __restrict__ flag,
                                const unsigned int* __restrict__ edge_off,
                                const unsigned int* __restrict__ edge_cnt,
                                const SelState* __restrict__ st,
                                float* __restrict__ o_es, float* __restrict__ o_eh) {
    unsigned int e = blockIdx.x * 256 + threadIdx.x;
    if (e >= N_EDGES) return;
    float hi = st->hi_edge;
    unsigned int off = edge_off[e], deg = edge_cnt[e];
    unsigned int cnt = 0;
    for (unsigned int i = 0; i < deg; ++i)
        cnt += (probs_b[off + i] > hi || flag[off + i] == 2u) ? 1u : 0u;
    float cc = (float)(deg > 1u ? deg : 1u);
    o_es[e] = (float)cnt / cc;
    o_eh[e] = cnt ? 1.f : 0.f;
}

extern "C" void kernel_launch(void* const* d_in, const int* in_sizes, int n_in,
                              void* d_out, int out_size, void* d_ws, size_t ws_size,
                              hipStream_t stream) {
    const float* x  = (const float*)d_in[0];
    const int*   V  = (const int*)d_in[1];
    const int*   E  = (const int*)d_in[2];
    const float* W1 = (const float*)d_in[3];
    const float* b1 = (const float*)d_in[4];
    const float* W2 = (const float*)d_in[5];
    const float* b2 = (const float*)d_in[6];

    float* out     = (float*)d_out;
    float* o_probs = out;
    float* o_soft  = out + NNZ;
    float* o_hard  = out + 2 * (size_t)NNZ;
    float* o_ep    = out + 3 * (size_t)NNZ;
    float* o_es    = out + 3 * (size_t)NNZ + N_EDGES;
    float* o_eh    = out + 3 * (size_t)NNZ + 2 * (size_t)N_EDGES;

    char* w = (char*)d_ws;
    float2*             p_ab2    = (float2*)(w + OFF_PAB);
    float*              probs_b  = (float*)(w + OFF_PB32);
    uint2*              vj       = (uint2*)(w + OFF_VJ);
    unsigned int*       pos      = (unsigned int*)(w + OFF_POS);
    unsigned int*       edge_off = (unsigned int*)(w + OFF_EOFF);
    unsigned int*       cursor   = (unsigned int*)(w + OFF_CUR);
    unsigned int*       bsums    = (unsigned int*)(w + OFF_BS);
    unsigned int*       band_p   = (unsigned int*)(w + OFF_BANDP);
    unsigned int*       band_j   = (unsigned int*)(w + OFF_BANDJ);
    unsigned int*       band_e   = (unsigned int*)(w + OFF_BANDE);
    unsigned int*       band_v   = (unsigned int*)(w + OFF_BANDV);
    unsigned long long* band_key = (unsigned long long*)(w + OFF_BANDK);
    unsigned long long* tie_k    = (unsigned long long*)(w + OFF_TIEK);
    unsigned int*       tie_j    = (unsigned int*)(w + OFF_TIEJ);
    unsigned int*       tie_p    = (unsigned int*)(w + OFF_TIEP);
    unsigned char*      flag     = (unsigned char*)(w + OFF_FLAG);
    unsigned int*       edge_cnt = (unsigned int*)(w + OFF_ECNT);
    unsigned int*       hist     = (unsigned int*)(w + OFF_HIST);
    SelState*           st       = (SelState*)(w + OFF_ST);

    hipMemsetAsync(w + ZERO_OFF, 0, ZERO_LEN, stream);

    proj_kernel<<<(N_NODES + 7) / 8, 256, 0, stream>>>(x, W1, p_ab2);

    count_kernel<<<(NNZ + 255) / 256, 256, 0, stream>>>(E, edge_cnt);
    scanA_kernel<<<SCAN_BLOCKS, 256, 0, stream>>>(edge_cnt, edge_off, bsums);
    scanB_kernel<<<1, 256, 0, stream>>>(bsums);
    scanC_kernel<<<(N_EDGES + 255) / 256, 256, 0, stream>>>(edge_off, bsums, cursor);
    bucket_kernel<<<(NNZ + 2047) / 2048, 256, 0, stream>>>(V, E, cursor, vj, pos);

    edge_logit_kernel<<<(N_EDGES + 3) / 4, 256, 0, stream>>>(vj, edge_off, edge_cnt,
                                                             p_ab2, b1, W2, b2, probs_b, o_ep);

    hist1_kernel<<<1024, 256, 0, stream>>>(probs_b, hist);
    scan_sel_kernel<<<1, 256, 0, stream>>>(hist, st, 0);
    hist2_kernel<<<1024, 256, 0, stream>>>(probs_b, st, hist);
    scan_sel_kernel<<<1, 256, 0, stream>>>(hist, st, 1);

    band_kernel<<<1024, 256, 0, stream>>>(probs_b, st, flag);
    bandj_kernel<<<(NNZ + 255) / 256, 256, 0, stream>>>(E, vj, flag, st,
                                                        band_p, band_j, band_e, band_v);
    rescue_kernel<<<BANDCAP / 8, 256, 0, stream>>>(vj, edge_off, edge_cnt, x, W1, b1, W2, b2,
                                                   band_e, band_v, st, band_key);

    bhist1_kernel<<<64, 256, 0, stream>>>(band_key, st, hist);
    bscan_kernel<<<1, 256, 0, stream>>>(hist, st, 0);
    bhist2_kernel<<<64, 256, 0, stream>>>(band_key, st, hist);
    bscan_kernel<<<1, 256, 0, stream>>>(hist, st, 1);
    btie_kernel<<<BANDCAP / 256, 256, 0, stream>>>(band_key, band_j, band_p, st, flag,
                                                   tie_k, tie_j, tie_p);
    btierank_kernel<<<1, 256, 0, stream>>>(tie_k, tie_j, tie_p, st, flag);

    out_kernel<<<(NNZ + 255) / 256, 256, 0, stream>>>(probs_b, flag, pos, st, o_probs, o_soft, o_hard);
    edge_out_kernel<<<(N_EDGES + 255) / 256, 256, 0, stream>>>(probs_b, flag, edge_off, edge_cnt, st,
                                                               o_es, o_eh);
}

// Round 11
// 785.567 us; speedup vs baseline: 4.6671x; 1.0852x over previous
//
#include <hip/hip_runtime.h>
#include <math.h>

#define N_NODES   100000
#define N_EDGES   200000
#define NNZ       2000000
#define K_KEEP    1000000
#define BANDCAP   131072
#define TIECAP    4096
#define DELTA     1.0e-3f
#define SCAN_BLOCKS 196   // ceil(200000/1024)
#define USCALE (4294967296.0 / 4.0e-3)   // band key -> u32 map; band width < 4e-3 guaranteed

// ---------------- workspace layout (bytes) ----------------
#define OFF_PAB   ((size_t)0)          // float2 p_ab2 [N_NODES*32] 25,600,000 (.x=a_vk, .y=b_vk)
#define OFF_PB32  ((size_t)25600000)   // f32 probs_b [NNZ]        8,000,000 (CSR/p-order probs)
#define OFF_VJ    ((size_t)33600000)   // uint2 vj [NNZ]          16,000,000 (.x=vertex, .y=orig j)
#define OFF_POS   ((size_t)49600000)   // u32 pos [NNZ] j->p       8,000,000
#define OFF_EOFF  ((size_t)57600000)   // u32 edge_off [N_EDGES]     800,000
#define OFF_CUR   ((size_t)58400000)   // u32 cursor [N_EDGES]       800,000
#define OFF_BS    ((size_t)59200000)   // u32 bsums [256]              1,024
#define OFF_BANDP ((size_t)59201024)   // u32 band_p [BANDCAP]       524,288
#define OFF_BANDJ ((size_t)59725312)   // u32 band_j [BANDCAP]       524,288
#define OFF_BANDE ((size_t)60249600)   // u32 band_e [BANDCAP]       524,288
#define OFF_BANDV ((size_t)60773888)   // u32 band_v [BANDCAP]       524,288
#define OFF_BANDK ((size_t)61298176)   // u64 band_key [BANDCAP]   1,048,576
#define OFF_TIEK  ((size_t)62346752)   // u64 tie_k [TIECAP]          32,768
#define OFF_TIEJ  ((size_t)62379520)   // u32 tie_j [TIECAP]          16,384
#define OFF_TIEP  ((size_t)62395904)   // u32 tie_p [TIECAP]          16,384
// --- zero region ---
#define OFF_FLAG  ((size_t)62412288)   // u8  flag [NNZ]           2,000,000 (0 none,1 band,2 selected)
#define OFF_ECNT  ((size_t)64412288)   // u32 edge_cnt [N_EDGES]     800,000
#define OFF_HIST  ((size_t)65212288)   // u32 hist [4*2048]           32,768
#define OFF_ST    ((size_t)65245056)   // SelState                        64
#define ZERO_OFF  OFF_FLAG
#define ZERO_LEN  ((size_t)(65245120 - 62412288))

struct SelState {
    unsigned int B1;        // f32 pass-1 bucket
    unsigned int rem1;      // remaining rank within B1
    float lo_edge, hi_edge; // band boundaries
    unsigned int n_hi;      // count of f32 probs > hi_edge
    unsigned int band_n;    // band append counter
    unsigned int bB1;       // band-select pass-1 bucket (u32 map, bits 31:21)
    unsigned int brem1;     // remaining rank within bB1
    unsigned int bU0;       // threshold u-bucket base (width 1024)
    unsigned int brem2;     // remaining rank within the u-bucket
    unsigned int tie_n;     // tie-bucket append counter
};

__device__ __forceinline__ unsigned int band_u32(double key, float lo) {
    double t = (key - (double)lo) * USCALE;
    t = t < 0.0 ? 0.0 : (t > 4294967295.0 ? 4294967295.0 : t);
    return (unsigned int)t;   // monotone non-decreasing in key
}

// p_ab2[v][k] = (sum_d x[v][d]*W1[d][k], sum_d x[v][d]*W1[64+d][k])
__global__ void proj_kernel(const float* __restrict__ x, const float* __restrict__ W1,
                            float2* __restrict__ p_ab2) {
    __shared__ float sW[128 * 32];
    __shared__ float sx[8][64];
    for (int t = threadIdx.x; t < 128 * 32; t += 256) sW[t] = W1[t];
    int base = blockIdx.x * 8;
    for (int t = threadIdx.x; t < 512; t += 256) {
        int n = t >> 6, d = t & 63;
        int g = base + n;
        sx[n][d] = (g < N_NODES) ? x[(size_t)g * 64 + d] : 0.f;
    }
    __syncthreads();
    int ln = threadIdx.x >> 5;
    int k  = threadIdx.x & 31;
    int node = base + ln;
    if (node >= N_NODES) return;
    float sa = 0.f, sb = 0.f;
    for (int d = 0; d < 64; ++d) {
        float xv = sx[ln][d];
        sa += xv * sW[d * 32 + k];
        sb += xv * sW[(64 + d) * 32 + k];
    }
    p_ab2[(size_t)node * 32 + k] = make_float2(sa, sb);
}

// ---------------- CSR build ----------------
__global__ void count_kernel(const int* __restrict__ E, unsigned int* __restrict__ edge_cnt) {
    int j = blockIdx.x * 256 + threadIdx.x;
    if (j >= NNZ) return;
    atomicAdd(&edge_cnt[E[j]], 1u);
}

__global__ void scanA_kernel(const unsigned int* __restrict__ edge_cnt,
                             unsigned int* __restrict__ edge_off, unsigned int* __restrict__ bsums) {
    __shared__ unsigned int s[256];
    int tid = threadIdx.x;
    int base = blockIdx.x * 1024 + tid * 4;
    unsigned int v0 = (base + 0 < N_EDGES) ? edge_cnt[base + 0] : 0u;
    unsigned int v1 = (base + 1 < N_EDGES) ? edge_cnt[base + 1] : 0u;
    unsigned int v2 = (base + 2 < N_EDGES) ? edge_cnt[base + 2] : 0u;
    unsigned int v3 = (base + 3 < N_EDGES) ? edge_cnt[base + 3] : 0u;
    unsigned int tsum = v0 + v1 + v2 + v3;
    s[tid] = tsum;
    __syncthreads();
    for (int off = 1; off < 256; off <<= 1) {
        unsigned int t = (tid >= off) ? s[tid - off] : 0u;
        __syncthreads();
        s[tid] += t;
        __syncthreads();
    }
    unsigned int excl = s[tid] - tsum;
    if (base + 0 < N_EDGES) edge_off[base + 0] = excl;
    if (base + 1 < N_EDGES) edge_off[base + 1] = excl + v0;
    if (base + 2 < N_EDGES) edge_off[base + 2] = excl + v0 + v1;
    if (base + 3 < N_EDGES) edge_off[base + 3] = excl + v0 + v1 + v2;
    if (tid == 255) bsums[blockIdx.x] = s[255];
}

__global__ void scanB_kernel(unsigned int* __restrict__ bsums) {
    __shared__ unsigned int s[256];
    int tid = threadIdx.x;
    unsigned int v = (tid < SCAN_BLOCKS) ? bsums[tid] : 0u;
    s[tid] = v;
    __syncthreads();
    for (int off = 1; off < 256; off <<= 1) {
        unsigned int t = (tid >= off) ? s[tid - off] : 0u;
        __syncthreads();
        s[tid] += t;
        __syncthreads();
    }
    if (tid < SCAN_BLOCKS) bsums[tid] = s[tid] - v;
}

__global__ void scanC_kernel(unsigned int* __restrict__ edge_off, const unsigned int* __restrict__ bsums,
                             unsigned int* __restrict__ cursor) {
    int i = blockIdx.x * 256 + threadIdx.x;
    if (i >= N_EDGES) return;
    unsigned int o = edge_off[i] + bsums[i >> 10];
    edge_off[i] = o;
    cursor[i] = o;
}

// 8 incidences/thread: 8 independent atomic returns in flight (hide far-atomic latency)
__global__ void bucket_kernel(const int* __restrict__ V, const int* __restrict__ E,
                              unsigned int* __restrict__ cursor,
                              uint2* __restrict__ vj, unsigned int* __restrict__ pos) {
    unsigned int base = blockIdx.x * 2048 + threadIdx.x;
    int ev[8], vv[8];
    unsigned int pp[8];
    #pragma unroll
    for (int c = 0; c < 8; ++c) {
        unsigned int j = base + 256u * c;
        if (j < NNZ) { ev[c] = E[j]; vv[c] = V[j]; }
    }
    #pragma unroll
    for (int c = 0; c < 8; ++c) {
        unsigned int j = base + 256u * c;
        if (j < NNZ) pp[c] = atomicAdd(&cursor[ev[c]], 1u);
    }
    #pragma unroll
    for (int c = 0; c < 8; ++c) {
        unsigned int j = base + 256u * c;
        if (j < NNZ) {
            vj[pp[c]] = make_uint2((unsigned int)vv[c], j);
            pos[j] = pp[c];
        }
    }
}

// ---------------- fused per-edge mean + per-incidence MLP (f32, CSR-order writes) ----------------
__global__ void edge_logit_kernel(const uint2* __restrict__ vj,
                                  const unsigned int* __restrict__ edge_off,
                                  const unsigned int* __restrict__ edge_cnt,
                                  const float2* __restrict__ p_ab2,
                                  const float* __restrict__ b1, const float* __restrict__ W2,
                                  const float* __restrict__ b2,
                                  float* __restrict__ probs_b, float* __restrict__ o_ep) {
    __shared__ float sa[4][32 * 32];   // 16 KB: [wave][slot i][k]
    __shared__ float slog[4][32];      // per-incidence logits
    int e = blockIdx.x * 4 + (threadIdx.x >> 6);
    if (e >= N_EDGES) return;
    int w    = threadIdx.x >> 6;
    int lane = threadIdx.x & 63;
    int k    = lane & 31;
    unsigned int half = (unsigned int)(lane >> 5);

    unsigned int off = edge_off[e];
    unsigned int deg = edge_cnt[e];
    unsigned int mind = deg < 32u ? deg : 32u;

    // coalesced member-id preload (lanes 0..mind-1)
    unsigned int myv = ((unsigned int)lane < mind) ? vj[off + lane].x : 0u;

    float bacc = 0.f;
    for (unsigned int i = half; i < mind; i += 2u) {
        unsigned int v = (unsigned int)__shfl((int)myv, (int)i, 64);
        float2 r = p_ab2[(size_t)v * 32u + k];
        sa[w][i * 32 + k] = r.x;
        bacc += r.y;
    }
    for (unsigned int i = 32u + half; i < deg; i += 2u) {   // deg>32 tail: b only
        unsigned int v = vj[off + i].x;
        bacc += p_ab2[(size_t)v * 32u + k].y;
    }

    float cc  = (float)(deg > 1u ? deg : 1u);
    float emk = (bacc + __shfl_xor(bacc, 32)) / cc + b1[k];
    float w2k = W2[k];
    float b2v = b2[0];
    float prsum = 0.f;

    for (unsigned int i = half; i < mind; i += 2u) {
        float hk = sa[w][i * 32 + k] + emk;
        hk = hk > 0.f ? hk : 0.f;
        float t = hk * w2k;
        #pragma unroll
        for (int o = 16; o > 0; o >>= 1) t += __shfl_down(t, o, 32);
        if (k == 0) slog[w][i] = t;
    }
    // vectorized epilogue: lane i <-> incidence i (same wave; LDS ops in order)
    if ((unsigned int)lane < mind) {
        float pr = 1.f / (1.f + __expf(-(slog[w][lane] + b2v)));
        probs_b[off + lane] = pr;      // coalesced
        prsum = pr;
    }
    for (unsigned int i = 32u + half; i < deg; i += 2u) {   // deg>32 tail: a from global
        unsigned int v = vj[off + i].x;
        float hk = p_ab2[(size_t)v * 32u + k].x + emk;
        hk = hk > 0.f ? hk : 0.f;
        float t = hk * w2k;
        #pragma unroll
        for (int o = 16; o > 0; o >>= 1) t += __shfl_down(t, o, 32);
        if (k == 0) {
            float pr = 1.f / (1.f + __expf(-(t + b2v)));
            probs_b[off + i] = pr;
            prsum += pr;
        }
    }
    #pragma unroll
    for (int o = 32; o > 0; o >>= 1) prsum += __shfl_down(prsum, o, 64);
    if (lane == 0) o_ep[e] = prsum / cc;
}

// ---------------- 2-level radix histogram on f32 keys ----------------
__global__ void hist1_kernel(const float* __restrict__ probs_b, unsigned int* __restrict__ hist) {
    __shared__ unsigned int lh[2048];
    for (int t = threadIdx.x; t < 2048; t += 256) lh[t] = 0;
    __syncthreads();
    for (unsigned int i = blockIdx.x * 256 + threadIdx.x; i < NNZ; i += gridDim.x * 256) {
        unsigned int key = __float_as_uint(probs_b[i]);
        atomicAdd(&lh[key >> 21], 1u);
    }
    __syncthreads();
    for (int t = threadIdx.x; t < 2048; t += 256)
        if (lh[t]) atomicAdd(&hist[t], lh[t]);
}

__global__ void hist2_kernel(const float* __restrict__ probs_b, const SelState* __restrict__ st,
                             unsigned int* __restrict__ hist) {
    __shared__ unsigned int lh[2048];
    for (int t = threadIdx.x; t < 2048; t += 256) lh[t] = 0;
    __syncthreads();
    unsigned int B1 = st->B1;
    for (unsigned int i = blockIdx.x * 256 + threadIdx.x; i < NNZ; i += gridDim.x * 256) {
        unsigned int key = __float_as_uint(probs_b[i]);
        if ((key >> 21) == B1) atomicAdd(&lh[(key >> 10) & 2047u], 1u);
    }
    __syncthreads();
    for (int t = threadIdx.x; t < 2048; t += 256)
        if (lh[t]) atomicAdd(&hist[2048 + t], lh[t]);
}

// which=0: select bucket B1 at rank K_KEEP; which=1: select B2 at rank rem1, set band edges
__global__ void scan_sel_kernel(const unsigned int* __restrict__ hist, SelState* __restrict__ st, int which) {
    __shared__ unsigned int csum[256];
    int t = threadIdx.x;
    unsigned int target = (which == 0) ? (unsigned int)K_KEEP : st->rem1;
    const unsigned int* h = hist + (which ? 2048 : 0);
    unsigned int b[8];
    unsigned int s = 0;
    #pragma unroll
    for (int i = 0; i < 8; ++i) { b[i] = h[t * 8 + i]; s += b[i]; }
    csum[t] = s;
    __syncthreads();
    for (int off = 1; off < 256; off <<= 1) {
        unsigned int v = (t + off < 256) ? csum[t + off] : 0u;
        __syncthreads();
        csum[t] += v;
        __syncthreads();
    }
    unsigned int above = csum[t] - s;       // sum over chunks > t
    if (above < target && target <= above + s) {
        unsigned int rem = target - above;
        unsigned int cum = 0;
        #pragma unroll
        for (int i = 7; i >= 0; --i) {
            if (rem <= cum + b[i]) {
                unsigned int bin = (unsigned int)(t * 8 + i);
                if (which == 0) { st->B1 = bin; st->rem1 = rem - cum; }
                else {
                    unsigned int P = (st->B1 << 21) | (bin << 10);
                    st->lo_edge = __uint_as_float(P) - DELTA;
                    st->hi_edge = __uint_as_float(P + 1024u) + DELTA;
                }
                break;
            }
            cum += b[i];
        }
    }
}

// grid-stride: count n_hi (block-reduced, 1 atomic/block); flag band members [lo,hi]
__global__ void band_kernel(const float* __restrict__ probs_b, SelState* __restrict__ st,
                            unsigned char* __restrict__ flag) {
    __shared__ unsigned int cnt_s;
    if (threadIdx.x == 0) cnt_s = 0;
    __syncthreads();
    float hi = st->hi_edge, lo = st->lo_edge;
    unsigned int local = 0;
    for (unsigned int p = blockIdx.x * 256 + threadIdx.x; p < NNZ; p += gridDim.x * 256) {
        float pk = probs_b[p];
        if (pk > hi) local++;
        else if (pk >= lo) flag[p] = 1;
    }
    #pragma unroll
    for (int o = 32; o > 0; o >>= 1) local += __shfl_down(local, o);
    if ((threadIdx.x & 63) == 0 && local) atomicAdd(&cnt_s, local);
    __syncthreads();
    if (threadIdx.x == 0 && cnt_s) atomicAdd(&st->n_hi, cnt_s);
}

// p-order append with per-block aggregation: LDS compaction counter + ONE global atomic/block
__global__ void bandj_kernel(const int* __restrict__ E, const uint2* __restrict__ vj,
                             const unsigned char* __restrict__ flag,
                             SelState* __restrict__ st,
                             unsigned int* __restrict__ band_p, unsigned int* __restrict__ band_j,
                             unsigned int* __restrict__ band_e, unsigned int* __restrict__ band_v) {
    __shared__ unsigned int scnt, sbase;
    if (threadIdx.x == 0) scnt = 0;
    __syncthreads();
    unsigned int p = blockIdx.x * 256 + threadIdx.x;
    bool isband = (p < NNZ) && (flag[p] == 1u);
    unsigned int local = 0;
    if (isband) local = atomicAdd(&scnt, 1u);     // LDS atomic: on-CU, fast
    __syncthreads();
    if (threadIdx.x == 0 && scnt) sbase = atomicAdd(&st->band_n, scnt);
    __syncthreads();
    if (isband) {
        unsigned int s = sbase + local;
        if (s < BANDCAP) {
            uint2 t = vj[p];
            band_p[s] = p;
            band_j[s] = t.y;
            band_e[s] = (unsigned int)E[t.y];
            band_v[s] = t.x;
        }
    }
}

// exact f64 recompute for band members; W1 staged in LDS
__global__ void rescue_kernel(const uint2* __restrict__ vj,
                              const unsigned int* __restrict__ edge_off,
                              const unsigned int* __restrict__ edge_cnt,
                              const float* __restrict__ x, const float* __restrict__ W1,
                              const float* __restrict__ b1, const float* __restrict__ W2,
                              const float* __restrict__ b2,
                              const unsigned int* __restrict__ band_e,
                              const unsigned int* __restrict__ band_v,
                              const SelState* __restrict__ st,
                              unsigned long long* __restrict__ band_key) {
    unsigned int n = st->band_n; if (n > BANDCAP) n = BANDCAP;
    if (blockIdx.x * 8 >= n) return;
    __shared__ float sW[128 * 32];
    for (int t = threadIdx.x; t < 128 * 32; t += 256) sW[t] = W1[t];
    __syncthreads();
    unsigned int g = blockIdx.x * 8 + (threadIdx.x >> 5);
    if (g >= n) return;
    int k = threadIdx.x & 31;
    unsigned int v = band_v[g];
    unsigned int e = band_e[g];
    unsigned int off = edge_off[e];
    unsigned int deg = edge_cnt[e];

    const float* xv = x + (size_t)v * 64u;
    double a = 0.0;
    #pragma unroll 8
    for (int d = 0; d < 64; ++d) a += (double)xv[d] * (double)sW[d * 32 + k];
    double bsum = 0.0;
    for (unsigned int m = off; m < off + deg; ++m) {
        const float* xm = x + (size_t)vj[m].x * 64u;
        double acc = 0.0;
        #pragma unroll 8
        for (int d = 0; d < 64; ++d) acc += (double)xm[d] * (double)sW[(64 + d) * 32 + k];
        bsum += acc;
    }
    double cc = (double)(deg > 1u ? deg : 1u);
    double h = a + bsum / cc + (double)b1[k];
    h = h > 0.0 ? h : 0.0;
    double t = h * (double)W2[k];
    #pragma unroll
    for (int o = 16; o > 0; o >>= 1) t += __shfl_down(t, o, 32);
    if (k == 0) {
        double pr = 1.0 / (1.0 + exp(-(t + (double)b2[0])));
        band_key[g] = (unsigned long long)__double_as_longlong(pr);
    }
}

// ---------------- O(n) band selection: 2-level hist on monotone u32 map ----------------
__global__ void bhist1_kernel(const unsigned long long* __restrict__ band_key,
                              const SelState* __restrict__ st, unsigned int* __restrict__ hist) {
    __shared__ unsigned int lh[2048];
    for (int t = threadIdx.x; t < 2048; t += 256) lh[t] = 0;
    __syncthreads();
    unsigned int n = st->band_n; if (n > BANDCAP) n = BANDCAP;
    float lo = st->lo_edge;
    for (unsigned int i = blockIdx.x * 256 + threadIdx.x; i < n; i += gridDim.x * 256) {
        unsigned int u = band_u32(__longlong_as_double((long long)band_key[i]), lo);
        atomicAdd(&lh[u >> 21], 1u);
    }
    __syncthreads();
    for (int t = threadIdx.x; t < 2048; t += 256)
        if (lh[t]) atomicAdd(&hist[4096 + t], lh[t]);
}

__global__ void bhist2_kernel(const unsigned long long* __restrict__ band_key,
                              const SelState* __restrict__ st, unsigned int* __restrict__ hist) {
    __shared__ unsigned int lh[2048];
    for (int t = threadIdx.x; t < 2048; t += 256) lh[t] = 0;
    __syncthreads();
    unsigned int n = st->band_n; if (n > BANDCAP) n = BANDCAP;
    float lo = st->lo_edge;
    unsigned int bB1 = st->bB1;
    for (unsigned int i = blockIdx.x * 256 + threadIdx.x; i < n; i += gridDim.x * 256) {
        unsigned int u = band_u32(__longlong_as_double((long long)band_key[i]), lo);
        if ((u >> 21) == bB1) atomicAdd(&lh[(u >> 10) & 2047u], 1u);
    }
    __syncthreads();
    for (int t = threadIdx.x; t < 2048; t += 256)
        if (lh[t]) atomicAdd(&hist[6144 + t], lh[t]);
}

// which=0: bucket bB1 at rank (K_KEEP - n_hi); which=1: bucket bB2 at rank brem1 -> bU0, brem2
__global__ void bscan_kernel(const unsigned int* __restrict__ hist, SelState* __restrict__ st, int which) {
    __shared__ unsigned int csum[256];
    int t = threadIdx.x;
    unsigned int target = (which == 0) ? ((unsigned int)K_KEEP - st->n_hi) : st->brem1;
    const unsigned int* h = hist + (which ? 6144 : 4096);
    unsigned int b[8];
    unsigned int s = 0;
    #pragma unroll
    for (int i = 0; i < 8; ++i) { b[i] = h[t * 8 + i]; s += b[i]; }
    csum[t] = s;
    __syncthreads();
    for (int off = 1; off < 256; off <<= 1) {
        unsigned int v = (t + off < 256) ? csum[t + off] : 0u;
        __syncthreads();
        csum[t] += v;
        __syncthreads();
    }
    unsigned int above = csum[t] - s;
    if (above < target && target <= above + s) {
        unsigned int rem = target - above;
        unsigned int cum = 0;
        #pragma unroll
        for (int i = 7; i >= 0; --i) {
            if (rem <= cum + b[i]) {
                unsigned int bin = (unsigned int)(t * 8 + i);
                if (which == 0) { st->bB1 = bin; st->brem1 = rem - cum; }
                else            { st->bU0 = (st->bB1 << 21) | (bin << 10); st->brem2 = rem - cum; }
                break;
            }
            cum += b[i];
        }
    }
}

// mark u >= bU0+1024 selected; collect tie bucket [bU0, bU0+1024)
__global__ void btie_kernel(const unsigned long long* __restrict__ band_key,
                            const unsigned int* __restrict__ band_j,
                            const unsigned int* __restrict__ band_p,
                            SelState* __restrict__ st, unsigned char* __restrict__ flag,
                            unsigned long long* __restrict__ tie_k,
                            unsigned int* __restrict__ tie_j, unsigned int* __restrict__ tie_p) {
    unsigned int n = st->band_n; if (n > BANDCAP) n = BANDCAP;
    unsigned int i = blockIdx.x * 256 + threadIdx.x;
    if (i >= n) return;
    float lo = st->lo_edge;
    unsigned int U0 = st->bU0;
    unsigned long long key = band_key[i];
    unsigned int u = band_u32(__longlong_as_double((long long)key), lo);
    if (u >= U0 + 1024u) {
        flag[band_p[i]] = 2u;
    } else if (u >= U0) {
        unsigned int s = atomicAdd(&st->tie_n, 1u);
        if (s < TIECAP) { tie_k[s] = key; tie_j[s] = band_j[i]; tie_p[s] = band_p[i]; }
    }
}

// exact rank inside the (tiny) tie bucket by (key desc, j asc); take first brem2
__global__ void btierank_kernel(const unsigned long long* __restrict__ tie_k,
                                const unsigned int* __restrict__ tie_j,
                                const unsigned int* __restrict__ tie_p,
                                const SelState* __restrict__ st, unsigned char* __restrict__ flag) {
    unsigned int n = st->tie_n; if (n > TIECAP) n = TIECAP;
    unsigned int need = st->brem2;
    for (unsigned int i = threadIdx.x; i < n; i += 256) {
        unsigned long long ki = tie_k[i];
        unsigned int ji = tie_j[i];
        unsigned int r = 0;
        for (unsigned int q = 0; q < n; ++q) {
            unsigned long long kq = tie_k[q];
            if (kq > ki || (kq == ki && tie_j[q] < ji)) r++;
        }
        if (r < need) flag[tie_p[i]] = 2u;
    }
}

// j-order coalesced outputs; hard bit computed inline from gathered probs/flag
__global__ void out_kernel(const float* __restrict__ probs_b, const unsigned char* __restrict__ flag,
                           const unsigned int* __restrict__ pos, const SelState* __restrict__ st,
                           float* __restrict__ o_probs, float* __restrict__ o_soft, float* __restrict__ o_hard) {
    unsigned int j = blockIdx.x * 256 + threadIdx.x;
    if (j >= NNZ) return;
    float hi = st->hi_edge;
    unsigned int p = pos[j];
    float pk = probs_b[p];
    float hb = (pk > hi || flag[p] == 2u) ? 1.f : 0.f;
    o_probs[j] = pk;
    o_soft[j]  = hb;
    o_hard[j]  = hb;
}

// per-edge: edge_soft / edge_hard recomputed from CSR-coalesced probs/flag
__global__ void edge_out_kernel(const float* __restrict__ probs_b, const unsigned char* __restrict__ flag,
                                const unsigned int* __restrict__ edge_off,
                                const unsigned int* __restrict__ edge_cnt,
                                const SelState* __restrict__ st,
                                float* __restrict__ o_es, float* __restrict__ o_eh) {
    unsigned int e = blockIdx.x * 256 + threadIdx.x;
    if (e >= N_EDGES) return;
    float hi = st->hi_edge;
    unsigned int off = edge_off[e], deg = edge_cnt[e];
    unsigned int cnt = 0;
    for (unsigned int i = 0; i < deg; ++i)
        cnt += (probs_b[off + i] > hi || flag[off + i] == 2u) ? 1u : 0u;
    float cc = (float)(deg > 1u ? deg : 1u);
    o_es[e] = (float)cnt / cc;
    o_eh[e] = cnt ? 1.f : 0.f;
}

extern "C" void kernel_launch(void* const* d_in, const int* in_sizes, int n_in,
                              void* d_out, int out_size, void* d_ws, size_t ws_size,
                              hipStream_t stream) {
    const float* x  = (const float*)d_in[0];
    const int*   V  = (const int*)d_in[1];
    const int*   E  = (const int*)d_in[2];
    const float* W1 = (const float*)d_in[3];
    const float* b1 = (const float*)d_in[4];
    const float* W2 = (const float*)d_in[5];
    const float* b2 = (const float*)d_in[6];

    float* out     = (float*)d_out;
    float* o_probs = out;
    float* o_soft  = out + NNZ;
    float* o_hard  = out + 2 * (size_t)NNZ;
    float* o_ep    = out + 3 * (size_t)NNZ;
    float* o_es    = out + 3 * (size_t)NNZ + N_EDGES;
    float* o_eh    = out + 3 * (size_t)NNZ + 2 * (size_t)N_EDGES;

    char* w = (char*)d_ws;
    float2*             p_ab2    = (float2*)(w + OFF_PAB);
    float*              probs_b  = (float*)(w + OFF_PB32);
    uint2*              vj       = (uint2*)(w + OFF_VJ);
    unsigned int*       pos      = (unsigned int*)(w + OFF_POS);
    unsigned int*       edge_off = (unsigned int*)(w + OFF_EOFF);
    unsigned int*       cursor   = (unsigned int*)(w + OFF_CUR);
    unsigned int*       bsums    = (unsigned int*)(w + OFF_BS);
    unsigned int*       band_p   = (unsigned int*)(w + OFF_BANDP);
    unsigned int*       band_j   = (unsigned int*)(w + OFF_BANDJ);
    unsigned int*       band_e   = (unsigned int*)(w + OFF_BANDE);
    unsigned int*       band_v   = (unsigned int*)(w + OFF_BANDV);
    unsigned long long* band_key = (unsigned long long*)(w + OFF_BANDK);
    unsigned long long* tie_k    = (unsigned long long*)(w + OFF_TIEK);
    unsigned int*       tie_j    = (unsigned int*)(w + OFF_TIEJ);
    unsigned int*       tie_p    = (unsigned int*)(w + OFF_TIEP);
    unsigned char*      flag     = (unsigned char*)(w + OFF_FLAG);
    unsigned int*       edge_cnt = (unsigned int*)(w + OFF_ECNT);
    unsigned int*       hist     = (unsigned int*)(w + OFF_HIST);
    SelState*           st       = (SelState*)(w + OFF_ST);

    hipMemsetAsync(w + ZERO_OFF, 0, ZERO_LEN, stream);

    proj_kernel<<<(N_NODES + 7) / 8, 256, 0, stream>>>(x, W1, p_ab2);

    count_kernel<<<(NNZ + 255) / 256, 256, 0, stream>>>(E, edge_cnt);
    scanA_kernel<<<SCAN_BLOCKS, 256, 0, stream>>>(edge_cnt, edge_off, bsums);
    scanB_kernel<<<1, 256, 0, stream>>>(bsums);
    scanC_kernel<<<(N_EDGES + 255) / 256, 256, 0, stream>>>(edge_off, bsums, cursor);
    bucket_kernel<<<(NNZ + 2047) / 2048, 256, 0, stream>>>(V, E, cursor, vj, pos);

    edge_logit_kernel<<<(N_EDGES + 3) / 4, 256, 0, stream>>>(vj, edge_off, edge_cnt,
                                                             p_ab2, b1, W2, b2, probs_b, o_ep);

    hist1_kernel<<<1024, 256, 0, stream>>>(probs_b, hist);
    scan_sel_kernel<<<1, 256, 0, stream>>>(hist, st, 0);
    hist2_kernel<<<1024, 256, 0, stream>>>(probs_b, st, hist);
    scan_sel_kernel<<<1, 256, 0, stream>>>(hist, st, 1);

    band_kernel<<<1024, 256, 0, stream>>>(probs_b, st, flag);
    bandj_kernel<<<(NNZ + 255) / 256, 256, 0, stream>>>(E, vj, flag, st,
                                                        band_p, band_j, band_e, band_v);
    rescue_kernel<<<BANDCAP / 8, 256, 0, stream>>>(vj, edge_off, edge_cnt, x, W1, b1, W2, b2,
                                                   band_e, band_v, st, band_key);

    bhist1_kernel<<<64, 256, 0, stream>>>(band_key, st, hist);
    bscan_kernel<<<1, 256, 0, stream>>>(hist, st, 0);
    bhist2_kernel<<<64, 256, 0, stream>>>(band_key, st, hist);
    bscan_kernel<<<1, 256, 0, stream>>>(hist, st, 1);
    btie_kernel<<<BANDCAP / 256, 256, 0, stream>>>(band_key, band_j, band_p, st, flag,
                                                   tie_k, tie_j, tie_p);
    btierank_kernel<<<1, 256, 0, stream>>>(tie_k, tie_j, tie_p, st, flag);

    out_kernel<<<(NNZ + 255) / 256, 256, 0, stream>>>(probs_b, flag, pos, st, o_probs, o_soft, o_hard);
    edge_out_kernel<<<(N_EDGES + 255) / 256, 256, 0, stream>>>(probs_b, flag, edge_off, edge_cnt, st,
                                                               o_es, o_eh);
}